// Round 1
// baseline (607.500 us; speedup 1.0000x reference)
//
#include <hip/hip_runtime.h>
#include <hip/hip_bf16.h>

#define NPIX 32768
#define DCH 512
#define HWSZ 1024
#define BM 128
#define BN 128
#define BK 64

typedef __bf16 bf16x8_t __attribute__((ext_vector_type(8)));
typedef float f32x4_t __attribute__((ext_vector_type(4)));
typedef unsigned short u16x8_t __attribute__((ext_vector_type(8)));
typedef unsigned short u16x4_t __attribute__((ext_vector_type(4)));

static __device__ __forceinline__ unsigned short f2bf(float f) {
    return __builtin_bit_cast(unsigned short, __float2bfloat16(f));
}

// ---------------------------------------------------------------------------
// Weight fp32 -> bf16 convert (tiny)
// ---------------------------------------------------------------------------
__global__ void cvt_bf16(const float* __restrict__ s, __hip_bfloat16* __restrict__ d, int n)
{
    int i = (blockIdx.x * 256 + threadIdx.x) * 4;
    if (i >= n) return;
    float4 f = *(const float4*)(s + i);
    u16x4_t v;
    v[0] = f2bf(f.x); v[1] = f2bf(f.y); v[2] = f2bf(f.z); v[3] = f2bf(f.w);
    *(u16x4_t*)((unsigned short*)d + i) = v;
}

// ---------------------------------------------------------------------------
// Stage: X[b][c][hw] fp32 -> XbT[branch][n][c] bf16 with gamma scale.
// LDS 64x64 tile transpose. grid: (16 hw-tiles, 8 c-tiles, 3*32 branch*b)
// ---------------------------------------------------------------------------
__global__ __launch_bounds__(256)
void stage_transpose(const float* __restrict__ x0, const float* __restrict__ x1,
                     const float* __restrict__ x2,
                     const float* __restrict__ gp0, const float* __restrict__ gp1,
                     const float* __restrict__ gp2,
                     __hip_bfloat16* __restrict__ XbT)
{
    __shared__ float tile[64][65];
    const int hw0 = blockIdx.x * 64;
    const int c0  = blockIdx.y * 64;
    const int bz  = blockIdx.z;
    const int br  = bz >> 5;
    const int b   = bz & 31;
    const float* x = (br == 0) ? x0 : ((br == 1) ? x1 : x2);
    const float g  = ((br == 0) ? gp0 : ((br == 1) ? gp1 : gp2))[0];
    const int t = threadIdx.x;

    // read 64c x 64hw, coalesced along hw
    const int hwi = t & 63;
    const int cb  = t >> 6;
    const float* src = x + (size_t)b * (DCH * HWSZ) + (size_t)c0 * HWSZ + hw0;
#pragma unroll
    for (int i = 0; i < 16; ++i) {
        const int ci = cb + i * 4;
        tile[ci][hwi] = g * src[(size_t)ci * HWSZ + hwi];
    }
    __syncthreads();

    // write rows n = b*1024+hw0+hwr, 64 c contiguous (bf16)
    const int hwr = t >> 2;
    const int cch = (t & 3) * 16;
    __hip_bfloat16* dst = XbT + (size_t)((size_t)br * NPIX + b * HWSZ + hw0 + hwr) * DCH + c0 + cch;
    u16x8_t v0, v1;
#pragma unroll
    for (int e = 0; e < 8; ++e) v0[e] = f2bf(tile[cch + e][hwr]);
#pragma unroll
    for (int e = 0; e < 8; ++e) v1[e] = f2bf(tile[cch + 8 + e][hwr]);
    *(u16x8_t*)dst = v0;
    *((u16x8_t*)dst + 1) = v1;
}

// ---------------------------------------------------------------------------
// NT GEMM: C^T[n][o] = sum_k A[n][k] * B[o][k] + bias[o]
// A: activations [*][lda] bf16 (n-major, k-contig), B: weights [o][ldb] bf16.
// trans_out=0: write C[n*ldc + coff + o] bf16
// trans_out=1: LDS-transpose epilogue, write C[(coff+o)*ldc + n] bf16
// grid.x = ntiles*NO flat, XCD-swizzled: n-outer / o-inner per XCD chunk.
// ---------------------------------------------------------------------------
__global__ __launch_bounds__(256)
void gemm_nt(const __hip_bfloat16* __restrict__ A, int lda,
             const __hip_bfloat16* __restrict__ B, int ldb,
             const float* __restrict__ bias,
             __hip_bfloat16* __restrict__ C, int ldc, int coff,
             int K, int NO, int trans_out)
{
    __shared__ __align__(16) unsigned char smem[32768];
    __hip_bfloat16 (*As)[BK] = (__hip_bfloat16 (*)[BK])smem;
    __hip_bfloat16 (*Bs)[BK] = (__hip_bfloat16 (*)[BK])(smem + BM * BK * 2);

    const int tid  = threadIdx.x;
    const int lane = tid & 63;
    const int wave = tid >> 6;

    // XCD-aware swizzle (grid divisible by 8): hw round-robins f&7 across XCDs
    const int per  = gridDim.x >> 3;
    const int xcd  = blockIdx.x & 7;
    const int j    = blockIdx.x >> 3;
    const int ntile = xcd * (per / NO) + j / NO;
    const int otile = j % NO;
    const int n0 = ntile * BM;
    const int o0 = otile * BN;

    const int wn  = (wave >> 1) * 64;
    const int wo  = (wave & 1) * 64;
    const int l16 = lane & 15;
    const int l4  = lane >> 4;

    f32x4_t acc[4][4] = {};

    const int rsub = wave * 32 + (lane >> 3);   // row within tile (+ch*8)
    const int kcol = (lane & 7) * 8;            // element offset in 64-wide k slab

    for (int k0 = 0; k0 < K; k0 += BK) {
#pragma unroll
        for (int ch = 0; ch < 4; ++ch) {
            const __hip_bfloat16* ga = A + (size_t)(n0 + rsub + ch * 8) * lda + k0 + kcol;
            __builtin_amdgcn_global_load_lds(
                (const __attribute__((address_space(1))) unsigned int*)ga,
                (__attribute__((address_space(3))) unsigned int*)(smem + (wave * 32 + ch * 8) * (BK * 2)),
                16, 0, 0);
        }
#pragma unroll
        for (int ch = 0; ch < 4; ++ch) {
            const __hip_bfloat16* gb = B + (size_t)(o0 + rsub + ch * 8) * ldb + k0 + kcol;
            __builtin_amdgcn_global_load_lds(
                (const __attribute__((address_space(1))) unsigned int*)gb,
                (__attribute__((address_space(3))) unsigned int*)(smem + BM * BK * 2 + (wave * 32 + ch * 8) * (BK * 2)),
                16, 0, 0);
        }
        __syncthreads();   // compiler drains vmcnt(0) before s_barrier (m97 structure)

#pragma unroll
        for (int kk = 0; kk < 2; ++kk) {
            bf16x8_t af[4], bfr[4];
#pragma unroll
            for (int m = 0; m < 4; ++m)
                af[m] = *(const bf16x8_t*)&As[wn + m * 16 + l16][kk * 32 + l4 * 8];
#pragma unroll
            for (int nn = 0; nn < 4; ++nn)
                bfr[nn] = *(const bf16x8_t*)&Bs[wo + nn * 16 + l16][kk * 32 + l4 * 8];
#pragma unroll
            for (int m = 0; m < 4; ++m)
#pragma unroll
                for (int nn = 0; nn < 4; ++nn)
                    acc[m][nn] = __builtin_amdgcn_mfma_f32_16x16x32_bf16(af[m], bfr[nn], acc[m][nn], 0, 0, 0);
        }
        __syncthreads();
    }

    if (!trans_out) {
#pragma unroll
        for (int nn = 0; nn < 4; ++nn) {
            const int oc = o0 + wo + nn * 16 + l16;
            const float bv = bias[oc];
#pragma unroll
            for (int m = 0; m < 4; ++m)
#pragma unroll
                for (int r = 0; r < 4; ++r) {
                    const int nr = n0 + wn + m * 16 + l4 * 4 + r;
                    C[(size_t)nr * ldc + coff + oc] = __float2bfloat16(acc[m][nn][r] + bv);
                }
        }
    } else {
        // transpose tile through LDS, write channel-major [coff+o][NPIX]
        __hip_bfloat16 (*Ct)[BN] = (__hip_bfloat16 (*)[BN])smem;
#pragma unroll
        for (int nn = 0; nn < 4; ++nn) {
            const int ocl = wo + nn * 16 + l16;
            const float bv = bias[o0 + ocl];
#pragma unroll
            for (int m = 0; m < 4; ++m)
#pragma unroll
                for (int r = 0; r < 4; ++r)
                    Ct[wn + m * 16 + l4 * 4 + r][ocl] = __float2bfloat16(acc[m][nn][r] + bv);
        }
        __syncthreads();
        const int ol   = tid & 127;
        const int half = tid >> 7;
        __hip_bfloat16* dst = C + (size_t)(coff + o0 + ol) * ldc + n0 + half * 64;
#pragma unroll
        for (int jj = 0; jj < 8; ++jj) {
            u16x8_t v;
#pragma unroll
            for (int e = 0; e < 8; ++e)
                v[e] = __builtin_bit_cast(unsigned short, Ct[half * 64 + jj * 8 + e][ol]);
            *(u16x8_t*)((unsigned short*)dst + jj * 8) = v;
        }
    }
}

// ---------------------------------------------------------------------------
// Final: g_i = sigmoid(S_i), w = softmax(g), out = sum w_i * gamma_i * x_i
// G: [1536][NPIX] bf16 channel-major (branch i at rows i*512..). All n-contig.
// grid: (NPIX/256, DCH/64)
// ---------------------------------------------------------------------------
__global__ __launch_bounds__(256)
void final_fuse(const __hip_bfloat16* __restrict__ G,
                const float* __restrict__ x0, const float* __restrict__ x1,
                const float* __restrict__ x2,
                const float* __restrict__ gp0, const float* __restrict__ gp1,
                const float* __restrict__ gp2,
                float* __restrict__ out)
{
    const int n  = blockIdx.x * 256 + threadIdx.x;
    const int b  = n >> 10;
    const int hw = n & (HWSZ - 1);
    const int c0 = blockIdx.y * 64;
    const float ga0 = gp0[0], ga1 = gp1[0], ga2 = gp2[0];
    for (int cc = 0; cc < 64; ++cc) {
        const int c = c0 + cc;
        const float s0 = __bfloat162float(G[(size_t)c * NPIX + n]);
        const float s1 = __bfloat162float(G[(size_t)(c + DCH) * NPIX + n]);
        const float s2 = __bfloat162float(G[(size_t)(c + 2 * DCH) * NPIX + n]);
        const float g0v = 1.0f / (1.0f + __expf(-s0));
        const float g1v = 1.0f / (1.0f + __expf(-s1));
        const float g2v = 1.0f / (1.0f + __expf(-s2));
        const float e0 = __expf(g0v), e1 = __expf(g1v), e2 = __expf(g2v);
        const float inv = 1.0f / (e0 + e1 + e2);
        const size_t xo = (size_t)b * (DCH * HWSZ) + (size_t)c * HWSZ + hw;
        out[xo] = inv * (e0 * ga0 * x0[xo] + e1 * ga1 * x1[xo] + e2 * ga2 * x2[xo]);
    }
}

// ---------------------------------------------------------------------------
extern "C" void kernel_launch(void* const* d_in, const int* in_sizes, int n_in,
                              void* d_out, int out_size, void* d_ws, size_t ws_size,
                              hipStream_t stream)
{
    const float* out0   = (const float*)d_in[0];
    const float* out1   = (const float*)d_in[1];
    const float* out2   = (const float*)d_in[2];
    const float* gamma0 = (const float*)d_in[3];
    const float* gamma1 = (const float*)d_in[4];
    const float* gamma2 = (const float*)d_in[5];
    const float* W_in1  = (const float*)d_in[6];
    const float* b_in1  = (const float*)d_in[7];
    const float* W_in2  = (const float*)d_in[8];
    const float* b_in2  = (const float*)d_in[9];
    const float* W_in3  = (const float*)d_in[10];
    const float* b_in3  = (const float*)d_in[11];
    const float* W_tr   = (const float*)d_in[12];
    const float* b_tr   = (const float*)d_in[13];
    const float* W_o1   = (const float*)d_in[14];
    const float* b_o1   = (const float*)d_in[15];
    const float* W_o2   = (const float*)d_in[16];
    const float* b_o2   = (const float*)d_in[17];
    const float* W_o3   = (const float*)d_in[18];
    const float* b_o3   = (const float*)d_in[19];
    float* outp = (float*)d_out;

    unsigned char* ws = (unsigned char*)d_ws;
    const size_t SZ_ACT = (size_t)3 * NPIX * DCH * 2;   // 96MB per activation buffer
    __hip_bfloat16* buf0 = (__hip_bfloat16*)ws;              // XbT, then HtraT
    __hip_bfloat16* buf1 = (__hip_bfloat16*)(ws + SZ_ACT);   // HcatT, then G
    __hip_bfloat16* Wb     = (__hip_bfloat16*)(ws + 2 * SZ_ACT);
    __hip_bfloat16* Wb_in1 = Wb;
    __hip_bfloat16* Wb_in2 = Wb_in1 + DCH * DCH;
    __hip_bfloat16* Wb_in3 = Wb_in2 + DCH * DCH;
    __hip_bfloat16* Wb_tr  = Wb_in3 + DCH * DCH;
    __hip_bfloat16* Wb_o1  = Wb_tr + 3 * DCH * 3 * DCH;
    __hip_bfloat16* Wb_o2  = Wb_o1 + DCH * DCH;
    __hip_bfloat16* Wb_o3  = Wb_o2 + DCH * DCH;

    const int WSQ = DCH * DCH;           // 262144
    const int WTR = 3 * DCH * 3 * DCH;   // 2359296
    cvt_bf16<<<WSQ / 1024, 256, 0, stream>>>(W_in1, Wb_in1, WSQ);
    cvt_bf16<<<WSQ / 1024, 256, 0, stream>>>(W_in2, Wb_in2, WSQ);
    cvt_bf16<<<WSQ / 1024, 256, 0, stream>>>(W_in3, Wb_in3, WSQ);
    cvt_bf16<<<WTR / 1024, 256, 0, stream>>>(W_tr,  Wb_tr,  WTR);
    cvt_bf16<<<WSQ / 1024, 256, 0, stream>>>(W_o1,  Wb_o1,  WSQ);
    cvt_bf16<<<WSQ / 1024, 256, 0, stream>>>(W_o2,  Wb_o2,  WSQ);
    cvt_bf16<<<WSQ / 1024, 256, 0, stream>>>(W_o3,  Wb_o3,  WSQ);

    // stage: gamma-scale + transpose to pixel-major bf16
    stage_transpose<<<dim3(16, 8, 96), 256, 0, stream>>>(out0, out1, out2,
                                                         gamma0, gamma1, gamma2, buf0);

    // GEMM-A: Hcat^T[n][i*512+o] = XbT_i x W_in_i   (K=512)
    const int NT = NPIX / BM;  // 256
    {
        const __hip_bfloat16* Ws[3] = {Wb_in1, Wb_in2, Wb_in3};
        const float* bs[3] = {b_in1, b_in2, b_in3};
        for (int i = 0; i < 3; ++i) {
            gemm_nt<<<dim3(NT * (DCH / BN)), 256, 0, stream>>>(
                buf0 + (size_t)i * NPIX * DCH, DCH, Ws[i], DCH, bs[i],
                buf1, 3 * DCH, i * DCH, DCH, DCH / BN, 0);
        }
    }
    // GEMM-B: Htra^T = Hcat^T x W_trans  (K=1536) -> buf0
    gemm_nt<<<dim3(NT * (3 * DCH / BN)), 256, 0, stream>>>(
        buf1, 3 * DCH, Wb_tr, 3 * DCH, b_tr,
        buf0, 3 * DCH, 0, 3 * DCH, 3 * DCH / BN, 0);

    // GEMM-C: G[i*512+o][n] = s_i^T x W_out_i (trans-out epilogue) -> buf1
    {
        const __hip_bfloat16* Ws[3] = {Wb_o1, Wb_o2, Wb_o3};
        const float* bs[3] = {b_o1, b_o2, b_o3};
        for (int i = 0; i < 3; ++i) {
            gemm_nt<<<dim3(NT * (DCH / BN)), 256, 0, stream>>>(
                buf0 + i * DCH, 3 * DCH, Ws[i], DCH, bs[i],
                buf1, NPIX, i * DCH, DCH, DCH / BN, 1);
        }
    }

    final_fuse<<<dim3(NPIX / 256, DCH / 64), 256, 0, stream>>>(
        buf1, out0, out1, out2, gamma0, gamma1, gamma2, outp);
}

// Round 2
// 503.867 us; speedup vs baseline: 1.2057x; 1.2057x over previous
//
#include <hip/hip_runtime.h>
#include <hip/hip_bf16.h>

#define NPIX 32768
#define DCH 512
#define HWSZ 1024

typedef __bf16 bf16x8_t __attribute__((ext_vector_type(8)));
typedef float f32x4_t __attribute__((ext_vector_type(4)));
typedef unsigned short u16x8_t __attribute__((ext_vector_type(8)));
typedef unsigned short u16x4_t __attribute__((ext_vector_type(4)));

static __device__ __forceinline__ unsigned short f2bf(float f) {
    return __builtin_bit_cast(unsigned short, __float2bfloat16(f));
}

// ---------------------------------------------------------------------------
// Weight fp32 -> bf16 convert (tiny)
// ---------------------------------------------------------------------------
__global__ void cvt_bf16(const float* __restrict__ s, __hip_bfloat16* __restrict__ d, int n)
{
    int i = (blockIdx.x * 256 + threadIdx.x) * 4;
    if (i >= n) return;
    float4 f = *(const float4*)(s + i);
    u16x4_t v;
    v[0] = f2bf(f.x); v[1] = f2bf(f.y); v[2] = f2bf(f.z); v[3] = f2bf(f.w);
    *(u16x4_t*)((unsigned short*)d + i) = v;
}

// ---------------------------------------------------------------------------
// Stage: X[b][c][hw] fp32 -> XbT[branch][n][c] bf16 with gamma scale.
// ---------------------------------------------------------------------------
__global__ __launch_bounds__(256)
void stage_transpose(const float* __restrict__ x0, const float* __restrict__ x1,
                     const float* __restrict__ x2,
                     const float* __restrict__ gp0, const float* __restrict__ gp1,
                     const float* __restrict__ gp2,
                     __hip_bfloat16* __restrict__ XbT)
{
    __shared__ float tile[64][65];
    const int hw0 = blockIdx.x * 64;
    const int c0  = blockIdx.y * 64;
    const int bz  = blockIdx.z;
    const int br  = bz >> 5;
    const int b   = bz & 31;
    const float* x = (br == 0) ? x0 : ((br == 1) ? x1 : x2);
    const float g  = ((br == 0) ? gp0 : ((br == 1) ? gp1 : gp2))[0];
    const int t = threadIdx.x;

    const int hwi = t & 63;
    const int cb  = t >> 6;
    const float* src = x + (size_t)b * (DCH * HWSZ) + (size_t)c0 * HWSZ + hw0;
#pragma unroll
    for (int i = 0; i < 16; ++i) {
        const int ci = cb + i * 4;
        tile[ci][hwi] = g * src[(size_t)ci * HWSZ + hwi];
    }
    __syncthreads();

    const int hwr = t >> 2;
    const int cch = (t & 3) * 16;
    __hip_bfloat16* dst = XbT + (size_t)((size_t)br * NPIX + b * HWSZ + hw0 + hwr) * DCH + c0 + cch;
    u16x8_t v0, v1;
#pragma unroll
    for (int e = 0; e < 8; ++e) v0[e] = f2bf(tile[cch + e][hwr]);
#pragma unroll
    for (int e = 0; e < 8; ++e) v1[e] = f2bf(tile[cch + 8 + e][hwr]);
    *(u16x8_t*)dst = v0;
    *((u16x8_t*)dst + 1) = v1;
}

// ---------------------------------------------------------------------------
// 256x256 8-phase NT GEMM: C^T[n][o] = sum_k A[n][k]*B[o][k] + bias[o]
// 512 thr = 8 waves (2M x 4N), per-wave 128x64 out. BK=64, 2-tile LDS dbuf,
// T2 swizzle (kbyte ^= (row&7)<<4) via pre-swizzled global_load_lds source,
// counted vmcnt(8) once per K-tile, setprio around MFMA clusters.
// ---------------------------------------------------------------------------
__global__ __launch_bounds__(512, 2)
void gemm256(const __hip_bfloat16* __restrict__ A, int lda,
             const __hip_bfloat16* __restrict__ B, int ldb,
             const float* __restrict__ bias,
             __hip_bfloat16* __restrict__ C, int ldc, int coff,
             int K, int NO, int trans_out)
{
    __shared__ __align__(16) unsigned char smem[131072];
    const int tid  = threadIdx.x;
    const int lane = tid & 63;
    const int wave = tid >> 6;
    const int wm   = wave >> 2;    // 0..1
    const int wn   = wave & 3;     // 0..3
    const int l16  = lane & 15;
    const int l4   = lane >> 4;

    // XCD swizzle: n-outer / o-inner per XCD chunk (grid % 8 == 0)
    const int per   = gridDim.x >> 3;
    const int xcd   = blockIdx.x & 7;
    const int j     = blockIdx.x >> 3;
    const int ntile = xcd * (per / NO) + j / NO;
    const int otile = j % NO;
    const int n0 = ntile * 256;
    const int o0 = otile * 256;
    const int NT = K >> 6;

    // read-side offsets (swizzled)
    const unsigned xorv = (unsigned)((l16 & 7) << 4);
    unsigned aRowOff[8], bRowOff[4], kOff[2];
#pragma unroll
    for (int m = 0; m < 8; ++m) aRowOff[m] = (unsigned)((wm * 128 + m * 16 + l16) * 128);
#pragma unroll
    for (int n = 0; n < 4; ++n) bRowOff[n] = (unsigned)(32768 + (wn * 64 + n * 16 + l16) * 128);
#pragma unroll
    for (int kk = 0; kk < 2; ++kk) kOff[kk] = (unsigned)((kk * 64 + l4 * 16) ^ xorv);

    // staging: per lane, inverse-swizzled global source
    const int rr  = lane >> 3;                 // row within 8-row group == row&7
    const int kel = 8 * ((lane & 7) ^ rr);     // element offset (bf16)

    auto stageA = [&](int t, int half) {
        const unsigned dst = (unsigned)((t & 1) * 65536 + half * 16384 + wave * 2048);
        const __hip_bfloat16* g = A + (size_t)(n0 + half * 128 + wave * 16 + rr) * lda + t * 64 + kel;
#pragma unroll
        for (int s = 0; s < 2; ++s) {
            __builtin_amdgcn_global_load_lds(
                (const __attribute__((address_space(1))) unsigned int*)(g + (size_t)s * 8 * lda),
                (__attribute__((address_space(3))) unsigned int*)(smem + dst + s * 1024),
                16, 0, 0);
        }
    };
    auto stageB = [&](int t, int half) {
        const unsigned dst = (unsigned)((t & 1) * 65536 + 32768 + half * 16384 + wave * 2048);
        const __hip_bfloat16* g = B + (size_t)(o0 + half * 128 + wave * 16 + rr) * ldb + t * 64 + kel;
#pragma unroll
        for (int s = 0; s < 2; ++s) {
            __builtin_amdgcn_global_load_lds(
                (const __attribute__((address_space(1))) unsigned int*)(g + (size_t)s * 8 * ldb),
                (__attribute__((address_space(3))) unsigned int*)(smem + dst + s * 1024),
                16, 0, 0);
        }
    };

    // prologue: stage tiles 0 (oldest) and 1
    stageA(0, 0); stageA(0, 1); stageB(0, 0); stageB(0, 1);
    stageA(1, 0); stageA(1, 1); stageB(1, 0); stageB(1, 1);
    asm volatile("s_waitcnt vmcnt(8)" ::: "memory");   // tile 0 landed
    __builtin_amdgcn_s_barrier();

    f32x4_t acc[8][4];
#pragma unroll
    for (int m = 0; m < 8; ++m)
#pragma unroll
        for (int n = 0; n < 4; ++n) acc[m][n] = (f32x4_t){0.f, 0.f, 0.f, 0.f};

    for (int t = 0; t < NT; ++t) {
        const unsigned cb = (unsigned)((t & 1) * 65536);
        const bool pf = (t + 2 < NT);
        bf16x8_t aR[4][2], bR[4][2];

        // ---- P0: read A(m0-3) + all B; MFMA (m0-3 x n0-1)
#pragma unroll
        for (int m = 0; m < 4; ++m)
#pragma unroll
            for (int kk = 0; kk < 2; ++kk)
                aR[m][kk] = *(const bf16x8_t*)(smem + cb + aRowOff[m] + kOff[kk]);
#pragma unroll
        for (int n = 0; n < 4; ++n)
#pragma unroll
            for (int kk = 0; kk < 2; ++kk)
                bR[n][kk] = *(const bf16x8_t*)(smem + cb + bRowOff[n] + kOff[kk]);
        __builtin_amdgcn_s_barrier();
        asm volatile("s_waitcnt lgkmcnt(0)" ::: "memory");
        __builtin_amdgcn_sched_barrier(0);
        __builtin_amdgcn_s_setprio(1);
#pragma unroll
        for (int m = 0; m < 4; ++m)
#pragma unroll
            for (int n = 0; n < 2; ++n)
#pragma unroll
                for (int kk = 0; kk < 2; ++kk)
                    acc[m][n] = __builtin_amdgcn_mfma_f32_16x16x32_bf16(aR[m][kk], bR[n][kk], acc[m][n], 0, 0, 0);
        __builtin_amdgcn_s_setprio(0);
        __builtin_amdgcn_s_barrier();

        // ---- P1: stage B-half0 of t+2 (B region dead after P0); MFMA (m0-3 x n2-3)
        if (pf) stageB(t + 2, 0);
        __builtin_amdgcn_s_barrier();
        __builtin_amdgcn_s_setprio(1);
#pragma unroll
        for (int m = 0; m < 4; ++m)
#pragma unroll
            for (int n = 2; n < 4; ++n)
#pragma unroll
                for (int kk = 0; kk < 2; ++kk)
                    acc[m][n] = __builtin_amdgcn_mfma_f32_16x16x32_bf16(aR[m][kk], bR[n][kk], acc[m][n], 0, 0, 0);
        __builtin_amdgcn_s_setprio(0);
        __builtin_amdgcn_s_barrier();

        // ---- P2: read A(m4-7); stage B-half1; MFMA (m4-7 x n0-1)
#pragma unroll
        for (int m = 0; m < 4; ++m)
#pragma unroll
            for (int kk = 0; kk < 2; ++kk)
                aR[m][kk] = *(const bf16x8_t*)(smem + cb + aRowOff[m + 4] + kOff[kk]);
        if (pf) stageB(t + 2, 1);
        __builtin_amdgcn_s_barrier();
        asm volatile("s_waitcnt lgkmcnt(0)" ::: "memory");
        __builtin_amdgcn_sched_barrier(0);
        __builtin_amdgcn_s_setprio(1);
#pragma unroll
        for (int m = 0; m < 4; ++m)
#pragma unroll
            for (int n = 0; n < 2; ++n)
#pragma unroll
                for (int kk = 0; kk < 2; ++kk)
                    acc[m + 4][n] = __builtin_amdgcn_mfma_f32_16x16x32_bf16(aR[m][kk], bR[n][kk], acc[m + 4][n], 0, 0, 0);
        __builtin_amdgcn_s_setprio(0);
        __builtin_amdgcn_s_barrier();

        // ---- P3: stage A halves of t+2 (A region dead after P2); MFMA (m4-7 x n2-3)
        if (pf) { stageA(t + 2, 0); stageA(t + 2, 1); }
        __builtin_amdgcn_s_barrier();
        __builtin_amdgcn_s_setprio(1);
#pragma unroll
        for (int m = 0; m < 4; ++m)
#pragma unroll
            for (int n = 2; n < 4; ++n)
#pragma unroll
                for (int kk = 0; kk < 2; ++kk)
                    acc[m + 4][n] = __builtin_amdgcn_mfma_f32_16x16x32_bf16(aR[m][kk], bR[n][kk], acc[m + 4][n], 0, 0, 0);
        __builtin_amdgcn_s_setprio(0);
        // iteration end: counted drain (tile t+1 lands; tile t+2 stays in flight)
        if (pf)                 { asm volatile("s_waitcnt vmcnt(8)" ::: "memory"); }
        else if (t + 2 == NT)   { asm volatile("s_waitcnt vmcnt(0)" ::: "memory"); }
        __builtin_amdgcn_s_barrier();
    }

    if (!trans_out) {
#pragma unroll
        for (int n = 0; n < 4; ++n) {
            const int oc = o0 + wn * 64 + n * 16 + l16;
            const float bv = bias[oc];
#pragma unroll
            for (int m = 0; m < 8; ++m)
#pragma unroll
                for (int r = 0; r < 4; ++r) {
                    const int nr = n0 + wm * 128 + m * 16 + l4 * 4 + r;
                    C[(size_t)nr * ldc + coff + oc] = __float2bfloat16(acc[m][n][r] + bv);
                }
        }
    } else {
        // channel-major output: transpose 256x256 tile through smem (swizzled)
        // loop-end barrier already aligned all waves; smem (tile data) is dead.
#pragma unroll
        for (int n = 0; n < 4; ++n) {
            const int ocl = wn * 64 + n * 16 + l16;
            const float bv = bias[o0 + ocl];
#pragma unroll
            for (int m = 0; m < 8; ++m)
#pragma unroll
                for (int r = 0; r < 4; ++r) {
                    const int nrow = wm * 128 + m * 16 + l4 * 4 + r;
                    const unsigned phys = (unsigned)nrow * 512u
                        + (((unsigned)ocl * 2u) ^ (((unsigned)(nrow & 7)) << 4));
                    *(unsigned short*)(smem + phys) =
                        __builtin_bit_cast(unsigned short, __float2bfloat16(acc[m][n][r] + bv));
                }
        }
        __syncthreads();
        const int ol = tid >> 1;
        const int nh = (tid & 1) * 128;
        __hip_bfloat16* dst = C + (size_t)(coff + o0 + ol) * ldc + n0 + nh;
#pragma unroll
        for (int j8 = 0; j8 < 16; ++j8) {
            u16x8_t v;
#pragma unroll
            for (int e = 0; e < 8; ++e) {
                const int n2 = nh + j8 * 8 + e;
                v[e] = *(const unsigned short*)(smem + (unsigned)n2 * 512u
                        + ((((unsigned)ol * 2u) ^ ((unsigned)e << 4))));
            }
            *(u16x8_t*)((unsigned short*)dst + j8 * 8) = v;
        }
    }
}

// ---------------------------------------------------------------------------
// Final: g_i = sigmoid(S_i), w = softmax(g), out = sum w_i * gamma_i * x_i
// ---------------------------------------------------------------------------
__global__ __launch_bounds__(256)
void final_fuse(const __hip_bfloat16* __restrict__ G,
                const float* __restrict__ x0, const float* __restrict__ x1,
                const float* __restrict__ x2,
                const float* __restrict__ gp0, const float* __restrict__ gp1,
                const float* __restrict__ gp2,
                float* __restrict__ out)
{
    const int n  = blockIdx.x * 256 + threadIdx.x;
    const int b  = n >> 10;
    const int hw = n & (HWSZ - 1);
    const int c0 = blockIdx.y * 64;
    const float ga0 = gp0[0], ga1 = gp1[0], ga2 = gp2[0];
    for (int cc = 0; cc < 64; ++cc) {
        const int c = c0 + cc;
        const float s0 = __bfloat162float(G[(size_t)c * NPIX + n]);
        const float s1 = __bfloat162float(G[(size_t)(c + DCH) * NPIX + n]);
        const float s2 = __bfloat162float(G[(size_t)(c + 2 * DCH) * NPIX + n]);
        const float g0v = 1.0f / (1.0f + __expf(-s0));
        const float g1v = 1.0f / (1.0f + __expf(-s1));
        const float g2v = 1.0f / (1.0f + __expf(-s2));
        const float e0 = __expf(g0v), e1 = __expf(g1v), e2 = __expf(g2v);
        const float inv = 1.0f / (e0 + e1 + e2);
        const size_t xo = (size_t)b * (DCH * HWSZ) + (size_t)c * HWSZ + hw;
        out[xo] = inv * (e0 * ga0 * x0[xo] + e1 * ga1 * x1[xo] + e2 * ga2 * x2[xo]);
    }
}

// ---------------------------------------------------------------------------
extern "C" void kernel_launch(void* const* d_in, const int* in_sizes, int n_in,
                              void* d_out, int out_size, void* d_ws, size_t ws_size,
                              hipStream_t stream)
{
    const float* out0   = (const float*)d_in[0];
    const float* out1   = (const float*)d_in[1];
    const float* out2   = (const float*)d_in[2];
    const float* gamma0 = (const float*)d_in[3];
    const float* gamma1 = (const float*)d_in[4];
    const float* gamma2 = (const float*)d_in[5];
    const float* W_in1  = (const float*)d_in[6];
    const float* b_in1  = (const float*)d_in[7];
    const float* W_in2  = (const float*)d_in[8];
    const float* b_in2  = (const float*)d_in[9];
    const float* W_in3  = (const float*)d_in[10];
    const float* b_in3  = (const float*)d_in[11];
    const float* W_tr   = (const float*)d_in[12];
    const float* b_tr   = (const float*)d_in[13];
    const float* W_o1   = (const float*)d_in[14];
    const float* b_o1   = (const float*)d_in[15];
    const float* W_o2   = (const float*)d_in[16];
    const float* b_o2   = (const float*)d_in[17];
    const float* W_o3   = (const float*)d_in[18];
    const float* b_o3   = (const float*)d_in[19];
    float* outp = (float*)d_out;

    unsigned char* ws = (unsigned char*)d_ws;
    const size_t SZ_ACT = (size_t)3 * NPIX * DCH * 2;
    __hip_bfloat16* buf0 = (__hip_bfloat16*)ws;
    __hip_bfloat16* buf1 = (__hip_bfloat16*)(ws + SZ_ACT);
    __hip_bfloat16* Wb     = (__hip_bfloat16*)(ws + 2 * SZ_ACT);
    __hip_bfloat16* Wb_in1 = Wb;
    __hip_bfloat16* Wb_in2 = Wb_in1 + DCH * DCH;
    __hip_bfloat16* Wb_in3 = Wb_in2 + DCH * DCH;
    __hip_bfloat16* Wb_tr  = Wb_in3 + DCH * DCH;
    __hip_bfloat16* Wb_o1  = Wb_tr + 3 * DCH * 3 * DCH;
    __hip_bfloat16* Wb_o2  = Wb_o1 + DCH * DCH;
    __hip_bfloat16* Wb_o3  = Wb_o2 + DCH * DCH;

    const int WSQ = DCH * DCH;
    const int WTR = 3 * DCH * 3 * DCH;
    cvt_bf16<<<WSQ / 1024, 256, 0, stream>>>(W_in1, Wb_in1, WSQ);
    cvt_bf16<<<WSQ / 1024, 256, 0, stream>>>(W_in2, Wb_in2, WSQ);
    cvt_bf16<<<WSQ / 1024, 256, 0, stream>>>(W_in3, Wb_in3, WSQ);
    cvt_bf16<<<WTR / 1024, 256, 0, stream>>>(W_tr,  Wb_tr,  WTR);
    cvt_bf16<<<WSQ / 1024, 256, 0, stream>>>(W_o1,  Wb_o1,  WSQ);
    cvt_bf16<<<WSQ / 1024, 256, 0, stream>>>(W_o2,  Wb_o2,  WSQ);
    cvt_bf16<<<WSQ / 1024, 256, 0, stream>>>(W_o3,  Wb_o3,  WSQ);

    stage_transpose<<<dim3(16, 8, 96), 256, 0, stream>>>(out0, out1, out2,
                                                         gamma0, gamma1, gamma2, buf0);

    const int NTILE = NPIX / 256;  // 128
    // GEMM-A: Hcat^T[n][i*512+o] = XbT_i x W_in_i (K=512)
    {
        const __hip_bfloat16* Ws[3] = {Wb_in1, Wb_in2, Wb_in3};
        const float* bs[3] = {b_in1, b_in2, b_in3};
        for (int i = 0; i < 3; ++i) {
            gemm256<<<dim3(NTILE * 2), 512, 0, stream>>>(
                buf0 + (size_t)i * NPIX * DCH, DCH, Ws[i], DCH, bs[i],
                buf1, 3 * DCH, i * DCH, DCH, 2, 0);
        }
    }
    // GEMM-B: Htra^T = Hcat^T x W_trans (K=1536)
    gemm256<<<dim3(NTILE * 6), 512, 0, stream>>>(
        buf1, 3 * DCH, Wb_tr, 3 * DCH, b_tr,
        buf0, 3 * DCH, 0, 3 * DCH, 6, 0);

    // GEMM-C: G[i*512+o][n] = s_i^T x W_out_i (trans-out epilogue)
    {
        const __hip_bfloat16* Ws[3] = {Wb_o1, Wb_o2, Wb_o3};
        const float* bs[3] = {b_o1, b_o2, b_o3};
        for (int i = 0; i < 3; ++i) {
            gemm256<<<dim3(NTILE * 2), 512, 0, stream>>>(
                buf0 + i * DCH, 3 * DCH, Ws[i], DCH, bs[i],
                buf1, NPIX, i * DCH, DCH, 2, 1);
        }
    }

    final_fuse<<<dim3(NPIX / 256, DCH / 64), 256, 0, stream>>>(
        buf1, out0, out1, out2, gamma0, gamma1, gamma2, outp);
}

// Round 3
// 481.577 us; speedup vs baseline: 1.2615x; 1.0463x over previous
//
#include <hip/hip_runtime.h>
#include <hip/hip_bf16.h>

#define NPIX 32768
#define DCH 512
#define HWSZ 1024

typedef __bf16 bf16x8_t __attribute__((ext_vector_type(8)));
typedef float f32x4_t __attribute__((ext_vector_type(4)));
typedef unsigned short u16x8_t __attribute__((ext_vector_type(8)));
typedef unsigned short u16x4_t __attribute__((ext_vector_type(4)));

static __device__ __forceinline__ unsigned short f2bf(float f) {
    return __builtin_bit_cast(unsigned short, __float2bfloat16(f));
}

// ---------------------------------------------------------------------------
// Weight fp32 -> bf16 convert (tiny)
// ---------------------------------------------------------------------------
__global__ void cvt_bf16(const float* __restrict__ s, __hip_bfloat16* __restrict__ d, int n)
{
    int i = (blockIdx.x * 256 + threadIdx.x) * 4;
    if (i >= n) return;
    float4 f = *(const float4*)(s + i);
    u16x4_t v;
    v[0] = f2bf(f.x); v[1] = f2bf(f.y); v[2] = f2bf(f.z); v[3] = f2bf(f.w);
    *(u16x4_t*)((unsigned short*)d + i) = v;
}

// ---------------------------------------------------------------------------
// Stage: X[b][c][hw] fp32 -> XbT[branch][n][c] bf16 with gamma scale.
// ---------------------------------------------------------------------------
__global__ __launch_bounds__(256)
void stage_transpose(const float* __restrict__ x0, const float* __restrict__ x1,
                     const float* __restrict__ x2,
                     const float* __restrict__ gp0, const float* __restrict__ gp1,
                     const float* __restrict__ gp2,
                     __hip_bfloat16* __restrict__ XbT)
{
    __shared__ float tile[64][65];
    const int hw0 = blockIdx.x * 64;
    const int c0  = blockIdx.y * 64;
    const int bz  = blockIdx.z;
    const int br  = bz >> 5;
    const int b   = bz & 31;
    const float* x = (br == 0) ? x0 : ((br == 1) ? x1 : x2);
    const float g  = ((br == 0) ? gp0 : ((br == 1) ? gp1 : gp2))[0];
    const int t = threadIdx.x;

    const int hwi = t & 63;
    const int cb  = t >> 6;
    const float* src = x + (size_t)b * (DCH * HWSZ) + (size_t)c0 * HWSZ + hw0;
#pragma unroll
    for (int i = 0; i < 16; ++i) {
        const int ci = cb + i * 4;
        tile[ci][hwi] = g * src[(size_t)ci * HWSZ + hwi];
    }
    __syncthreads();

    const int hwr = t >> 2;
    const int cch = (t & 3) * 16;
    __hip_bfloat16* dst = XbT + (size_t)((size_t)br * NPIX + b * HWSZ + hw0 + hwr) * DCH + c0 + cch;
    u16x8_t v0, v1;
#pragma unroll
    for (int e = 0; e < 8; ++e) v0[e] = f2bf(tile[cch + e][hwr]);
#pragma unroll
    for (int e = 0; e < 8; ++e) v1[e] = f2bf(tile[cch + 8 + e][hwr]);
    *(u16x8_t*)dst = v0;
    *((u16x8_t*)dst + 1) = v1;
}

// ---------------------------------------------------------------------------
// 256x256 pipelined 4-phase NT GEMM: C^T[n][o] = sum_k A[n][k]*B[o][k]+bias
// 8 waves (2M x 4N), per-wave 128x64. BK=64, 2-tile LDS dbuf, T2 swizzle.
// ds_reads issued ONE PHASE AHEAD (latency hides under MFMA cluster);
// asm ds_read_b128; vmcnt(4) tile-landing guarantee at P2 (pre-barrier);
// stages into dead regions only (B@P2, A@P3). 4 barriers/K-tile.
// ---------------------------------------------------------------------------
__global__ __launch_bounds__(512, 2)
void gemm256(const __hip_bfloat16* __restrict__ A, int lda,
             const __hip_bfloat16* __restrict__ B, int ldb,
             const float* __restrict__ bias,
             __hip_bfloat16* __restrict__ C, int ldc, int coff,
             int K, int NO, int trans_out)
{
    __shared__ __align__(16) unsigned char smem[131072];
    const int tid  = threadIdx.x;
    const int lane = tid & 63;
    const int wave = tid >> 6;
    const int wm   = wave >> 2;    // 0..1
    const int wn   = wave & 3;     // 0..3
    const int l16  = lane & 15;
    const int l4   = lane >> 4;

    // XCD swizzle: n-outer / o-inner per XCD chunk (grid % 8 == 0)
    const int per   = gridDim.x >> 3;
    const int xcd   = blockIdx.x & 7;
    const int j     = blockIdx.x >> 3;
    const int ntile = xcd * (per / NO) + j / NO;
    const int otile = j % NO;
    const int n0 = ntile * 256;
    const int o0 = otile * 256;
    const int NT = K >> 6;

    // read-side swizzled base addresses (byte offsets in LDS)
    const unsigned xorv = (unsigned)((l16 & 7) << 4);
    unsigned baseA[2], baseB[2];
#pragma unroll
    for (int kk = 0; kk < 2; ++kk) {
        const unsigned ko = ((unsigned)(kk * 64 + l4 * 16)) ^ xorv;
        baseA[kk] = (unsigned)((wm * 128 + l16) * 128) + ko;
        baseB[kk] = 32768u + (unsigned)((wn * 64 + l16) * 128) + ko;
    }

    // staging: per lane, inverse-swizzled global source
    const int rr  = lane >> 3;
    const int kel = 8 * ((lane & 7) ^ rr);

    auto stageA = [&](int t, int half) {
        const unsigned dst = (unsigned)((t & 1) * 65536 + half * 16384 + wave * 2048);
        const __hip_bfloat16* g = A + (size_t)(n0 + half * 128 + wave * 16 + rr) * lda + t * 64 + kel;
#pragma unroll
        for (int s = 0; s < 2; ++s) {
            __builtin_amdgcn_global_load_lds(
                (const __attribute__((address_space(1))) unsigned int*)(g + (size_t)s * 8 * lda),
                (__attribute__((address_space(3))) unsigned int*)(smem + dst + s * 1024),
                16, 0, 0);
        }
    };
    auto stageB = [&](int t, int half) {
        const unsigned dst = (unsigned)((t & 1) * 65536 + 32768 + half * 16384 + wave * 2048);
        const __hip_bfloat16* g = B + (size_t)(o0 + half * 128 + wave * 16 + rr) * ldb + t * 64 + kel;
#pragma unroll
        for (int s = 0; s < 2; ++s) {
            __builtin_amdgcn_global_load_lds(
                (const __attribute__((address_space(1))) unsigned int*)(g + (size_t)s * 8 * ldb),
                (__attribute__((address_space(3))) unsigned int*)(smem + dst + s * 1024),
                16, 0, 0);
        }
    };

#define DSR(dst, a) asm volatile("ds_read_b128 %0, %1" : "=v"(dst) : "v"(a))
#define BC(x) __builtin_bit_cast(bf16x8_t, x)

    // prologue: stage tiles 0,1; wait tile 0 (own loads) + barrier (all waves)
    stageA(0, 0); stageA(0, 1); stageB(0, 0); stageB(0, 1);
    stageA(1, 0); stageA(1, 1); stageB(1, 0); stageB(1, 1);
    asm volatile("s_waitcnt vmcnt(8)");
    __builtin_amdgcn_s_barrier();

    f32x4_t aR[4][2], a2[4][2], bR[4][2];
    f32x4_t acc[8][4];
#pragma unroll
    for (int m = 0; m < 8; ++m)
#pragma unroll
        for (int n = 0; n < 4; ++n) acc[m][n] = (f32x4_t){0.f, 0.f, 0.f, 0.f};

    // Q0(t=0) reads: aR (8) + bR[0-1] (4), buffer 0
#pragma unroll
    for (int m = 0; m < 4; ++m)
#pragma unroll
        for (int kk = 0; kk < 2; ++kk)
            DSR(aR[m][kk], baseA[kk] + (unsigned)(m * 2048));
#pragma unroll
    for (int n = 0; n < 2; ++n)
#pragma unroll
        for (int kk = 0; kk < 2; ++kk)
            DSR(bR[n][kk], baseB[kk] + (unsigned)(n * 2048));

    unsigned cb = 0;
    for (int t = 0; t < NT; ++t) {
        const unsigned cbn = cb ^ 65536u;

        // ---- P0: wait Q0 data; MFMA (m0-3 x n0-1); issue bR[2-3]
        asm volatile("s_waitcnt lgkmcnt(0)");
        __builtin_amdgcn_sched_barrier(0);
        __builtin_amdgcn_s_setprio(1);
#pragma unroll
        for (int m = 0; m < 4; ++m)
#pragma unroll
            for (int n = 0; n < 2; ++n)
#pragma unroll
                for (int kk = 0; kk < 2; ++kk)
                    acc[m][n] = __builtin_amdgcn_mfma_f32_16x16x32_bf16(BC(aR[m][kk]), BC(bR[n][kk]), acc[m][n], 0, 0, 0);
        __builtin_amdgcn_s_setprio(0);
#pragma unroll
        for (int n = 2; n < 4; ++n)
#pragma unroll
            for (int kk = 0; kk < 2; ++kk)
                DSR(bR[n][kk], cb + baseB[kk] + (unsigned)(n * 2048));
        __builtin_amdgcn_s_barrier();

        // ---- P1: wait bR[2-3]; MFMA (m0-3 x n2-3); issue a2 (m4-7)
        asm volatile("s_waitcnt lgkmcnt(0)");
        __builtin_amdgcn_sched_barrier(0);
        __builtin_amdgcn_s_setprio(1);
#pragma unroll
        for (int m = 0; m < 4; ++m)
#pragma unroll
            for (int n = 2; n < 4; ++n)
#pragma unroll
                for (int kk = 0; kk < 2; ++kk)
                    acc[m][n] = __builtin_amdgcn_mfma_f32_16x16x32_bf16(BC(aR[m][kk]), BC(bR[n][kk]), acc[m][n], 0, 0, 0);
        __builtin_amdgcn_s_setprio(0);
#pragma unroll
        for (int m = 0; m < 4; ++m)
#pragma unroll
            for (int kk = 0; kk < 2; ++kk)
                DSR(a2[m][kk], cb + baseA[kk] + (unsigned)((m + 4) * 2048));
        __builtin_amdgcn_s_barrier();

        // ---- P2: wait a2; MFMA (m4-7 x n0-1); stage B(t+2); vmcnt guarantee
        asm volatile("s_waitcnt lgkmcnt(0)");
        __builtin_amdgcn_sched_barrier(0);
        __builtin_amdgcn_s_setprio(1);
#pragma unroll
        for (int m = 0; m < 4; ++m)
#pragma unroll
            for (int n = 0; n < 2; ++n)
#pragma unroll
                for (int kk = 0; kk < 2; ++kk)
                    acc[m + 4][n] = __builtin_amdgcn_mfma_f32_16x16x32_bf16(BC(a2[m][kk]), BC(bR[n][kk]), acc[m + 4][n], 0, 0, 0);
        __builtin_amdgcn_s_setprio(0);
        if (t + 2 < NT) {
            stageB(t + 2, 0); stageB(t + 2, 1);
            asm volatile("s_waitcnt vmcnt(4)");   // tile t+1 fully landed
        } else if (t + 2 == NT) {
            asm volatile("s_waitcnt vmcnt(0)");
        }
        __builtin_amdgcn_s_barrier();

        // ---- P3: MFMA (m4-7 x n2-3); issue next-tile Q0 reads; stage A(t+2)
        __builtin_amdgcn_s_setprio(1);
#pragma unroll
        for (int m = 0; m < 4; ++m)
#pragma unroll
            for (int n = 2; n < 4; ++n)
#pragma unroll
                for (int kk = 0; kk < 2; ++kk)
                    acc[m + 4][n] = __builtin_amdgcn_mfma_f32_16x16x32_bf16(BC(a2[m][kk]), BC(bR[n][kk]), acc[m + 4][n], 0, 0, 0);
        __builtin_amdgcn_s_setprio(0);
        if (t + 1 < NT) {
#pragma unroll
            for (int m = 0; m < 4; ++m)
#pragma unroll
                for (int kk = 0; kk < 2; ++kk)
                    DSR(aR[m][kk], cbn + baseA[kk] + (unsigned)(m * 2048));
#pragma unroll
            for (int n = 0; n < 2; ++n)
#pragma unroll
                for (int kk = 0; kk < 2; ++kk)
                    DSR(bR[n][kk], cbn + baseB[kk] + (unsigned)(n * 2048));
        }
        if (t + 2 < NT) { stageA(t + 2, 0); stageA(t + 2, 1); }
        __builtin_amdgcn_s_barrier();
        cb = cbn;
    }

    if (!trans_out) {
#pragma unroll
        for (int n = 0; n < 4; ++n) {
            const int oc = o0 + wn * 64 + n * 16 + l16;
            const float bv = bias[oc];
#pragma unroll
            for (int m = 0; m < 8; ++m)
#pragma unroll
                for (int r = 0; r < 4; ++r) {
                    const int nr = n0 + wm * 128 + m * 16 + l4 * 4 + r;
                    C[(size_t)nr * ldc + coff + oc] = __float2bfloat16(acc[m][n][r] + bv);
                }
        }
    } else {
        // channel-major output: transpose 256x256 tile through smem (swizzled)
#pragma unroll
        for (int n = 0; n < 4; ++n) {
            const int ocl = wn * 64 + n * 16 + l16;
            const float bv = bias[o0 + ocl];
#pragma unroll
            for (int m = 0; m < 8; ++m)
#pragma unroll
                for (int r = 0; r < 4; ++r) {
                    const int nrow = wm * 128 + m * 16 + l4 * 4 + r;
                    const unsigned phys = (unsigned)nrow * 512u
                        + (((unsigned)ocl * 2u) ^ (((unsigned)(nrow & 7)) << 4));
                    *(unsigned short*)(smem + phys) =
                        __builtin_bit_cast(unsigned short, __float2bfloat16(acc[m][n][r] + bv));
                }
        }
        __syncthreads();
        const int ol = tid >> 1;
        const int nh = (tid & 1) * 128;
        __hip_bfloat16* dst = C + (size_t)(coff + o0 + ol) * ldc + n0 + nh;
#pragma unroll
        for (int j8 = 0; j8 < 16; ++j8) {
            u16x8_t v;
#pragma unroll
            for (int e = 0; e < 8; ++e) {
                const int n2 = nh + j8 * 8 + e;
                v[e] = *(const unsigned short*)(smem + (unsigned)n2 * 512u
                        + ((((unsigned)ol * 2u) ^ ((unsigned)e << 4))));
            }
            *(u16x8_t*)((unsigned short*)dst + j8 * 8) = v;
        }
    }
#undef DSR
#undef BC
}

// ---------------------------------------------------------------------------
// Final: g_i = sigmoid(S_i), w = softmax(g), out = sum w_i * gamma_i * x_i
// ---------------------------------------------------------------------------
__global__ __launch_bounds__(256)
void final_fuse(const __hip_bfloat16* __restrict__ G,
                const float* __restrict__ x0, const float* __restrict__ x1,
                const float* __restrict__ x2,
                const float* __restrict__ gp0, const float* __restrict__ gp1,
                const float* __restrict__ gp2,
                float* __restrict__ out)
{
    const int n  = blockIdx.x * 256 + threadIdx.x;
    const int b  = n >> 10;
    const int hw = n & (HWSZ - 1);
    const int c0 = blockIdx.y * 64;
    const float ga0 = gp0[0], ga1 = gp1[0], ga2 = gp2[0];
    for (int cc = 0; cc < 64; ++cc) {
        const int c = c0 + cc;
        const float s0 = __bfloat162float(G[(size_t)c * NPIX + n]);
        const float s1 = __bfloat162float(G[(size_t)(c + DCH) * NPIX + n]);
        const float s2 = __bfloat162float(G[(size_t)(c + 2 * DCH) * NPIX + n]);
        const float g0v = 1.0f / (1.0f + __expf(-s0));
        const float g1v = 1.0f / (1.0f + __expf(-s1));
        const float g2v = 1.0f / (1.0f + __expf(-s2));
        const float e0 = __expf(g0v), e1 = __expf(g1v), e2 = __expf(g2v);
        const float inv = 1.0f / (e0 + e1 + e2);
        const size_t xo = (size_t)b * (DCH * HWSZ) + (size_t)c * HWSZ + hw;
        out[xo] = inv * (e0 * ga0 * x0[xo] + e1 * ga1 * x1[xo] + e2 * ga2 * x2[xo]);
    }
}

// ---------------------------------------------------------------------------
extern "C" void kernel_launch(void* const* d_in, const int* in_sizes, int n_in,
                              void* d_out, int out_size, void* d_ws, size_t ws_size,
                              hipStream_t stream)
{
    const float* out0   = (const float*)d_in[0];
    const float* out1   = (const float*)d_in[1];
    const float* out2   = (const float*)d_in[2];
    const float* gamma0 = (const float*)d_in[3];
    const float* gamma1 = (const float*)d_in[4];
    const float* gamma2 = (const float*)d_in[5];
    const float* W_in1  = (const float*)d_in[6];
    const float* b_in1  = (const float*)d_in[7];
    const float* W_in2  = (const float*)d_in[8];
    const float* b_in2  = (const float*)d_in[9];
    const float* W_in3  = (const float*)d_in[10];
    const float* b_in3  = (const float*)d_in[11];
    const float* W_tr   = (const float*)d_in[12];
    const float* b_tr   = (const float*)d_in[13];
    const float* W_o1   = (const float*)d_in[14];
    const float* b_o1   = (const float*)d_in[15];
    const float* W_o2   = (const float*)d_in[16];
    const float* b_o2   = (const float*)d_in[17];
    const float* W_o3   = (const float*)d_in[18];
    const float* b_o3   = (const float*)d_in[19];
    float* outp = (float*)d_out;

    unsigned char* ws = (unsigned char*)d_ws;
    const size_t SZ_ACT = (size_t)3 * NPIX * DCH * 2;
    __hip_bfloat16* buf0 = (__hip_bfloat16*)ws;
    __hip_bfloat16* buf1 = (__hip_bfloat16*)(ws + SZ_ACT);
    __hip_bfloat16* Wb     = (__hip_bfloat16*)(ws + 2 * SZ_ACT);
    __hip_bfloat16* Wb_in1 = Wb;
    __hip_bfloat16* Wb_in2 = Wb_in1 + DCH * DCH;
    __hip_bfloat16* Wb_in3 = Wb_in2 + DCH * DCH;
    __hip_bfloat16* Wb_tr  = Wb_in3 + DCH * DCH;
    __hip_bfloat16* Wb_o1  = Wb_tr + 3 * DCH * 3 * DCH;
    __hip_bfloat16* Wb_o2  = Wb_o1 + DCH * DCH;
    __hip_bfloat16* Wb_o3  = Wb_o2 + DCH * DCH;

    const int WSQ = DCH * DCH;
    const int WTR = 3 * DCH * 3 * DCH;
    cvt_bf16<<<WSQ / 1024, 256, 0, stream>>>(W_in1, Wb_in1, WSQ);
    cvt_bf16<<<WSQ / 1024, 256, 0, stream>>>(W_in2, Wb_in2, WSQ);
    cvt_bf16<<<WSQ / 1024, 256, 0, stream>>>(W_in3, Wb_in3, WSQ);
    cvt_bf16<<<WTR / 1024, 256, 0, stream>>>(W_tr,  Wb_tr,  WTR);
    cvt_bf16<<<WSQ / 1024, 256, 0, stream>>>(W_o1,  Wb_o1,  WSQ);
    cvt_bf16<<<WSQ / 1024, 256, 0, stream>>>(W_o2,  Wb_o2,  WSQ);
    cvt_bf16<<<WSQ / 1024, 256, 0, stream>>>(W_o3,  Wb_o3,  WSQ);

    stage_transpose<<<dim3(16, 8, 96), 256, 0, stream>>>(out0, out1, out2,
                                                         gamma0, gamma1, gamma2, buf0);

    const int NTILE = NPIX / 256;  // 128
    // GEMM-A: Hcat^T[n][i*512+o] = XbT_i x W_in_i (K=512)
    {
        const __hip_bfloat16* Ws[3] = {Wb_in1, Wb_in2, Wb_in3};
        const float* bs[3] = {b_in1, b_in2, b_in3};
        for (int i = 0; i < 3; ++i) {
            gemm256<<<dim3(NTILE * 2), 512, 0, stream>>>(
                buf0 + (size_t)i * NPIX * DCH, DCH, Ws[i], DCH, bs[i],
                buf1, 3 * DCH, i * DCH, DCH, 2, 0);
        }
    }
    // GEMM-B: Htra^T = Hcat^T x W_trans (K=1536)
    gemm256<<<dim3(NTILE * 6), 512, 0, stream>>>(
        buf1, 3 * DCH, Wb_tr, 3 * DCH, b_tr,
        buf0, 3 * DCH, 0, 3 * DCH, 6, 0);

    // GEMM-C: G[i*512+o][n] = s_i^T x W_out_i (trans-out epilogue)
    {
        const __hip_bfloat16* Ws[3] = {Wb_o1, Wb_o2, Wb_o3};
        const float* bs[3] = {b_o1, b_o2, b_o3};
        for (int i = 0; i < 3; ++i) {
            gemm256<<<dim3(NTILE * 2), 512, 0, stream>>>(
                buf0 + i * DCH, 3 * DCH, Ws[i], DCH, bs[i],
                buf1, NPIX, i * DCH, DCH, 2, 1);
        }
    }

    final_fuse<<<dim3(NPIX / 256, DCH / 64), 256, 0, stream>>>(
        buf1, out0, out1, out2, gamma0, gamma1, gamma2, outp);
}

// Round 4
// 476.589 us; speedup vs baseline: 1.2747x; 1.0105x over previous
//
#include <hip/hip_runtime.h>
#include <hip/hip_bf16.h>

#define NPIX 32768
#define DCH 512
#define HWSZ 1024

typedef __bf16 bf16x8_t __attribute__((ext_vector_type(8)));
typedef float f32x4_t __attribute__((ext_vector_type(4)));
typedef unsigned short u16x8_t __attribute__((ext_vector_type(8)));
typedef unsigned short u16x4_t __attribute__((ext_vector_type(4)));

static __device__ __forceinline__ unsigned short f2bf(float f) {
    return __builtin_bit_cast(unsigned short, __float2bfloat16(f));
}

// ---------------------------------------------------------------------------
// Weight fp32 -> bf16 convert (tiny)
// ---------------------------------------------------------------------------
__global__ void cvt_bf16(const float* __restrict__ s, __hip_bfloat16* __restrict__ d, int n)
{
    int i = (blockIdx.x * 256 + threadIdx.x) * 4;
    if (i >= n) return;
    float4 f = *(const float4*)(s + i);
    u16x4_t v;
    v[0] = f2bf(f.x); v[1] = f2bf(f.y); v[2] = f2bf(f.z); v[3] = f2bf(f.w);
    *(u16x4_t*)((unsigned short*)d + i) = v;
}

// ---------------------------------------------------------------------------
// Stage: X[b][c][hw] fp32 -> XbT[branch][n][c] bf16 with gamma scale.
// ---------------------------------------------------------------------------
__global__ __launch_bounds__(256)
void stage_transpose(const float* __restrict__ x0, const float* __restrict__ x1,
                     const float* __restrict__ x2,
                     const float* __restrict__ gp0, const float* __restrict__ gp1,
                     const float* __restrict__ gp2,
                     __hip_bfloat16* __restrict__ XbT)
{
    __shared__ float tile[64][65];
    const int hw0 = blockIdx.x * 64;
    const int c0  = blockIdx.y * 64;
    const int bz  = blockIdx.z;
    const int br  = bz >> 5;
    const int b   = bz & 31;
    const float* x = (br == 0) ? x0 : ((br == 1) ? x1 : x2);
    const float g  = ((br == 0) ? gp0 : ((br == 1) ? gp1 : gp2))[0];
    const int t = threadIdx.x;

    const int hwi = t & 63;
    const int cb  = t >> 6;
    const float* src = x + (size_t)b * (DCH * HWSZ) + (size_t)c0 * HWSZ + hw0;
#pragma unroll
    for (int i = 0; i < 16; ++i) {
        const int ci = cb + i * 4;
        tile[ci][hwi] = g * src[(size_t)ci * HWSZ + hwi];
    }
    __syncthreads();

    const int hwr = t >> 2;
    const int cch = (t & 3) * 16;
    __hip_bfloat16* dst = XbT + (size_t)((size_t)br * NPIX + b * HWSZ + hw0 + hwr) * DCH + c0 + cch;
    u16x8_t v0, v1;
#pragma unroll
    for (int e = 0; e < 8; ++e) v0[e] = f2bf(tile[cch + e][hwr]);
#pragma unroll
    for (int e = 0; e < 8; ++e) v1[e] = f2bf(tile[cch + 8 + e][hwr]);
    *(u16x8_t*)dst = v0;
    *((u16x8_t*)dst + 1) = v1;
}

// ---------------------------------------------------------------------------
// 256x256 deep-pipelined NT GEMM: C^T[n][o] = sum_k A[n][k]*B[o][k]+bias
// 8 waves (2M x 4N), per-wave 128x64. BK=64, 2-tile LDS dbuf, T2 swizzle.
// Every phase's ds_reads are issued at the TOP of the PREVIOUS phase
// (before its MFMA cluster), so read latency hides under MFMA issue:
//   P0: wait(aR,bA) issue bB   | MFMA m0-3 x n0-1 | barrier
//   P1: wait(bB)    issue a2   | MFMA m0-3 x n2-3 | barrier
//   P2: wait(a2)    stageB t+2 | MFMA m4-7 x n0-1 | vmcnt(4) barrier
//   P3: issue aR,bA(t+1) stageA t+2 | MFMA m4-7 x n2-3 | (no barrier)
// Immediate-offset ds_read_b128 (4 addr adds per tile).
// ---------------------------------------------------------------------------
__global__ __launch_bounds__(512, 2)
void gemm256(const __hip_bfloat16* __restrict__ A, int lda,
             const __hip_bfloat16* __restrict__ B, int ldb,
             const float* __restrict__ bias,
             __hip_bfloat16* __restrict__ C, int ldc, int coff,
             int K, int NO, int trans_out)
{
    __shared__ __align__(16) unsigned char smem[131072];
    const int tid  = threadIdx.x;
    const int lane = tid & 63;
    const int wave = tid >> 6;
    const int wm   = wave >> 2;    // 0..1
    const int wn   = wave & 3;     // 0..3
    const int l16  = lane & 15;
    const int l4   = lane >> 4;

    // XCD swizzle: n-outer / o-inner per XCD chunk (grid % 8 == 0)
    const int per   = gridDim.x >> 3;
    const int xcd   = blockIdx.x & 7;
    const int j     = blockIdx.x >> 3;
    const int ntile = xcd * (per / NO) + j / NO;
    const int otile = j % NO;
    const int n0 = ntile * 256;
    const int o0 = otile * 256;
    const int NT = K >> 6;

    // read-side swizzled base addresses (byte offsets in LDS)
    const unsigned xorv = (unsigned)((l16 & 7) << 4);
    unsigned baseA[2], baseB[2];
#pragma unroll
    for (int kk = 0; kk < 2; ++kk) {
        const unsigned ko = ((unsigned)(kk * 64 + l4 * 16)) ^ xorv;
        baseA[kk] = (unsigned)((wm * 128 + l16) * 128) + ko;
        baseB[kk] = 32768u + (unsigned)((wn * 64 + l16) * 128) + ko;
    }

    // staging: per lane, inverse-swizzled global source
    const int rr  = lane >> 3;
    const int kel = 8 * ((lane & 7) ^ rr);

    auto stageA = [&](int t, int half) {
        const unsigned dst = (unsigned)((t & 1) * 65536 + half * 16384 + wave * 2048);
        const __hip_bfloat16* g = A + (size_t)(n0 + half * 128 + wave * 16 + rr) * lda + t * 64 + kel;
#pragma unroll
        for (int s = 0; s < 2; ++s) {
            __builtin_amdgcn_global_load_lds(
                (const __attribute__((address_space(1))) unsigned int*)(g + (size_t)s * 8 * lda),
                (__attribute__((address_space(3))) unsigned int*)(smem + dst + s * 1024),
                16, 0, 0);
        }
    };
    auto stageB = [&](int t, int half) {
        const unsigned dst = (unsigned)((t & 1) * 65536 + 32768 + half * 16384 + wave * 2048);
        const __hip_bfloat16* g = B + (size_t)(o0 + half * 128 + wave * 16 + rr) * ldb + t * 64 + kel;
#pragma unroll
        for (int s = 0; s < 2; ++s) {
            __builtin_amdgcn_global_load_lds(
                (const __attribute__((address_space(1))) unsigned int*)(g + (size_t)s * 8 * ldb),
                (__attribute__((address_space(3))) unsigned int*)(smem + dst + s * 1024),
                16, 0, 0);
        }
    };

// immediate-offset ds_read_b128: OFF must be a literal token
#define DSRO(dst, addr, OFF) \
    asm volatile("ds_read_b128 %0, %1 offset:" #OFF : "=v"(dst) : "v"(addr))
#define BC(x) __builtin_bit_cast(bf16x8_t, x)

    // prologue: stage tiles 0,1; wait tile 0; issue aR(0)+bA(0)
    stageA(0, 0); stageA(0, 1); stageB(0, 0); stageB(0, 1);
    stageA(1, 0); stageA(1, 1); stageB(1, 0); stageB(1, 1);
    asm volatile("s_waitcnt vmcnt(8)");
    __builtin_amdgcn_s_barrier();

    f32x4_t aR[4][2], a2[4][2], bA[2][2], bB[2][2];
    f32x4_t acc[8][4];
#pragma unroll
    for (int m = 0; m < 8; ++m)
#pragma unroll
        for (int n = 0; n < 4; ++n) acc[m][n] = (f32x4_t){0.f, 0.f, 0.f, 0.f};

    {
        unsigned a0 = baseA[0], a1 = baseA[1], b0 = baseB[0], b1 = baseB[1];
        DSRO(aR[0][0], a0, 0);    DSRO(aR[1][0], a0, 2048);
        DSRO(aR[2][0], a0, 4096); DSRO(aR[3][0], a0, 6144);
        DSRO(aR[0][1], a1, 0);    DSRO(aR[1][1], a1, 2048);
        DSRO(aR[2][1], a1, 4096); DSRO(aR[3][1], a1, 6144);
        DSRO(bA[0][0], b0, 0);    DSRO(bA[1][0], b0, 2048);
        DSRO(bA[0][1], b1, 0);    DSRO(bA[1][1], b1, 2048);
    }

    unsigned cb = 0;
    for (int t = 0; t < NT; ++t) {
        const unsigned cbn = cb ^ 65536u;
        const unsigned a0 = cb + baseA[0], a1 = cb + baseA[1];
        const unsigned b0 = cb + baseB[0], b1 = cb + baseB[1];

        // ---- P0: wait aR,bA; issue bB; MFMA m0-3 x n0-1
        asm volatile("s_waitcnt lgkmcnt(0)");
        __builtin_amdgcn_sched_barrier(0);
        DSRO(bB[0][0], b0, 4096); DSRO(bB[1][0], b0, 6144);
        DSRO(bB[0][1], b1, 4096); DSRO(bB[1][1], b1, 6144);
        __builtin_amdgcn_sched_barrier(0);
        __builtin_amdgcn_s_setprio(1);
#pragma unroll
        for (int m = 0; m < 4; ++m)
#pragma unroll
            for (int n = 0; n < 2; ++n)
#pragma unroll
                for (int kk = 0; kk < 2; ++kk)
                    acc[m][n] = __builtin_amdgcn_mfma_f32_16x16x32_bf16(BC(aR[m][kk]), BC(bA[n][kk]), acc[m][n], 0, 0, 0);
        __builtin_amdgcn_s_setprio(0);
        __builtin_amdgcn_s_barrier();

        // ---- P1: wait bB; issue a2; MFMA m0-3 x n2-3
        asm volatile("s_waitcnt lgkmcnt(0)");
        __builtin_amdgcn_sched_barrier(0);
        DSRO(a2[0][0], a0, 8192);  DSRO(a2[1][0], a0, 10240);
        DSRO(a2[2][0], a0, 12288); DSRO(a2[3][0], a0, 14336);
        DSRO(a2[0][1], a1, 8192);  DSRO(a2[1][1], a1, 10240);
        DSRO(a2[2][1], a1, 12288); DSRO(a2[3][1], a1, 14336);
        __builtin_amdgcn_sched_barrier(0);
        __builtin_amdgcn_s_setprio(1);
#pragma unroll
        for (int m = 0; m < 4; ++m)
#pragma unroll
            for (int n = 0; n < 2; ++n)
#pragma unroll
                for (int kk = 0; kk < 2; ++kk)
                    acc[m][n + 2] = __builtin_amdgcn_mfma_f32_16x16x32_bf16(BC(aR[m][kk]), BC(bB[n][kk]), acc[m][n + 2], 0, 0, 0);
        __builtin_amdgcn_s_setprio(0);
        __builtin_amdgcn_s_barrier();

        // ---- P2: wait a2; stage B(t+2); MFMA m4-7 x n0-1; vmcnt(t+1 landed)
        asm volatile("s_waitcnt lgkmcnt(0)");
        __builtin_amdgcn_sched_barrier(0);
        if (t + 2 < NT) { stageB(t + 2, 0); stageB(t + 2, 1); }
        __builtin_amdgcn_sched_barrier(0);
        __builtin_amdgcn_s_setprio(1);
#pragma unroll
        for (int m = 0; m < 4; ++m)
#pragma unroll
            for (int n = 0; n < 2; ++n)
#pragma unroll
                for (int kk = 0; kk < 2; ++kk)
                    acc[m + 4][n] = __builtin_amdgcn_mfma_f32_16x16x32_bf16(BC(a2[m][kk]), BC(bA[n][kk]), acc[m + 4][n], 0, 0, 0);
        __builtin_amdgcn_s_setprio(0);
        if (t + 2 < NT)        { asm volatile("s_waitcnt vmcnt(4)"); }
        else if (t + 2 == NT)  { asm volatile("s_waitcnt vmcnt(0)"); }
        __builtin_amdgcn_s_barrier();

        // ---- P3: issue aR,bA(t+1); stage A(t+2); MFMA m4-7 x n2-3
        if (t + 1 < NT) {
            const unsigned na0 = cbn + baseA[0], na1 = cbn + baseA[1];
            const unsigned nb0 = cbn + baseB[0], nb1 = cbn + baseB[1];
            DSRO(aR[0][0], na0, 0);    DSRO(aR[1][0], na0, 2048);
            DSRO(aR[2][0], na0, 4096); DSRO(aR[3][0], na0, 6144);
            DSRO(aR[0][1], na1, 0);    DSRO(aR[1][1], na1, 2048);
            DSRO(aR[2][1], na1, 4096); DSRO(aR[3][1], na1, 6144);
            DSRO(bA[0][0], nb0, 0);    DSRO(bA[1][0], nb0, 2048);
            DSRO(bA[0][1], nb1, 0);    DSRO(bA[1][1], nb1, 2048);
        }
        if (t + 2 < NT) { stageA(t + 2, 0); stageA(t + 2, 1); }
        __builtin_amdgcn_sched_barrier(0);
        __builtin_amdgcn_s_setprio(1);
#pragma unroll
        for (int m = 0; m < 4; ++m)
#pragma unroll
            for (int n = 0; n < 2; ++n)
#pragma unroll
                for (int kk = 0; kk < 2; ++kk)
                    acc[m + 4][n + 2] = __builtin_amdgcn_mfma_f32_16x16x32_bf16(BC(a2[m][kk]), BC(bB[n][kk]), acc[m + 4][n + 2], 0, 0, 0);
        __builtin_amdgcn_s_setprio(0);
        // no barrier: cross-wave WAR/RAW covered by P0-P2 waits+barriers
        cb = cbn;
    }

    if (!trans_out) {
#pragma unroll
        for (int n = 0; n < 4; ++n) {
            const int oc = o0 + wn * 64 + n * 16 + l16;
            const float bv = bias[oc];
#pragma unroll
            for (int m = 0; m < 8; ++m)
#pragma unroll
                for (int r = 0; r < 4; ++r) {
                    const int nr = n0 + wm * 128 + m * 16 + l4 * 4 + r;
                    C[(size_t)nr * ldc + coff + oc] = __float2bfloat16(acc[m][n][r] + bv);
                }
        }
    } else {
        // channel-major output: transpose 256x256 tile through smem (swizzled)
#pragma unroll
        for (int n = 0; n < 4; ++n) {
            const int ocl = wn * 64 + n * 16 + l16;
            const float bv = bias[o0 + ocl];
#pragma unroll
            for (int m = 0; m < 8; ++m)
#pragma unroll
                for (int r = 0; r < 4; ++r) {
                    const int nrow = wm * 128 + m * 16 + l4 * 4 + r;
                    const unsigned phys = (unsigned)nrow * 512u
                        + (((unsigned)ocl * 2u) ^ (((unsigned)(nrow & 7)) << 4));
                    *(unsigned short*)(smem + phys) =
                        __builtin_bit_cast(unsigned short, __float2bfloat16(acc[m][n][r] + bv));
                }
        }
        __syncthreads();
        const int ol = tid >> 1;
        const int nh = (tid & 1) * 128;
        __hip_bfloat16* dst = C + (size_t)(coff + o0 + ol) * ldc + n0 + nh;
#pragma unroll
        for (int j8 = 0; j8 < 16; ++j8) {
            u16x8_t v;
#pragma unroll
            for (int e = 0; e < 8; ++e) {
                const int n2 = nh + j8 * 8 + e;
                v[e] = *(const unsigned short*)(smem + (unsigned)n2 * 512u
                        + ((((unsigned)ol * 2u) ^ ((unsigned)e << 4))));
            }
            *(u16x8_t*)((unsigned short*)dst + j8 * 8) = v;
        }
    }
#undef DSRO
#undef BC
}

// ---------------------------------------------------------------------------
// Final: g_i = sigmoid(S_i), w = softmax(g), out = sum w_i * gamma_i * x_i
// ---------------------------------------------------------------------------
__global__ __launch_bounds__(256)
void final_fuse(const __hip_bfloat16* __restrict__ G,
                const float* __restrict__ x0, const float* __restrict__ x1,
                const float* __restrict__ x2,
                const float* __restrict__ gp0, const float* __restrict__ gp1,
                const float* __restrict__ gp2,
                float* __restrict__ out)
{
    const int n  = blockIdx.x * 256 + threadIdx.x;
    const int b  = n >> 10;
    const int hw = n & (HWSZ - 1);
    const int c0 = blockIdx.y * 64;
    const float ga0 = gp0[0], ga1 = gp1[0], ga2 = gp2[0];
    for (int cc = 0; cc < 64; ++cc) {
        const int c = c0 + cc;
        const float s0 = __bfloat162float(G[(size_t)c * NPIX + n]);
        const float s1 = __bfloat162float(G[(size_t)(c + DCH) * NPIX + n]);
        const float s2 = __bfloat162float(G[(size_t)(c + 2 * DCH) * NPIX + n]);
        const float g0v = 1.0f / (1.0f + __expf(-s0));
        const float g1v = 1.0f / (1.0f + __expf(-s1));
        const float g2v = 1.0f / (1.0f + __expf(-s2));
        const float e0 = __expf(g0v), e1 = __expf(g1v), e2 = __expf(g2v);
        const float inv = 1.0f / (e0 + e1 + e2);
        const size_t xo = (size_t)b * (DCH * HWSZ) + (size_t)c * HWSZ + hw;
        out[xo] = inv * (e0 * ga0 * x0[xo] + e1 * ga1 * x1[xo] + e2 * ga2 * x2[xo]);
    }
}

// ---------------------------------------------------------------------------
extern "C" void kernel_launch(void* const* d_in, const int* in_sizes, int n_in,
                              void* d_out, int out_size, void* d_ws, size_t ws_size,
                              hipStream_t stream)
{
    const float* out0   = (const float*)d_in[0];
    const float* out1   = (const float*)d_in[1];
    const float* out2   = (const float*)d_in[2];
    const float* gamma0 = (const float*)d_in[3];
    const float* gamma1 = (const float*)d_in[4];
    const float* gamma2 = (const float*)d_in[5];
    const float* W_in1  = (const float*)d_in[6];
    const float* b_in1  = (const float*)d_in[7];
    const float* W_in2  = (const float*)d_in[8];
    const float* b_in2  = (const float*)d_in[9];
    const float* W_in3  = (const float*)d_in[10];
    const float* b_in3  = (const float*)d_in[11];
    const float* W_tr   = (const float*)d_in[12];
    const float* b_tr   = (const float*)d_in[13];
    const float* W_o1   = (const float*)d_in[14];
    const float* b_o1   = (const float*)d_in[15];
    const float* W_o2   = (const float*)d_in[16];
    const float* b_o2   = (const float*)d_in[17];
    const float* W_o3   = (const float*)d_in[18];
    const float* b_o3   = (const float*)d_in[19];
    float* outp = (float*)d_out;

    unsigned char* ws = (unsigned char*)d_ws;
    const size_t SZ_ACT = (size_t)3 * NPIX * DCH * 2;
    __hip_bfloat16* buf0 = (__hip_bfloat16*)ws;
    __hip_bfloat16* buf1 = (__hip_bfloat16*)(ws + SZ_ACT);
    __hip_bfloat16* Wb     = (__hip_bfloat16*)(ws + 2 * SZ_ACT);
    __hip_bfloat16* Wb_in1 = Wb;
    __hip_bfloat16* Wb_in2 = Wb_in1 + DCH * DCH;
    __hip_bfloat16* Wb_in3 = Wb_in2 + DCH * DCH;
    __hip_bfloat16* Wb_tr  = Wb_in3 + DCH * DCH;
    __hip_bfloat16* Wb_o1  = Wb_tr + 3 * DCH * 3 * DCH;
    __hip_bfloat16* Wb_o2  = Wb_o1 + DCH * DCH;
    __hip_bfloat16* Wb_o3  = Wb_o2 + DCH * DCH;

    const int WSQ = DCH * DCH;
    const int WTR = 3 * DCH * 3 * DCH;
    cvt_bf16<<<WSQ / 1024, 256, 0, stream>>>(W_in1, Wb_in1, WSQ);
    cvt_bf16<<<WSQ / 1024, 256, 0, stream>>>(W_in2, Wb_in2, WSQ);
    cvt_bf16<<<WSQ / 1024, 256, 0, stream>>>(W_in3, Wb_in3, WSQ);
    cvt_bf16<<<WTR / 1024, 256, 0, stream>>>(W_tr,  Wb_tr,  WTR);
    cvt_bf16<<<WSQ / 1024, 256, 0, stream>>>(W_o1,  Wb_o1,  WSQ);
    cvt_bf16<<<WSQ / 1024, 256, 0, stream>>>(W_o2,  Wb_o2,  WSQ);
    cvt_bf16<<<WSQ / 1024, 256, 0, stream>>>(W_o3,  Wb_o3,  WSQ);

    stage_transpose<<<dim3(16, 8, 96), 256, 0, stream>>>(out0, out1, out2,
                                                         gamma0, gamma1, gamma2, buf0);

    const int NTILE = NPIX / 256;  // 128
    // GEMM-A: Hcat^T[n][i*512+o] = XbT_i x W_in_i (K=512)
    {
        const __hip_bfloat16* Ws[3] = {Wb_in1, Wb_in2, Wb_in3};
        const float* bs[3] = {b_in1, b_in2, b_in3};
        for (int i = 0; i < 3; ++i) {
            gemm256<<<dim3(NTILE * 2), 512, 0, stream>>>(
                buf0 + (size_t)i * NPIX * DCH, DCH, Ws[i], DCH, bs[i],
                buf1, 3 * DCH, i * DCH, DCH, 2, 0);
        }
    }
    // GEMM-B: Htra^T = Hcat^T x W_trans (K=1536)
    gemm256<<<dim3(NTILE * 6), 512, 0, stream>>>(
        buf1, 3 * DCH, Wb_tr, 3 * DCH, b_tr,
        buf0, 3 * DCH, 0, 3 * DCH, 6, 0);

    // GEMM-C: G[i*512+o][n] = s_i^T x W_out_i (trans-out epilogue)
    {
        const __hip_bfloat16* Ws[3] = {Wb_o1, Wb_o2, Wb_o3};
        const float* bs[3] = {b_o1, b_o2, b_o3};
        for (int i = 0; i < 3; ++i) {
            gemm256<<<dim3(NTILE * 2), 512, 0, stream>>>(
                buf0 + i * DCH, 3 * DCH, Ws[i], DCH, bs[i],
                buf1, NPIX, i * DCH, DCH, 2, 1);
        }
    }

    final_fuse<<<dim3(NPIX / 256, DCH / 64), 256, 0, stream>>>(
        buf1, out0, out1, out2, gamma0, gamma1, gamma2, outp);
}

// Round 6
// 465.479 us; speedup vs baseline: 1.3051x; 1.0239x over previous
//
#include <hip/hip_runtime.h>
#include <hip/hip_bf16.h>

#define NPIX 32768
#define DCH 512
#define HWSZ 1024
#define WSQ (DCH * DCH)
#define WTR (3 * DCH * 3 * DCH)

typedef __bf16 bf16x8_t __attribute__((ext_vector_type(8)));
typedef float f32x4_t __attribute__((ext_vector_type(4)));
typedef unsigned short u16x8_t __attribute__((ext_vector_type(8)));
typedef unsigned short u16x4_t __attribute__((ext_vector_type(4)));

static __device__ __forceinline__ unsigned short f2bf(float f) {
    return __builtin_bit_cast(unsigned short, __float2bfloat16(f));
}
static __device__ __forceinline__ float bf2f(unsigned short u) {
    unsigned v = (unsigned)u << 16;
    return __builtin_bit_cast(float, v);
}

// ---------------------------------------------------------------------------
// All-weights fp32 -> bf16 (single launch, region lookup by prefix)
// order: in1,in2,in3 (WSQ each), tr (WTR), o1,o2,o3 (WSQ each)
// ---------------------------------------------------------------------------
__global__ __launch_bounds__(256)
void cvt_all(const float* __restrict__ w0, const float* __restrict__ w1,
             const float* __restrict__ w2, const float* __restrict__ w3,
             const float* __restrict__ w4, const float* __restrict__ w5,
             const float* __restrict__ w6, __hip_bfloat16* __restrict__ d)
{
    const int i = (blockIdx.x * 256 + threadIdx.x) * 4;
    const int total = 6 * WSQ + WTR;
    if (i >= total) return;
    const float* src;
    int off;
    if (i < 3 * WSQ) {
        int r = i >> 18;  // /WSQ
        src = (r == 0) ? w0 : ((r == 1) ? w1 : w2);
        off = i - r * WSQ;
    } else if (i < 3 * WSQ + WTR) {
        src = w3; off = i - 3 * WSQ;
    } else {
        int j = i - 3 * WSQ - WTR;
        int r = j >> 18;
        src = (r == 0) ? w4 : ((r == 1) ? w5 : w6);
        off = j - r * WSQ;
    }
    float4 f = *(const float4*)(src + off);
    u16x4_t v;
    v[0] = f2bf(f.x); v[1] = f2bf(f.y); v[2] = f2bf(f.z); v[3] = f2bf(f.w);
    *(u16x4_t*)((unsigned short*)d + i) = v;
}

// contiguous bias copy: d[0..3072) = {bin1,bin2,bin3,bo1,bo2,bo3}
__global__ void copy_bias(const float* a0, const float* a1, const float* a2,
                          const float* a3, const float* a4, const float* a5,
                          float* d)
{
    int t = threadIdx.x;
    if (t < 512) {
        d[t] = a0[t]; d[512 + t] = a1[t]; d[1024 + t] = a2[t];
        d[1536 + t] = a3[t]; d[2048 + t] = a4[t]; d[2560 + t] = a5[t];
    }
}

// ---------------------------------------------------------------------------
// Stage: X[b][c][hw] fp32 -> XbT[branch][n][c] bf16 with gamma scale.
// ---------------------------------------------------------------------------
__global__ __launch_bounds__(256)
void stage_transpose(const float* __restrict__ x0, const float* __restrict__ x1,
                     const float* __restrict__ x2,
                     const float* __restrict__ gp0, const float* __restrict__ gp1,
                     const float* __restrict__ gp2,
                     __hip_bfloat16* __restrict__ XbT)
{
    __shared__ float tile[64][65];
    const int hw0 = blockIdx.x * 64;
    const int c0  = blockIdx.y * 64;
    const int bz  = blockIdx.z;
    const int br  = bz >> 5;
    const int b   = bz & 31;
    const float* x = (br == 0) ? x0 : ((br == 1) ? x1 : x2);
    const float g  = ((br == 0) ? gp0 : ((br == 1) ? gp1 : gp2))[0];
    const int t = threadIdx.x;

    const int hwi = t & 63;
    const int cb  = t >> 6;
    const float* src = x + (size_t)b * (DCH * HWSZ) + (size_t)c0 * HWSZ + hw0;
#pragma unroll
    for (int i = 0; i < 16; ++i) {
        const int ci = cb + i * 4;
        tile[ci][hwi] = g * src[(size_t)ci * HWSZ + hwi];
    }
    __syncthreads();

    const int hwr = t >> 2;
    const int cch = (t & 3) * 16;
    __hip_bfloat16* dst = XbT + (size_t)((size_t)br * NPIX + b * HWSZ + hw0 + hwr) * DCH + c0 + cch;
    u16x8_t v0, v1;
#pragma unroll
    for (int e = 0; e < 8; ++e) v0[e] = f2bf(tile[cch + e][hwr]);
#pragma unroll
    for (int e = 0; e < 8; ++e) v1[e] = f2bf(tile[cch + 8 + e][hwr]);
    *(u16x8_t*)dst = v0;
    *((u16x8_t*)dst + 1) = v1;
}

// ---------------------------------------------------------------------------
// 256x256 pipelined NT GEMM (R4 K-loop) + batched-branch decode +
// LDS-staged vectorized epilogues.
// ---------------------------------------------------------------------------
__global__ __launch_bounds__(512, 2)
void gemm256(const __hip_bfloat16* __restrict__ A, int lda,
             const __hip_bfloat16* __restrict__ B, int ldb,
             const float* __restrict__ bias,
             __hip_bfloat16* __restrict__ C, int ldc, int coff0,
             int K, int NO, int TPB, int brA, int brB, int bstride,
             int cstride, int trans_out)
{
    __shared__ __align__(16) unsigned char smem[131072];
    const int tid  = threadIdx.x;
    const int lane = tid & 63;
    const int wave = tid >> 6;
    const int wm   = wave >> 2;
    const int wn   = wave & 3;
    const int l16  = lane & 15;
    const int l4   = lane >> 4;

    // XCD swizzle on flat id, then batch decode (grid % 8 == 0)
    const int per  = gridDim.x >> 3;
    const int flat = (blockIdx.x & 7) * per + (blockIdx.x >> 3);
    const int br   = flat / TPB;
    const int rem  = flat - br * TPB;
    const int nt   = rem / NO;
    const int ot   = rem - nt * NO;
    const int n0 = nt * 256;
    const int o0 = ot * 256;
    const int NT = K >> 6;

    A    += (size_t)br * (size_t)brA;
    B    += (size_t)br * (size_t)brB;
    bias += br * bstride;
    const int coff = coff0 + br * cstride;

    // read-side swizzled base addresses
    const unsigned xorv = (unsigned)((l16 & 7) << 4);
    unsigned baseA[2], baseB[2];
#pragma unroll
    for (int kk = 0; kk < 2; ++kk) {
        const unsigned ko = ((unsigned)(kk * 64 + l4 * 16)) ^ xorv;
        baseA[kk] = (unsigned)((wm * 128 + l16) * 128) + ko;
        baseB[kk] = 32768u + (unsigned)((wn * 64 + l16) * 128) + ko;
    }

    const int rr  = lane >> 3;
    const int kel = 8 * ((lane & 7) ^ rr);

    auto stageA = [&](int t, int half) {
        const unsigned dst = (unsigned)((t & 1) * 65536 + half * 16384 + wave * 2048);
        const __hip_bfloat16* g = A + (size_t)(n0 + half * 128 + wave * 16 + rr) * lda + t * 64 + kel;
#pragma unroll
        for (int s = 0; s < 2; ++s) {
            __builtin_amdgcn_global_load_lds(
                (const __attribute__((address_space(1))) unsigned int*)(g + (size_t)s * 8 * lda),
                (__attribute__((address_space(3))) unsigned int*)(smem + dst + s * 1024),
                16, 0, 0);
        }
    };
    auto stageB = [&](int t, int half) {
        const unsigned dst = (unsigned)((t & 1) * 65536 + 32768 + half * 16384 + wave * 2048);
        const __hip_bfloat16* g = B + (size_t)(o0 + half * 128 + wave * 16 + rr) * ldb + t * 64 + kel;
#pragma unroll
        for (int s = 0; s < 2; ++s) {
            __builtin_amdgcn_global_load_lds(
                (const __attribute__((address_space(1))) unsigned int*)(g + (size_t)s * 8 * ldb),
                (__attribute__((address_space(3))) unsigned int*)(smem + dst + s * 1024),
                16, 0, 0);
        }
    };

#define DSRO(dst, addr, OFF) \
    asm volatile("ds_read_b128 %0, %1 offset:" #OFF : "=v"(dst) : "v"(addr))
#define BC(x) __builtin_bit_cast(bf16x8_t, x)

    stageA(0, 0); stageA(0, 1); stageB(0, 0); stageB(0, 1);
    stageA(1, 0); stageA(1, 1); stageB(1, 0); stageB(1, 1);
    asm volatile("s_waitcnt vmcnt(8)");
    __builtin_amdgcn_s_barrier();

    f32x4_t aR[4][2], a2[4][2], bA[2][2], bB[2][2];
    f32x4_t acc[8][4];
#pragma unroll
    for (int m = 0; m < 8; ++m)
#pragma unroll
        for (int n = 0; n < 4; ++n) acc[m][n] = (f32x4_t){0.f, 0.f, 0.f, 0.f};

    {
        unsigned a0 = baseA[0], a1 = baseA[1], b0 = baseB[0], b1 = baseB[1];
        DSRO(aR[0][0], a0, 0);    DSRO(aR[1][0], a0, 2048);
        DSRO(aR[2][0], a0, 4096); DSRO(aR[3][0], a0, 6144);
        DSRO(aR[0][1], a1, 0);    DSRO(aR[1][1], a1, 2048);
        DSRO(aR[2][1], a1, 4096); DSRO(aR[3][1], a1, 6144);
        DSRO(bA[0][0], b0, 0);    DSRO(bA[1][0], b0, 2048);
        DSRO(bA[0][1], b1, 0);    DSRO(bA[1][1], b1, 2048);
    }

    unsigned cb = 0;
    for (int t = 0; t < NT; ++t) {
        const unsigned cbn = cb ^ 65536u;
        const unsigned a0 = cb + baseA[0], a1 = cb + baseA[1];
        const unsigned b0 = cb + baseB[0], b1 = cb + baseB[1];

        // ---- P0
        asm volatile("s_waitcnt lgkmcnt(0)");
        __builtin_amdgcn_sched_barrier(0);
        DSRO(bB[0][0], b0, 4096); DSRO(bB[1][0], b0, 6144);
        DSRO(bB[0][1], b1, 4096); DSRO(bB[1][1], b1, 6144);
        __builtin_amdgcn_sched_barrier(0);
        __builtin_amdgcn_s_setprio(1);
#pragma unroll
        for (int m = 0; m < 4; ++m)
#pragma unroll
            for (int n = 0; n < 2; ++n)
#pragma unroll
                for (int kk = 0; kk < 2; ++kk)
                    acc[m][n] = __builtin_amdgcn_mfma_f32_16x16x32_bf16(BC(aR[m][kk]), BC(bA[n][kk]), acc[m][n], 0, 0, 0);
        __builtin_amdgcn_s_setprio(0);
        __builtin_amdgcn_s_barrier();

        // ---- P1
        asm volatile("s_waitcnt lgkmcnt(0)");
        __builtin_amdgcn_sched_barrier(0);
        DSRO(a2[0][0], a0, 8192);  DSRO(a2[1][0], a0, 10240);
        DSRO(a2[2][0], a0, 12288); DSRO(a2[3][0], a0, 14336);
        DSRO(a2[0][1], a1, 8192);  DSRO(a2[1][1], a1, 10240);
        DSRO(a2[2][1], a1, 12288); DSRO(a2[3][1], a1, 14336);
        __builtin_amdgcn_sched_barrier(0);
        __builtin_amdgcn_s_setprio(1);
#pragma unroll
        for (int m = 0; m < 4; ++m)
#pragma unroll
            for (int n = 0; n < 2; ++n)
#pragma unroll
                for (int kk = 0; kk < 2; ++kk)
                    acc[m][n + 2] = __builtin_amdgcn_mfma_f32_16x16x32_bf16(BC(aR[m][kk]), BC(bB[n][kk]), acc[m][n + 2], 0, 0, 0);
        __builtin_amdgcn_s_setprio(0);
        __builtin_amdgcn_s_barrier();

        // ---- P2
        asm volatile("s_waitcnt lgkmcnt(0)");
        __builtin_amdgcn_sched_barrier(0);
        if (t + 2 < NT) { stageB(t + 2, 0); stageB(t + 2, 1); }
        __builtin_amdgcn_sched_barrier(0);
        __builtin_amdgcn_s_setprio(1);
#pragma unroll
        for (int m = 0; m < 4; ++m)
#pragma unroll
            for (int n = 0; n < 2; ++n)
#pragma unroll
                for (int kk = 0; kk < 2; ++kk)
                    acc[m + 4][n] = __builtin_amdgcn_mfma_f32_16x16x32_bf16(BC(a2[m][kk]), BC(bA[n][kk]), acc[m + 4][n], 0, 0, 0);
        __builtin_amdgcn_s_setprio(0);
        if (t + 2 < NT)        { asm volatile("s_waitcnt vmcnt(4)"); }
        else if (t + 2 == NT)  { asm volatile("s_waitcnt vmcnt(0)"); }
        __builtin_amdgcn_s_barrier();

        // ---- P3
        if (t + 1 < NT) {
            const unsigned na0 = cbn + baseA[0], na1 = cbn + baseA[1];
            const unsigned nb0 = cbn + baseB[0], nb1 = cbn + baseB[1];
            DSRO(aR[0][0], na0, 0);    DSRO(aR[1][0], na0, 2048);
            DSRO(aR[2][0], na0, 4096); DSRO(aR[3][0], na0, 6144);
            DSRO(aR[0][1], na1, 0);    DSRO(aR[1][1], na1, 2048);
            DSRO(aR[2][1], na1, 4096); DSRO(aR[3][1], na1, 6144);
            DSRO(bA[0][0], nb0, 0);    DSRO(bA[1][0], nb0, 2048);
            DSRO(bA[0][1], nb1, 0);    DSRO(bA[1][1], nb1, 2048);
        }
        if (t + 2 < NT) { stageA(t + 2, 0); stageA(t + 2, 1); }
        __builtin_amdgcn_sched_barrier(0);
        __builtin_amdgcn_s_setprio(1);
#pragma unroll
        for (int m = 0; m < 4; ++m)
#pragma unroll
            for (int n = 0; n < 2; ++n)
#pragma unroll
                for (int kk = 0; kk < 2; ++kk)
                    acc[m + 4][n + 2] = __builtin_amdgcn_mfma_f32_16x16x32_bf16(BC(a2[m][kk]), BC(bB[n][kk]), acc[m + 4][n + 2], 0, 0, 0);
        __builtin_amdgcn_s_setprio(0);
        cb = cbn;
    }

    if (!trans_out) {
        // LDS-staged vectorized row writes
        __syncthreads();
#pragma unroll
        for (int n = 0; n < 4; ++n) {
            const int col = wn * 64 + n * 16 + l16;
            const float bv = bias[o0 + col];
#pragma unroll
            for (int m = 0; m < 8; ++m)
#pragma unroll
                for (int r = 0; r < 4; ++r) {
                    const int row = wm * 128 + m * 16 + l4 * 4 + r;
                    const unsigned byte = (unsigned)row * 512u
                        + (((unsigned)col * 2u) ^ (((unsigned)(row & 7)) << 4));
                    *(unsigned short*)(smem + byte) = f2bf(acc[m][n][r] + bv);
                }
        }
        __syncthreads();
        const int row  = tid >> 1;
        const int half = tid & 1;
        // R5 BUG WAS HERE: o0 was missing from dst
        __hip_bfloat16* dst = C + (size_t)(n0 + row) * ldc + coff + o0 + half * 128;
        const unsigned xr = ((unsigned)(row & 7)) << 4;
#pragma unroll
        for (int k = 0; k < 16; ++k) {
            const unsigned byteL = (unsigned)row * 512u + (((unsigned)(half * 256 + k * 16)) ^ xr);
            *(u16x8_t*)((unsigned short*)dst + k * 8) = *(const u16x8_t*)(smem + byteL);
        }
    } else {
        // channel-major output (fallback path only)
        __syncthreads();
#pragma unroll
        for (int n = 0; n < 4; ++n) {
            const int ocl = wn * 64 + n * 16 + l16;
            const float bv = bias[o0 + ocl];
#pragma unroll
            for (int m = 0; m < 8; ++m)
#pragma unroll
                for (int r = 0; r < 4; ++r) {
                    const int nrow = wm * 128 + m * 16 + l4 * 4 + r;
                    const unsigned phys = (unsigned)nrow * 512u
                        + (((unsigned)ocl * 2u) ^ (((unsigned)(nrow & 7)) << 4));
                    *(unsigned short*)(smem + phys) = f2bf(acc[m][n][r] + bv);
                }
        }
        __syncthreads();
        const int ol = tid >> 1;
        const int nh = (tid & 1) * 128;
        __hip_bfloat16* dst = C + (size_t)(coff + o0 + ol) * ldc + n0 + nh;
#pragma unroll
        for (int j8 = 0; j8 < 16; ++j8) {
            u16x8_t v;
#pragma unroll
            for (int e = 0; e < 8; ++e) {
                const int n2 = nh + j8 * 8 + e;
                v[e] = *(const unsigned short*)(smem + (unsigned)n2 * 512u
                        + ((((unsigned)ol * 2u) ^ ((unsigned)e << 4))));
            }
            *(u16x8_t*)((unsigned short*)dst + j8 * 8) = v;
        }
    }
#undef DSRO
#undef BC
}

// ---------------------------------------------------------------------------
// final_v2: G^T [NPIX][1536] n-major, Xb [3][NPIX][512] bf16 (= gamma_i x_i).
// ---------------------------------------------------------------------------
__global__ __launch_bounds__(256)
void final_v2(const __hip_bfloat16* __restrict__ G,
              const __hip_bfloat16* __restrict__ Xb,
              float* __restrict__ out)
{
    __shared__ float tile[64][68];
    const int n0  = blockIdx.x * 64;
    const int b   = n0 >> 10;
    const int hw0 = n0 & (HWSZ - 1);
    const int t   = threadIdx.x;
    const int nl  = t >> 2;
    const int cg  = (t & 3) * 16;
    const int n   = n0 + nl;
    const unsigned short* gr = (const unsigned short*)G + (size_t)n * 1536;
    const unsigned short* xr = (const unsigned short*)Xb + (size_t)n * 512;
    const int seg = t & 3;
    float* outb = out + (size_t)b * (DCH * HWSZ) + hw0;

    for (int c0 = 0; c0 < DCH; c0 += 64) {
        u16x8_t gl[3][2], xl[3][2];
#pragma unroll
        for (int i = 0; i < 3; ++i) {
            gl[i][0] = *(const u16x8_t*)(gr + i * 512 + c0 + cg);
            gl[i][1] = *(const u16x8_t*)(gr + i * 512 + c0 + cg + 8);
            xl[i][0] = *(const u16x8_t*)(xr + (size_t)i * NPIX * 512 + c0 + cg);
            xl[i][1] = *(const u16x8_t*)(xr + (size_t)i * NPIX * 512 + c0 + cg + 8);
        }
#pragma unroll
        for (int e = 0; e < 16; ++e) {
            const int h = e >> 3, w = e & 7;
            const float s0 = bf2f(gl[0][h][w]);
            const float s1 = bf2f(gl[1][h][w]);
            const float s2 = bf2f(gl[2][h][w]);
            const float g0 = 1.0f / (1.0f + __expf(-s0));
            const float g1 = 1.0f / (1.0f + __expf(-s1));
            const float g2 = 1.0f / (1.0f + __expf(-s2));
            const float e0 = __expf(g0), e1 = __expf(g1), e2 = __expf(g2);
            const float inv = 1.0f / (e0 + e1 + e2);
            tile[cg + e][nl] = inv * (e0 * bf2f(xl[0][h][w])
                                    + e1 * bf2f(xl[1][h][w])
                                    + e2 * bf2f(xl[2][h][w]));
        }
        __syncthreads();
#pragma unroll
        for (int j4 = 0; j4 < 4; ++j4) {
            float4 v = *(const float4*)&tile[nl][seg * 16 + j4 * 4];
            *(float4*)(outb + (size_t)(c0 + nl) * HWSZ + seg * 16 + j4 * 4) = v;
        }
        __syncthreads();
    }
}

// ---------------------------------------------------------------------------
// final (fallback): G channel-major [1536][NPIX], x fp32 natural layout.
// ---------------------------------------------------------------------------
__global__ __launch_bounds__(256)
void final_fuse(const __hip_bfloat16* __restrict__ G,
                const float* __restrict__ x0, const float* __restrict__ x1,
                const float* __restrict__ x2,
                const float* __restrict__ gp0, const float* __restrict__ gp1,
                const float* __restrict__ gp2,
                float* __restrict__ out)
{
    const int n  = blockIdx.x * 256 + threadIdx.x;
    const int b  = n >> 10;
    const int hw = n & (HWSZ - 1);
    const int c0 = blockIdx.y * 64;
    const float ga0 = gp0[0], ga1 = gp1[0], ga2 = gp2[0];
    for (int cc = 0; cc < 64; ++cc) {
        const int c = c0 + cc;
        const float s0 = __bfloat162float(G[(size_t)c * NPIX + n]);
        const float s1 = __bfloat162float(G[(size_t)(c + DCH) * NPIX + n]);
        const float s2 = __bfloat162float(G[(size_t)(c + 2 * DCH) * NPIX + n]);
        const float g0v = 1.0f / (1.0f + __expf(-s0));
        const float g1v = 1.0f / (1.0f + __expf(-s1));
        const float g2v = 1.0f / (1.0f + __expf(-s2));
        const float e0 = __expf(g0v), e1 = __expf(g1v), e2 = __expf(g2v);
        const float inv = 1.0f / (e0 + e1 + e2);
        const size_t xo = (size_t)b * (DCH * HWSZ) + (size_t)c * HWSZ + hw;
        out[xo] = inv * (e0 * ga0 * x0[xo] + e1 * ga1 * x1[xo] + e2 * ga2 * x2[xo]);
    }
}

// ---------------------------------------------------------------------------
extern "C" void kernel_launch(void* const* d_in, const int* in_sizes, int n_in,
                              void* d_out, int out_size, void* d_ws, size_t ws_size,
                              hipStream_t stream)
{
    const float* out0   = (const float*)d_in[0];
    const float* out1   = (const float*)d_in[1];
    const float* out2   = (const float*)d_in[2];
    const float* gamma0 = (const float*)d_in[3];
    const float* gamma1 = (const float*)d_in[4];
    const float* gamma2 = (const float*)d_in[5];
    const float* W_in1  = (const float*)d_in[6];
    const float* W_in2  = (const float*)d_in[8];
    const float* W_in3  = (const float*)d_in[10];
    const float* b_in1  = (const float*)d_in[7];
    const float* b_in2  = (const float*)d_in[9];
    const float* b_in3  = (const float*)d_in[11];
    const float* W_tr   = (const float*)d_in[12];
    const float* b_tr   = (const float*)d_in[13];
    const float* W_o1   = (const float*)d_in[14];
    const float* b_o1   = (const float*)d_in[15];
    const float* W_o2   = (const float*)d_in[16];
    const float* b_o2   = (const float*)d_in[17];
    const float* W_o3   = (const float*)d_in[18];
    const float* b_o3   = (const float*)d_in[19];
    float* outp = (float*)d_out;

    unsigned char* ws = (unsigned char*)d_ws;
    const size_t SZ_ACT   = (size_t)3 * NPIX * DCH * 2;     // 100663296
    const size_t WB_BYTES = (size_t)(6 * WSQ + WTR) * 2;    // 7864320
    const size_t NEED3    = 3 * SZ_ACT + WB_BYTES + 4096 * 4;
    const bool   big      = (ws_size >= NEED3);

    __hip_bfloat16* buf0 = (__hip_bfloat16*)ws;
    __hip_bfloat16* buf1 = (__hip_bfloat16*)(ws + SZ_ACT);
    __hip_bfloat16* buf2 = big ? (__hip_bfloat16*)(ws + 2 * SZ_ACT) : buf0;
    unsigned char*  wtop = ws + (big ? 3 : 2) * SZ_ACT;
    __hip_bfloat16* Wb     = (__hip_bfloat16*)wtop;
    __hip_bfloat16* Wb_tr  = Wb + 3 * WSQ;
    __hip_bfloat16* Wb_o   = Wb_tr + WTR;
    float*          biasWS = (float*)(wtop + WB_BYTES);      // [6][512]

    const int CVT_TOTAL = 6 * WSQ + WTR;
    cvt_all<<<CVT_TOTAL / 1024, 256, 0, stream>>>(W_in1, W_in2, W_in3, W_tr,
                                                  W_o1, W_o2, W_o3, Wb);
    copy_bias<<<1, 512, 0, stream>>>(b_in1, b_in2, b_in3, b_o1, b_o2, b_o3, biasWS);

    stage_transpose<<<dim3(16, 8, 96), 256, 0, stream>>>(out0, out1, out2,
                                                         gamma0, gamma1, gamma2, buf0);

    // GEMM-A (batched 3 branches): XbT x W_in_i -> HcatT[n][br*512+o]
    gemm256<<<dim3(768), 512, 0, stream>>>(
        buf0, DCH, Wb, DCH, biasWS,
        buf1, 3 * DCH, 0, DCH, 2, 256, NPIX * DCH, WSQ, DCH, DCH, 0);

    // GEMM-B: HcatT x W_trans -> HtraT (buf2 in fast path; buf0 in fallback)
    gemm256<<<dim3(768), 512, 0, stream>>>(
        buf1, 3 * DCH, Wb_tr, 3 * DCH, b_tr,
        buf2, 3 * DCH, 0, 3 * DCH, 6, 768, 0, 0, 0, 0, 0);

    if (big) {
        // GEMM-C (batched): HtraT[:, br*512:] x W_out_i -> G^T[n][br*512+o]
        gemm256<<<dim3(768), 512, 0, stream>>>(
            buf2, 3 * DCH, Wb_o, DCH, biasWS + 3 * DCH,
            buf1, 3 * DCH, 0, DCH, 2, 256, DCH, WSQ, DCH, DCH, 0);
        final_v2<<<dim3(NPIX / 64), 256, 0, stream>>>(buf1, buf0, outp);
    } else {
        // fallback: channel-major G + fp32-x final (R4 dataflow)
        gemm256<<<dim3(768), 512, 0, stream>>>(
            buf0, 3 * DCH, Wb_o, DCH, biasWS + 3 * DCH,
            buf1, NPIX, 0, DCH, 2, 256, DCH, WSQ, DCH, DCH, 1);
        final_fuse<<<dim3(NPIX / 256, DCH / 64), 256, 0, stream>>>(
            buf1, out0, out1, out2, gamma0, gamma1, gamma2, outp);
    }
}

// Round 7
// 446.674 us; speedup vs baseline: 1.3601x; 1.0421x over previous
//
#include <hip/hip_runtime.h>
#include <hip/hip_bf16.h>

#define NPIX 32768
#define DCH 512
#define HWSZ 1024
#define WSQ (DCH * DCH)
#define WTR (3 * DCH * 3 * DCH)

typedef __bf16 bf16x8_t __attribute__((ext_vector_type(8)));
typedef float f32x4_t __attribute__((ext_vector_type(4)));
typedef unsigned short u16x8_t __attribute__((ext_vector_type(8)));
typedef unsigned short u16x4_t __attribute__((ext_vector_type(4)));

static __device__ __forceinline__ unsigned short f2bf(float f) {
    return __builtin_bit_cast(unsigned short, __float2bfloat16(f));
}
static __device__ __forceinline__ float bf2f(unsigned short u) {
    unsigned v = (unsigned)u << 16;
    return __builtin_bit_cast(float, v);
}

// ---------------------------------------------------------------------------
// All-weights fp32 -> bf16 + bias gather (single launch).
// Weight order: in1,in2,in3 (WSQ each), tr (WTR), o1,o2,o3 (WSQ each).
// Last block copies the 6x512 biases into biasWS.
// ---------------------------------------------------------------------------
__global__ __launch_bounds__(256)
void cvt_all(const float* __restrict__ w0, const float* __restrict__ w1,
             const float* __restrict__ w2, const float* __restrict__ w3,
             const float* __restrict__ w4, const float* __restrict__ w5,
             const float* __restrict__ w6, __hip_bfloat16* __restrict__ d,
             const float* __restrict__ b0, const float* __restrict__ b1,
             const float* __restrict__ b2, const float* __restrict__ b3,
             const float* __restrict__ b4, const float* __restrict__ b5,
             float* __restrict__ biasd)
{
    if (blockIdx.x == gridDim.x - 1) {
        for (int idx = threadIdx.x; idx < 3072; idx += 256) {
            const int r = idx >> 9, off = idx & 511;
            const float* s = (r == 0) ? b0 : (r == 1) ? b1 : (r == 2) ? b2
                           : (r == 3) ? b3 : (r == 4) ? b4 : b5;
            biasd[idx] = s[off];
        }
        return;
    }
    const int i = (blockIdx.x * 256 + threadIdx.x) * 4;
    const float* src;
    int off;
    if (i < 3 * WSQ) {
        int r = i >> 18;
        src = (r == 0) ? w0 : ((r == 1) ? w1 : w2);
        off = i - r * WSQ;
    } else if (i < 3 * WSQ + WTR) {
        src = w3; off = i - 3 * WSQ;
    } else {
        int j = i - 3 * WSQ - WTR;
        int r = j >> 18;
        src = (r == 0) ? w4 : ((r == 1) ? w5 : w6);
        off = j - r * WSQ;
    }
    float4 f = *(const float4*)(src + off);
    u16x4_t v;
    v[0] = f2bf(f.x); v[1] = f2bf(f.y); v[2] = f2bf(f.z); v[3] = f2bf(f.w);
    *(u16x4_t*)((unsigned short*)d + i) = v;
}

// ---------------------------------------------------------------------------
// Stage: X[b][c][hw] fp32 -> XbT[branch][n][c] bf16 with gamma scale.
// ---------------------------------------------------------------------------
__global__ __launch_bounds__(256)
void stage_transpose(const float* __restrict__ x0, const float* __restrict__ x1,
                     const float* __restrict__ x2,
                     const float* __restrict__ gp0, const float* __restrict__ gp1,
                     const float* __restrict__ gp2,
                     __hip_bfloat16* __restrict__ XbT)
{
    __shared__ float tile[64][65];
    const int hw0 = blockIdx.x * 64;
    const int c0  = blockIdx.y * 64;
    const int bz  = blockIdx.z;
    const int br  = bz >> 5;
    const int b   = bz & 31;
    const float* x = (br == 0) ? x0 : ((br == 1) ? x1 : x2);
    const float g  = ((br == 0) ? gp0 : ((br == 1) ? gp1 : gp2))[0];
    const int t = threadIdx.x;

    const int hwi = t & 63;
    const int cb  = t >> 6;
    const float* src = x + (size_t)b * (DCH * HWSZ) + (size_t)c0 * HWSZ + hw0;
#pragma unroll
    for (int i = 0; i < 16; ++i) {
        const int ci = cb + i * 4;
        tile[ci][hwi] = g * src[(size_t)ci * HWSZ + hwi];
    }
    __syncthreads();

    const int hwr = t >> 2;
    const int cch = (t & 3) * 16;
    __hip_bfloat16* dst = XbT + (size_t)((size_t)br * NPIX + b * HWSZ + hw0 + hwr) * DCH + c0 + cch;
    u16x8_t v0, v1;
#pragma unroll
    for (int e = 0; e < 8; ++e) v0[e] = f2bf(tile[cch + e][hwr]);
#pragma unroll
    for (int e = 0; e < 8; ++e) v1[e] = f2bf(tile[cch + 8 + e][hwr]);
    *(u16x8_t*)dst = v0;
    *((u16x8_t*)dst + 1) = v1;
}

// ---------------------------------------------------------------------------
// 256x256 pipelined NT GEMM (R4 K-loop) + batched-branch decode.
// trans_out=0: direct scalar stores (R4-measured-faster than LDS staging).
// trans_out=1: channel-major via LDS transpose (fallback path only).
// ---------------------------------------------------------------------------
__global__ __launch_bounds__(512, 2)
void gemm256(const __hip_bfloat16* __restrict__ A, int lda,
             const __hip_bfloat16* __restrict__ B, int ldb,
             const float* __restrict__ bias,
             __hip_bfloat16* __restrict__ C, int ldc, int coff0,
             int K, int NO, int TPB, int brA, int brB, int bstride,
             int cstride, int trans_out)
{
    __shared__ __align__(16) unsigned char smem[131072];
    const int tid  = threadIdx.x;
    const int lane = tid & 63;
    const int wave = tid >> 6;
    const int wm   = wave >> 2;
    const int wn   = wave & 3;
    const int l16  = lane & 15;
    const int l4   = lane >> 4;

    // XCD swizzle on flat id, then batch decode (grid % 8 == 0)
    const int per  = gridDim.x >> 3;
    const int flat = (blockIdx.x & 7) * per + (blockIdx.x >> 3);
    const int br   = flat / TPB;
    const int rem  = flat - br * TPB;
    const int nt   = rem / NO;
    const int ot   = rem - nt * NO;
    const int n0 = nt * 256;
    const int o0 = ot * 256;
    const int NT = K >> 6;

    A    += (size_t)br * (size_t)brA;
    B    += (size_t)br * (size_t)brB;
    bias += br * bstride;
    const int coff = coff0 + br * cstride;

    // read-side swizzled base addresses
    const unsigned xorv = (unsigned)((l16 & 7) << 4);
    unsigned baseA[2], baseB[2];
#pragma unroll
    for (int kk = 0; kk < 2; ++kk) {
        const unsigned ko = ((unsigned)(kk * 64 + l4 * 16)) ^ xorv;
        baseA[kk] = (unsigned)((wm * 128 + l16) * 128) + ko;
        baseB[kk] = 32768u + (unsigned)((wn * 64 + l16) * 128) + ko;
    }

    const int rr  = lane >> 3;
    const int kel = 8 * ((lane & 7) ^ rr);

    auto stageA = [&](int t, int half) {
        const unsigned dst = (unsigned)((t & 1) * 65536 + half * 16384 + wave * 2048);
        const __hip_bfloat16* g = A + (size_t)(n0 + half * 128 + wave * 16 + rr) * lda + t * 64 + kel;
#pragma unroll
        for (int s = 0; s < 2; ++s) {
            __builtin_amdgcn_global_load_lds(
                (const __attribute__((address_space(1))) unsigned int*)(g + (size_t)s * 8 * lda),
                (__attribute__((address_space(3))) unsigned int*)(smem + dst + s * 1024),
                16, 0, 0);
        }
    };
    auto stageB = [&](int t, int half) {
        const unsigned dst = (unsigned)((t & 1) * 65536 + 32768 + half * 16384 + wave * 2048);
        const __hip_bfloat16* g = B + (size_t)(o0 + half * 128 + wave * 16 + rr) * ldb + t * 64 + kel;
#pragma unroll
        for (int s = 0; s < 2; ++s) {
            __builtin_amdgcn_global_load_lds(
                (const __attribute__((address_space(1))) unsigned int*)(g + (size_t)s * 8 * ldb),
                (__attribute__((address_space(3))) unsigned int*)(smem + dst + s * 1024),
                16, 0, 0);
        }
    };

#define DSRO(dst, addr, OFF) \
    asm volatile("ds_read_b128 %0, %1 offset:" #OFF : "=v"(dst) : "v"(addr))
#define BC(x) __builtin_bit_cast(bf16x8_t, x)

    stageA(0, 0); stageA(0, 1); stageB(0, 0); stageB(0, 1);
    stageA(1, 0); stageA(1, 1); stageB(1, 0); stageB(1, 1);
    asm volatile("s_waitcnt vmcnt(8)");
    __builtin_amdgcn_s_barrier();

    f32x4_t aR[4][2], a2[4][2], bA[2][2], bB[2][2];
    f32x4_t acc[8][4];
#pragma unroll
    for (int m = 0; m < 8; ++m)
#pragma unroll
        for (int n = 0; n < 4; ++n) acc[m][n] = (f32x4_t){0.f, 0.f, 0.f, 0.f};

    {
        unsigned a0 = baseA[0], a1 = baseA[1], b0 = baseB[0], b1 = baseB[1];
        DSRO(aR[0][0], a0, 0);    DSRO(aR[1][0], a0, 2048);
        DSRO(aR[2][0], a0, 4096); DSRO(aR[3][0], a0, 6144);
        DSRO(aR[0][1], a1, 0);    DSRO(aR[1][1], a1, 2048);
        DSRO(aR[2][1], a1, 4096); DSRO(aR[3][1], a1, 6144);
        DSRO(bA[0][0], b0, 0);    DSRO(bA[1][0], b0, 2048);
        DSRO(bA[0][1], b1, 0);    DSRO(bA[1][1], b1, 2048);
    }

    unsigned cb = 0;
    for (int t = 0; t < NT; ++t) {
        const unsigned cbn = cb ^ 65536u;
        const unsigned a0 = cb + baseA[0], a1 = cb + baseA[1];
        const unsigned b0 = cb + baseB[0], b1 = cb + baseB[1];

        // ---- P0
        asm volatile("s_waitcnt lgkmcnt(0)");
        __builtin_amdgcn_sched_barrier(0);
        DSRO(bB[0][0], b0, 4096); DSRO(bB[1][0], b0, 6144);
        DSRO(bB[0][1], b1, 4096); DSRO(bB[1][1], b1, 6144);
        __builtin_amdgcn_sched_barrier(0);
        __builtin_amdgcn_s_setprio(1);
#pragma unroll
        for (int m = 0; m < 4; ++m)
#pragma unroll
            for (int n = 0; n < 2; ++n)
#pragma unroll
                for (int kk = 0; kk < 2; ++kk)
                    acc[m][n] = __builtin_amdgcn_mfma_f32_16x16x32_bf16(BC(aR[m][kk]), BC(bA[n][kk]), acc[m][n], 0, 0, 0);
        __builtin_amdgcn_s_setprio(0);
        __builtin_amdgcn_s_barrier();

        // ---- P1
        asm volatile("s_waitcnt lgkmcnt(0)");
        __builtin_amdgcn_sched_barrier(0);
        DSRO(a2[0][0], a0, 8192);  DSRO(a2[1][0], a0, 10240);
        DSRO(a2[2][0], a0, 12288); DSRO(a2[3][0], a0, 14336);
        DSRO(a2[0][1], a1, 8192);  DSRO(a2[1][1], a1, 10240);
        DSRO(a2[2][1], a1, 12288); DSRO(a2[3][1], a1, 14336);
        __builtin_amdgcn_sched_barrier(0);
        __builtin_amdgcn_s_setprio(1);
#pragma unroll
        for (int m = 0; m < 4; ++m)
#pragma unroll
            for (int n = 0; n < 2; ++n)
#pragma unroll
                for (int kk = 0; kk < 2; ++kk)
                    acc[m][n + 2] = __builtin_amdgcn_mfma_f32_16x16x32_bf16(BC(aR[m][kk]), BC(bB[n][kk]), acc[m][n + 2], 0, 0, 0);
        __builtin_amdgcn_s_setprio(0);
        __builtin_amdgcn_s_barrier();

        // ---- P2
        asm volatile("s_waitcnt lgkmcnt(0)");
        __builtin_amdgcn_sched_barrier(0);
        if (t + 2 < NT) { stageB(t + 2, 0); stageB(t + 2, 1); }
        __builtin_amdgcn_sched_barrier(0);
        __builtin_amdgcn_s_setprio(1);
#pragma unroll
        for (int m = 0; m < 4; ++m)
#pragma unroll
            for (int n = 0; n < 2; ++n)
#pragma unroll
                for (int kk = 0; kk < 2; ++kk)
                    acc[m + 4][n] = __builtin_amdgcn_mfma_f32_16x16x32_bf16(BC(a2[m][kk]), BC(bA[n][kk]), acc[m + 4][n], 0, 0, 0);
        __builtin_amdgcn_s_setprio(0);
        if (t + 2 < NT)        { asm volatile("s_waitcnt vmcnt(4)"); }
        else if (t + 2 == NT)  { asm volatile("s_waitcnt vmcnt(0)"); }
        __builtin_amdgcn_s_barrier();

        // ---- P3
        if (t + 1 < NT) {
            const unsigned na0 = cbn + baseA[0], na1 = cbn + baseA[1];
            const unsigned nb0 = cbn + baseB[0], nb1 = cbn + baseB[1];
            DSRO(aR[0][0], na0, 0);    DSRO(aR[1][0], na0, 2048);
            DSRO(aR[2][0], na0, 4096); DSRO(aR[3][0], na0, 6144);
            DSRO(aR[0][1], na1, 0);    DSRO(aR[1][1], na1, 2048);
            DSRO(aR[2][1], na1, 4096); DSRO(aR[3][1], na1, 6144);
            DSRO(bA[0][0], nb0, 0);    DSRO(bA[1][0], nb0, 2048);
            DSRO(bA[0][1], nb1, 0);    DSRO(bA[1][1], nb1, 2048);
        }
        if (t + 2 < NT) { stageA(t + 2, 0); stageA(t + 2, 1); }
        __builtin_amdgcn_sched_barrier(0);
        __builtin_amdgcn_s_setprio(1);
#pragma unroll
        for (int m = 0; m < 4; ++m)
#pragma unroll
            for (int n = 0; n < 2; ++n)
#pragma unroll
                for (int kk = 0; kk < 2; ++kk)
                    acc[m + 4][n + 2] = __builtin_amdgcn_mfma_f32_16x16x32_bf16(BC(a2[m][kk]), BC(bB[n][kk]), acc[m + 4][n + 2], 0, 0, 0);
        __builtin_amdgcn_s_setprio(0);
        cb = cbn;
    }

    if (!trans_out) {
        // direct scalar stores (R4-measured: faster than LDS staging epilogue)
#pragma unroll
        for (int n = 0; n < 4; ++n) {
            const int oc = o0 + wn * 64 + n * 16 + l16;
            const float bv = bias[oc];
#pragma unroll
            for (int m = 0; m < 8; ++m)
#pragma unroll
                for (int r = 0; r < 4; ++r) {
                    const int nr = n0 + wm * 128 + m * 16 + l4 * 4 + r;
                    C[(size_t)nr * ldc + coff + oc] = __float2bfloat16(acc[m][n][r] + bv);
                }
        }
    } else {
        // channel-major output (fallback path only)
        __syncthreads();
#pragma unroll
        for (int n = 0; n < 4; ++n) {
            const int ocl = wn * 64 + n * 16 + l16;
            const float bv = bias[o0 + ocl];
#pragma unroll
            for (int m = 0; m < 8; ++m)
#pragma unroll
                for (int r = 0; r < 4; ++r) {
                    const int nrow = wm * 128 + m * 16 + l4 * 4 + r;
                    const unsigned phys = (unsigned)nrow * 512u
                        + (((unsigned)ocl * 2u) ^ (((unsigned)(nrow & 7)) << 4));
                    *(unsigned short*)(smem + phys) = f2bf(acc[m][n][r] + bv);
                }
        }
        __syncthreads();
        const int ol = tid >> 1;
        const int nh = (tid & 1) * 128;
        __hip_bfloat16* dst = C + (size_t)(coff + o0 + ol) * ldc + n0 + nh;
#pragma unroll
        for (int j8 = 0; j8 < 16; ++j8) {
            u16x8_t v;
#pragma unroll
            for (int e = 0; e < 8; ++e) {
                const int n2 = nh + j8 * 8 + e;
                v[e] = *(const unsigned short*)(smem + (unsigned)n2 * 512u
                        + ((((unsigned)ol * 2u) ^ ((unsigned)e << 4))));
            }
            *(u16x8_t*)((unsigned short*)dst + j8 * 8) = v;
        }
    }
#undef DSRO
#undef BC
}

// ---------------------------------------------------------------------------
// final_v2: G^T [NPIX][1536] n-major, Xb [3][NPIX][512] bf16 (= gamma_i x_i).
// ---------------------------------------------------------------------------
__global__ __launch_bounds__(256)
void final_v2(const __hip_bfloat16* __restrict__ G,
              const __hip_bfloat16* __restrict__ Xb,
              float* __restrict__ out)
{
    __shared__ float tile[64][68];
    const int n0  = blockIdx.x * 64;
    const int b   = n0 >> 10;
    const int hw0 = n0 & (HWSZ - 1);
    const int t   = threadIdx.x;
    const int nl  = t >> 2;
    const int cg  = (t & 3) * 16;
    const int n   = n0 + nl;
    const unsigned short* gr = (const unsigned short*)G + (size_t)n * 1536;
    const unsigned short* xr = (const unsigned short*)Xb + (size_t)n * 512;
    const int seg = t & 3;
    float* outb = out + (size_t)b * (DCH * HWSZ) + hw0;

    for (int c0 = 0; c0 < DCH; c0 += 64) {
        u16x8_t gl[3][2], xl[3][2];
#pragma unroll
        for (int i = 0; i < 3; ++i) {
            gl[i][0] = *(const u16x8_t*)(gr + i * 512 + c0 + cg);
            gl[i][1] = *(const u16x8_t*)(gr + i * 512 + c0 + cg + 8);
            xl[i][0] = *(const u16x8_t*)(xr + (size_t)i * NPIX * 512 + c0 + cg);
            xl[i][1] = *(const u16x8_t*)(xr + (size_t)i * NPIX * 512 + c0 + cg + 8);
        }
#pragma unroll
        for (int e = 0; e < 16; ++e) {
            const int h = e >> 3, w = e & 7;
            const float s0 = bf2f(gl[0][h][w]);
            const float s1 = bf2f(gl[1][h][w]);
            const float s2 = bf2f(gl[2][h][w]);
            const float g0 = 1.0f / (1.0f + __expf(-s0));
            const float g1 = 1.0f / (1.0f + __expf(-s1));
            const float g2 = 1.0f / (1.0f + __expf(-s2));
            const float e0 = __expf(g0), e1 = __expf(g1), e2 = __expf(g2);
            const float inv = 1.0f / (e0 + e1 + e2);
            tile[cg + e][nl] = inv * (e0 * bf2f(xl[0][h][w])
                                    + e1 * bf2f(xl[1][h][w])
                                    + e2 * bf2f(xl[2][h][w]));
        }
        __syncthreads();
#pragma unroll
        for (int j4 = 0; j4 < 4; ++j4) {
            float4 v = *(const float4*)&tile[nl][seg * 16 + j4 * 4];
            *(float4*)(outb + (size_t)(c0 + nl) * HWSZ + seg * 16 + j4 * 4) = v;
        }
        __syncthreads();
    }
}

// ---------------------------------------------------------------------------
// final (fallback): G channel-major [1536][NPIX], x fp32 natural layout.
// ---------------------------------------------------------------------------
__global__ __launch_bounds__(256)
void final_fuse(const __hip_bfloat16* __restrict__ G,
                const float* __restrict__ x0, const float* __restrict__ x1,
                const float* __restrict__ x2,
                const float* __restrict__ gp0, const float* __restrict__ gp1,
                const float* __restrict__ gp2,
                float* __restrict__ out)
{
    const int n  = blockIdx.x * 256 + threadIdx.x;
    const int b  = n >> 10;
    const int hw = n & (HWSZ - 1);
    const int c0 = blockIdx.y * 64;
    const float ga0 = gp0[0], ga1 = gp1[0], ga2 = gp2[0];
    for (int cc = 0; cc < 64; ++cc) {
        const int c = c0 + cc;
        const float s0 = __bfloat162float(G[(size_t)c * NPIX + n]);
        const float s1 = __bfloat162float(G[(size_t)(c + DCH) * NPIX + n]);
        const float s2 = __bfloat162float(G[(size_t)(c + 2 * DCH) * NPIX + n]);
        const float g0v = 1.0f / (1.0f + __expf(-s0));
        const float g1v = 1.0f / (1.0f + __expf(-s1));
        const float g2v = 1.0f / (1.0f + __expf(-s2));
        const float e0 = __expf(g0v), e1 = __expf(g1v), e2 = __expf(g2v);
        const float inv = 1.0f / (e0 + e1 + e2);
        const size_t xo = (size_t)b * (DCH * HWSZ) + (size_t)c * HWSZ + hw;
        out[xo] = inv * (e0 * ga0 * x0[xo] + e1 * ga1 * x1[xo] + e2 * ga2 * x2[xo]);
    }
}

// ---------------------------------------------------------------------------
extern "C" void kernel_launch(void* const* d_in, const int* in_sizes, int n_in,
                              void* d_out, int out_size, void* d_ws, size_t ws_size,
                              hipStream_t stream)
{
    const float* out0   = (const float*)d_in[0];
    const float* out1   = (const float*)d_in[1];
    const float* out2   = (const float*)d_in[2];
    const float* gamma0 = (const float*)d_in[3];
    const float* gamma1 = (const float*)d_in[4];
    const float* gamma2 = (const float*)d_in[5];
    const float* W_in1  = (const float*)d_in[6];
    const float* W_in2  = (const float*)d_in[8];
    const float* W_in3  = (const float*)d_in[10];
    const float* b_in1  = (const float*)d_in[7];
    const float* b_in2  = (const float*)d_in[9];
    const float* b_in3  = (const float*)d_in[11];
    const float* W_tr   = (const float*)d_in[12];
    const float* b_tr   = (const float*)d_in[13];
    const float* W_o1   = (const float*)d_in[14];
    const float* b_o1   = (const float*)d_in[15];
    const float* W_o2   = (const float*)d_in[16];
    const float* b_o2   = (const float*)d_in[17];
    const float* W_o3   = (const float*)d_in[18];
    const float* b_o3   = (const float*)d_in[19];
    float* outp = (float*)d_out;

    unsigned char* ws = (unsigned char*)d_ws;
    const size_t SZ_ACT   = (size_t)3 * NPIX * DCH * 2;     // 100663296
    const size_t WB_BYTES = (size_t)(6 * WSQ + WTR) * 2;    // 7864320
    const size_t NEED3    = 3 * SZ_ACT + WB_BYTES + 4096 * 4;
    const bool   big      = (ws_size >= NEED3);

    __hip_bfloat16* buf0 = (__hip_bfloat16*)ws;
    __hip_bfloat16* buf1 = (__hip_bfloat16*)(ws + SZ_ACT);
    __hip_bfloat16* buf2 = big ? (__hip_bfloat16*)(ws + 2 * SZ_ACT) : buf0;
    unsigned char*  wtop = ws + (big ? 3 : 2) * SZ_ACT;
    __hip_bfloat16* Wb     = (__hip_bfloat16*)wtop;
    __hip_bfloat16* Wb_tr  = Wb + 3 * WSQ;
    __hip_bfloat16* Wb_o   = Wb_tr + WTR;
    float*          biasWS = (float*)(wtop + WB_BYTES);      // [6][512]

    const int CVT_TOTAL = 6 * WSQ + WTR;
    cvt_all<<<CVT_TOTAL / 1024 + 1, 256, 0, stream>>>(
        W_in1, W_in2, W_in3, W_tr, W_o1, W_o2, W_o3, Wb,
        b_in1, b_in2, b_in3, b_o1, b_o2, b_o3, biasWS);

    stage_transpose<<<dim3(16, 8, 96), 256, 0, stream>>>(out0, out1, out2,
                                                         gamma0, gamma1, gamma2, buf0);

    // GEMM-A (batched 3 branches): XbT x W_in_i -> HcatT[n][br*512+o]
    gemm256<<<dim3(768), 512, 0, stream>>>(
        buf0, DCH, Wb, DCH, biasWS,
        buf1, 3 * DCH, 0, DCH, 2, 256, NPIX * DCH, WSQ, DCH, DCH, 0);

    // GEMM-B: HcatT x W_trans -> HtraT (buf2 in fast path; buf0 in fallback)
    gemm256<<<dim3(768), 512, 0, stream>>>(
        buf1, 3 * DCH, Wb_tr, 3 * DCH, b_tr,
        buf2, 3 * DCH, 0, 3 * DCH, 6, 768, 0, 0, 0, 0, 0);

    if (big) {
        // GEMM-C (batched): HtraT[:, br*512:] x W_out_i -> G^T[n][br*512+o]
        gemm256<<<dim3(768), 512, 0, stream>>>(
            buf2, 3 * DCH, Wb_o, DCH, biasWS + 3 * DCH,
            buf1, 3 * DCH, 0, DCH, 2, 256, DCH, WSQ, DCH, DCH, 0);
        final_v2<<<dim3(NPIX / 64), 256, 0, stream>>>(buf1, buf0, outp);
    } else {
        // fallback: channel-major G + fp32-x final (R4 dataflow)
        gemm256<<<dim3(768), 512, 0, stream>>>(
            buf0, 3 * DCH, Wb_o, DCH, biasWS + 3 * DCH,
            buf1, NPIX, 0, DCH, 2, 256, DCH, WSQ, DCH, DCH, 1);
        final_fuse<<<dim3(NPIX / 256, DCH / 64), 256, 0, stream>>>(
            buf1, out0, out1, out2, gamma0, gamma1, gamma2, outp);
    }
}

// Round 8
// 424.190 us; speedup vs baseline: 1.4321x; 1.0530x over previous
//
#include <hip/hip_runtime.h>
#include <hip/hip_bf16.h>

#define NPIX 32768
#define DCH 512
#define HWSZ 1024
#define WSQ (DCH * DCH)
#define WTR (3 * DCH * 3 * DCH)

typedef __bf16 bf16x8_t __attribute__((ext_vector_type(8)));
typedef float f32x4_t __attribute__((ext_vector_type(4)));
typedef float f32x16_t __attribute__((ext_vector_type(16)));
typedef int i32x4_t __attribute__((ext_vector_type(4)));
typedef int i32x8_t __attribute__((ext_vector_type(8)));
typedef unsigned short u16x8_t __attribute__((ext_vector_type(8)));
typedef unsigned short u16x4_t __attribute__((ext_vector_type(4)));

static __device__ __forceinline__ unsigned short f2bf(float f) {
    return __builtin_bit_cast(unsigned short, __float2bfloat16(f));
}
static __device__ __forceinline__ float bf2f(unsigned short u) {
    unsigned v = (unsigned)u << 16;
    return __builtin_bit_cast(float, v);
}

// fp32 -> OCP e4m3 (RNE, saturating). bias 7, max 448, denormal step 2^-9.
static __device__ __forceinline__ unsigned char f2e4m3(float f) {
    unsigned u = __builtin_bit_cast(unsigned, f);
    unsigned sgn = (u >> 24) & 0x80u;
    float a = fabsf(f);
    if (a >= 448.0f) return (unsigned char)(sgn | 0x7Eu);
    if (a < 0.0078125f) {                       // below 2^-7: denormal region
        int q = (int)rintf(a * 512.0f);         // 0..4
        return (unsigned char)(sgn | (unsigned)q);
    }
    unsigned m = u & 0x7FFFFFFFu;
    unsigned lsb = (m >> 20) & 1u;
    m += 0x7FFFFu + lsb;                        // RNE at 3-bit mantissa
    int e = (int)(m >> 23) - 127;
    unsigned mant3 = (m >> 20) & 7u;
    if (e < -6) {                               // rounded into denormal band
        int q = (int)rintf(a * 512.0f);         // 4..8 (8 == 2^-6 encodes fine)
        return (unsigned char)(sgn | (unsigned)q);
    }
    if (e > 8) return (unsigned char)(sgn | 0x7Eu);
    return (unsigned char)(sgn | ((unsigned)(e + 7) << 3) | mant3);
}

// ---------------------------------------------------------------------------
// Weights: in1-3 -> bf16, tr -> fp8 e4m3, o1-3 -> bf16. Last block: biases.
// ---------------------------------------------------------------------------
__global__ __launch_bounds__(256)
void cvt_all(const float* __restrict__ w0, const float* __restrict__ w1,
             const float* __restrict__ w2, const float* __restrict__ w3,
             const float* __restrict__ w4, const float* __restrict__ w5,
             const float* __restrict__ w6, __hip_bfloat16* __restrict__ d,
             const float* __restrict__ b0, const float* __restrict__ b1,
             const float* __restrict__ b2, const float* __restrict__ b3,
             const float* __restrict__ b4, const float* __restrict__ b5,
             float* __restrict__ biasd)
{
    if (blockIdx.x == gridDim.x - 1) {
        for (int idx = threadIdx.x; idx < 3072; idx += 256) {
            const int r = idx >> 9, off = idx & 511;
            const float* s = (r == 0) ? b0 : (r == 1) ? b1 : (r == 2) ? b2
                           : (r == 3) ? b3 : (r == 4) ? b4 : b5;
            biasd[idx] = s[off];
        }
        return;
    }
    const int i = (blockIdx.x * 256 + threadIdx.x) * 4;
    if (i < 3 * WSQ) {
        int r = i >> 18;
        const float* src = (r == 0) ? w0 : ((r == 1) ? w1 : w2);
        int off = i - r * WSQ;
        float4 f = *(const float4*)(src + off);
        u16x4_t v;
        v[0] = f2bf(f.x); v[1] = f2bf(f.y); v[2] = f2bf(f.z); v[3] = f2bf(f.w);
        *(u16x4_t*)((unsigned short*)d + i) = v;
    } else if (i < 3 * WSQ + WTR) {
        int off = i - 3 * WSQ;
        float4 f = *(const float4*)(w3 + off);
        unsigned char* d8 = (unsigned char*)(d + 3 * WSQ);   // Wtr8 region
        d8[off + 0] = f2e4m3(f.x); d8[off + 1] = f2e4m3(f.y);
        d8[off + 2] = f2e4m3(f.z); d8[off + 3] = f2e4m3(f.w);
    } else {
        int j = i - 3 * WSQ - WTR;
        int r = j >> 18;
        const float* src = (r == 0) ? w4 : ((r == 1) ? w5 : w6);
        int off = j - r * WSQ;
        float4 f = *(const float4*)(src + off);
        u16x4_t v;
        v[0] = f2bf(f.x); v[1] = f2bf(f.y); v[2] = f2bf(f.z); v[3] = f2bf(f.w);
        *(u16x4_t*)((unsigned short*)d + i) = v;
    }
}

// ---------------------------------------------------------------------------
// Stage: X[b][c][hw] fp32 -> XbT[branch][n][c] bf16 with gamma scale.
// ---------------------------------------------------------------------------
__global__ __launch_bounds__(256)
void stage_transpose(const float* __restrict__ x0, const float* __restrict__ x1,
                     const float* __restrict__ x2,
                     const float* __restrict__ gp0, const float* __restrict__ gp1,
                     const float* __restrict__ gp2,
                     __hip_bfloat16* __restrict__ XbT)
{
    __shared__ float tile[64][65];
    const int hw0 = blockIdx.x * 64;
    const int c0  = blockIdx.y * 64;
    const int bz  = blockIdx.z;
    const int br  = bz >> 5;
    const int b   = bz & 31;
    const float* x = (br == 0) ? x0 : ((br == 1) ? x1 : x2);
    const float g  = ((br == 0) ? gp0 : ((br == 1) ? gp1 : gp2))[0];
    const int t = threadIdx.x;

    const int hwi = t & 63;
    const int cb  = t >> 6;
    const float* src = x + (size_t)b * (DCH * HWSZ) + (size_t)c0 * HWSZ + hw0;
#pragma unroll
    for (int i = 0; i < 16; ++i) {
        const int ci = cb + i * 4;
        tile[ci][hwi] = g * src[(size_t)ci * HWSZ + hwi];
    }
    __syncthreads();

    const int hwr = t >> 2;
    const int cch = (t & 3) * 16;
    __hip_bfloat16* dst = XbT + (size_t)((size_t)br * NPIX + b * HWSZ + hw0 + hwr) * DCH + c0 + cch;
    u16x8_t v0, v1;
#pragma unroll
    for (int e = 0; e < 8; ++e) v0[e] = f2bf(tile[cch + e][hwr]);
#pragma unroll
    for (int e = 0; e < 8; ++e) v1[e] = f2bf(tile[cch + 8 + e][hwr]);
    *(u16x8_t*)dst = v0;
    *((u16x8_t*)dst + 1) = v1;
}

// ---------------------------------------------------------------------------
// 256x256 pipelined bf16 NT GEMM (R7 K-loop, unchanged) + batched decode.
// cmode=0: bf16 out. cmode=1: fp8 e4m3 out (for Hcat -> fp8 GEMM-B input).
// trans_out=1: channel-major bf16 (fallback path).
// ---------------------------------------------------------------------------
__global__ __launch_bounds__(512, 2)
void gemm256(const __hip_bfloat16* __restrict__ A, int lda,
             const __hip_bfloat16* __restrict__ B, int ldb,
             const float* __restrict__ bias,
             __hip_bfloat16* __restrict__ C, int ldc, int coff0,
             int K, int NO, int TPB, int brA, int brB, int bstride,
             int cstride, int trans_out, int cmode)
{
    __shared__ __align__(16) unsigned char smem[131072];
    const int tid  = threadIdx.x;
    const int lane = tid & 63;
    const int wave = tid >> 6;
    const int wm   = wave >> 2;
    const int wn   = wave & 3;
    const int l16  = lane & 15;
    const int l4   = lane >> 4;

    const int per  = gridDim.x >> 3;
    const int flat = (blockIdx.x & 7) * per + (blockIdx.x >> 3);
    const int br   = flat / TPB;
    const int rem  = flat - br * TPB;
    const int nt   = rem / NO;
    const int ot   = rem - nt * NO;
    const int n0 = nt * 256;
    const int o0 = ot * 256;
    const int NT = K >> 6;

    A    += (size_t)br * (size_t)brA;
    B    += (size_t)br * (size_t)brB;
    bias += br * bstride;
    const int coff = coff0 + br * cstride;

    const unsigned xorv = (unsigned)((l16 & 7) << 4);
    unsigned baseA[2], baseB[2];
#pragma unroll
    for (int kk = 0; kk < 2; ++kk) {
        const unsigned ko = ((unsigned)(kk * 64 + l4 * 16)) ^ xorv;
        baseA[kk] = (unsigned)((wm * 128 + l16) * 128) + ko;
        baseB[kk] = 32768u + (unsigned)((wn * 64 + l16) * 128) + ko;
    }

    const int rr  = lane >> 3;
    const int kel = 8 * ((lane & 7) ^ rr);

    auto stageA = [&](int t, int half) {
        const unsigned dst = (unsigned)((t & 1) * 65536 + half * 16384 + wave * 2048);
        const __hip_bfloat16* g = A + (size_t)(n0 + half * 128 + wave * 16 + rr) * lda + t * 64 + kel;
#pragma unroll
        for (int s = 0; s < 2; ++s) {
            __builtin_amdgcn_global_load_lds(
                (const __attribute__((address_space(1))) unsigned int*)(g + (size_t)s * 8 * lda),
                (__attribute__((address_space(3))) unsigned int*)(smem + dst + s * 1024),
                16, 0, 0);
        }
    };
    auto stageB = [&](int t, int half) {
        const unsigned dst = (unsigned)((t & 1) * 65536 + 32768 + half * 16384 + wave * 2048);
        const __hip_bfloat16* g = B + (size_t)(o0 + half * 128 + wave * 16 + rr) * ldb + t * 64 + kel;
#pragma unroll
        for (int s = 0; s < 2; ++s) {
            __builtin_amdgcn_global_load_lds(
                (const __attribute__((address_space(1))) unsigned int*)(g + (size_t)s * 8 * ldb),
                (__attribute__((address_space(3))) unsigned int*)(smem + dst + s * 1024),
                16, 0, 0);
        }
    };

#define DSRO(dst, addr, OFF) \
    asm volatile("ds_read_b128 %0, %1 offset:" #OFF : "=v"(dst) : "v"(addr))
#define BC(x) __builtin_bit_cast(bf16x8_t, x)

    stageA(0, 0); stageA(0, 1); stageB(0, 0); stageB(0, 1);
    stageA(1, 0); stageA(1, 1); stageB(1, 0); stageB(1, 1);
    asm volatile("s_waitcnt vmcnt(8)");
    __builtin_amdgcn_s_barrier();

    f32x4_t aR[4][2], a2[4][2], bA[2][2], bB[2][2];
    f32x4_t acc[8][4];
#pragma unroll
    for (int m = 0; m < 8; ++m)
#pragma unroll
        for (int n = 0; n < 4; ++n) acc[m][n] = (f32x4_t){0.f, 0.f, 0.f, 0.f};

    {
        unsigned a0 = baseA[0], a1 = baseA[1], b0 = baseB[0], b1 = baseB[1];
        DSRO(aR[0][0], a0, 0);    DSRO(aR[1][0], a0, 2048);
        DSRO(aR[2][0], a0, 4096); DSRO(aR[3][0], a0, 6144);
        DSRO(aR[0][1], a1, 0);    DSRO(aR[1][1], a1, 2048);
        DSRO(aR[2][1], a1, 4096); DSRO(aR[3][1], a1, 6144);
        DSRO(bA[0][0], b0, 0);    DSRO(bA[1][0], b0, 2048);
        DSRO(bA[0][1], b1, 0);    DSRO(bA[1][1], b1, 2048);
    }

    unsigned cb = 0;
    for (int t = 0; t < NT; ++t) {
        const unsigned cbn = cb ^ 65536u;
        const unsigned a0 = cb + baseA[0], a1 = cb + baseA[1];
        const unsigned b0 = cb + baseB[0], b1 = cb + baseB[1];

        // ---- P0
        asm volatile("s_waitcnt lgkmcnt(0)");
        __builtin_amdgcn_sched_barrier(0);
        DSRO(bB[0][0], b0, 4096); DSRO(bB[1][0], b0, 6144);
        DSRO(bB[0][1], b1, 4096); DSRO(bB[1][1], b1, 6144);
        __builtin_amdgcn_sched_barrier(0);
        __builtin_amdgcn_s_setprio(1);
#pragma unroll
        for (int m = 0; m < 4; ++m)
#pragma unroll
            for (int n = 0; n < 2; ++n)
#pragma unroll
                for (int kk = 0; kk < 2; ++kk)
                    acc[m][n] = __builtin_amdgcn_mfma_f32_16x16x32_bf16(BC(aR[m][kk]), BC(bA[n][kk]), acc[m][n], 0, 0, 0);
        __builtin_amdgcn_s_setprio(0);
        __builtin_amdgcn_s_barrier();

        // ---- P1
        asm volatile("s_waitcnt lgkmcnt(0)");
        __builtin_amdgcn_sched_barrier(0);
        DSRO(a2[0][0], a0, 8192);  DSRO(a2[1][0], a0, 10240);
        DSRO(a2[2][0], a0, 12288); DSRO(a2[3][0], a0, 14336);
        DSRO(a2[0][1], a1, 8192);  DSRO(a2[1][1], a1, 10240);
        DSRO(a2[2][1], a1, 12288); DSRO(a2[3][1], a1, 14336);
        __builtin_amdgcn_sched_barrier(0);
        __builtin_amdgcn_s_setprio(1);
#pragma unroll
        for (int m = 0; m < 4; ++m)
#pragma unroll
            for (int n = 0; n < 2; ++n)
#pragma unroll
                for (int kk = 0; kk < 2; ++kk)
                    acc[m][n + 2] = __builtin_amdgcn_mfma_f32_16x16x32_bf16(BC(aR[m][kk]), BC(bB[n][kk]), acc[m][n + 2], 0, 0, 0);
        __builtin_amdgcn_s_setprio(0);
        __builtin_amdgcn_s_barrier();

        // ---- P2
        asm volatile("s_waitcnt lgkmcnt(0)");
        __builtin_amdgcn_sched_barrier(0);
        if (t + 2 < NT) { stageB(t + 2, 0); stageB(t + 2, 1); }
        __builtin_amdgcn_sched_barrier(0);
        __builtin_amdgcn_s_setprio(1);
#pragma unroll
        for (int m = 0; m < 4; ++m)
#pragma unroll
            for (int n = 0; n < 2; ++n)
#pragma unroll
                for (int kk = 0; kk < 2; ++kk)
                    acc[m + 4][n] = __builtin_amdgcn_mfma_f32_16x16x32_bf16(BC(a2[m][kk]), BC(bA[n][kk]), acc[m + 4][n], 0, 0, 0);
        __builtin_amdgcn_s_setprio(0);
        if (t + 2 < NT)        { asm volatile("s_waitcnt vmcnt(4)"); }
        else if (t + 2 == NT)  { asm volatile("s_waitcnt vmcnt(0)"); }
        __builtin_amdgcn_s_barrier();

        // ---- P3
        if (t + 1 < NT) {
            const unsigned na0 = cbn + baseA[0], na1 = cbn + baseA[1];
            const unsigned nb0 = cbn + baseB[0], nb1 = cbn + baseB[1];
            DSRO(aR[0][0], na0, 0);    DSRO(aR[1][0], na0, 2048);
            DSRO(aR[2][0], na0, 4096); DSRO(aR[3][0], na0, 6144);
            DSRO(aR[0][1], na1, 0);    DSRO(aR[1][1], na1, 2048);
            DSRO(aR[2][1], na1, 4096); DSRO(aR[3][1], na1, 6144);
            DSRO(bA[0][0], nb0, 0);    DSRO(bA[1][0], nb0, 2048);
            DSRO(bA[0][1], nb1, 0);    DSRO(bA[1][1], nb1, 2048);
        }
        if (t + 2 < NT) { stageA(t + 2, 0); stageA(t + 2, 1); }
        __builtin_amdgcn_sched_barrier(0);
        __builtin_amdgcn_s_setprio(1);
#pragma unroll
        for (int m = 0; m < 4; ++m)
#pragma unroll
            for (int n = 0; n < 2; ++n)
#pragma unroll
                for (int kk = 0; kk < 2; ++kk)
                    acc[m + 4][n + 2] = __builtin_amdgcn_mfma_f32_16x16x32_bf16(BC(a2[m][kk]), BC(bB[n][kk]), acc[m + 4][n + 2], 0, 0, 0);
        __builtin_amdgcn_s_setprio(0);
        cb = cbn;
    }

    if (!trans_out) {
        if (cmode == 1) {
            unsigned char* C8 = (unsigned char*)C;
#pragma unroll
            for (int n = 0; n < 4; ++n) {
                const int oc = o0 + wn * 64 + n * 16 + l16;
                const float bv = bias[oc];
#pragma unroll
                for (int m = 0; m < 8; ++m)
#pragma unroll
                    for (int r = 0; r < 4; ++r) {
                        const int nr = n0 + wm * 128 + m * 16 + l4 * 4 + r;
                        C8[(size_t)nr * ldc + coff + oc] = f2e4m3(acc[m][n][r] + bv);
                    }
            }
        } else {
#pragma unroll
            for (int n = 0; n < 4; ++n) {
                const int oc = o0 + wn * 64 + n * 16 + l16;
                const float bv = bias[oc];
#pragma unroll
                for (int m = 0; m < 8; ++m)
#pragma unroll
                    for (int r = 0; r < 4; ++r) {
                        const int nr = n0 + wm * 128 + m * 16 + l4 * 4 + r;
                        C[(size_t)nr * ldc + coff + oc] = __float2bfloat16(acc[m][n][r] + bv);
                    }
            }
        }
    } else {
        __syncthreads();
#pragma unroll
        for (int n = 0; n < 4; ++n) {
            const int ocl = wn * 64 + n * 16 + l16;
            const float bv = bias[o0 + ocl];
#pragma unroll
            for (int m = 0; m < 8; ++m)
#pragma unroll
                for (int r = 0; r < 4; ++r) {
                    const int nrow = wm * 128 + m * 16 + l4 * 4 + r;
                    const unsigned phys = (unsigned)nrow * 512u
                        + (((unsigned)ocl * 2u) ^ (((unsigned)(nrow & 7)) << 4));
                    *(unsigned short*)(smem + phys) = f2bf(acc[m][n][r] + bv);
                }
        }
        __syncthreads();
        const int ol = tid >> 1;
        const int nh = (tid & 1) * 128;
        __hip_bfloat16* dst = C + (size_t)(coff + o0 + ol) * ldc + n0 + nh;
#pragma unroll
        for (int j8 = 0; j8 < 16; ++j8) {
            u16x8_t v;
#pragma unroll
            for (int e = 0; e < 8; ++e) {
                const int n2 = nh + j8 * 8 + e;
                v[e] = *(const unsigned short*)(smem + (unsigned)n2 * 512u
                        + ((((unsigned)ol * 2u) ^ ((unsigned)e << 4))));
            }
            *(u16x8_t*)((unsigned short*)dst + j8 * 8) = v;
        }
    }
#undef DSRO
#undef BC
}

// ---------------------------------------------------------------------------
// gemm_f8: 128x128 tile, 4 waves (2x2), per-wave 64x64, MX-fp8 K=64/instr.
// A [M][lda] e4m3, B [N][ldb] e4m3, C bf16 [M][ldc] = A·B^T + bias.
// Double-buffered 32KB LDS, 3 blocks/CU; scales fixed at 1.0 (0x7F bytes).
// LDS chunk swizzle: cidx ^= (row&3)^((row>>2)&3), applied stage-src + read.
// ---------------------------------------------------------------------------
__global__ __launch_bounds__(256, 3)
void gemm_f8(const unsigned char* __restrict__ A, int lda,
             const unsigned char* __restrict__ B, int ldb,
             const float* __restrict__ bias,
             __hip_bfloat16* __restrict__ C, int ldc,
             int K, int NO)
{
    __shared__ __align__(16) unsigned char smem[32768];
    const int tid  = threadIdx.x;
    const int lane = tid & 63;
    const int wave = tid >> 6;
    const int wm = wave >> 1, wn = wave & 1;
    const int l31 = lane & 31;
    const int h   = lane >> 5;

    const int per  = gridDim.x >> 3;
    const int flat = (blockIdx.x & 7) * per + (blockIdx.x >> 3);
    const int nt = flat / NO, ot = flat % NO;
    const int n0 = nt * 128, o0 = ot * 128;
    const int NT = K >> 6;

    auto stage = [&](int t, unsigned bufb) {
#pragma unroll
        for (int p = 0; p < 2; ++p) {
            const int f   = tid + p * 256;
            const int row = f >> 2, cidx = f & 3;
            const int gch = ((cidx ^ (row & 3) ^ ((row >> 2) & 3)) << 4);
            const unsigned char* ga = A + (size_t)(n0 + row) * lda + t * 64 + gch;
            __builtin_amdgcn_global_load_lds(
                (const __attribute__((address_space(1))) unsigned int*)ga,
                (__attribute__((address_space(3))) unsigned int*)(smem + bufb + f * 16),
                16, 0, 0);
            const unsigned char* gb = B + (size_t)(o0 + row) * ldb + t * 64 + gch;
            __builtin_amdgcn_global_load_lds(
                (const __attribute__((address_space(1))) unsigned int*)gb,
                (__attribute__((address_space(3))) unsigned int*)(smem + bufb + 8192u + f * 16),
                16, 0, 0);
        }
    };

    f32x16_t acc[2][2];
#pragma unroll
    for (int mf = 0; mf < 2; ++mf)
#pragma unroll
        for (int nf = 0; nf < 2; ++nf)
#pragma unroll
            for (int e = 0; e < 16; ++e) acc[mf][nf][e] = 0.f;

    stage(0, 0);
    __syncthreads();

    for (int t = 0; t < NT; ++t) {
        const unsigned bb = (unsigned)((t & 1) << 14);
        if (t + 1 < NT) stage(t + 1, bb ^ 16384u);

        i32x8_t af[2], bf[2];
#pragma unroll
        for (int mf = 0; mf < 2; ++mf) {
            const int r = wm * 64 + mf * 32 + l31;
            const int s = (r & 3) ^ ((r >> 2) & 3);
            const unsigned base = bb + (unsigned)(r << 6);
            i32x4_t lo = *(const i32x4_t*)(smem + base + ((((h << 1) | 0) ^ s) << 4));
            i32x4_t hi = *(const i32x4_t*)(smem + base + ((((h << 1) | 1) ^ s) << 4));
            af[mf][0] = lo[0]; af[mf][1] = lo[1]; af[mf][2] = lo[2]; af[mf][3] = lo[3];
            af[mf][4] = hi[0]; af[mf][5] = hi[1]; af[mf][6] = hi[2]; af[mf][7] = hi[3];
        }
#pragma unroll
        for (int nf = 0; nf < 2; ++nf) {
            const int r = wn * 64 + nf * 32 + l31;
            const int s = (r & 3) ^ ((r >> 2) & 3);
            const unsigned base = bb + 8192u + (unsigned)(r << 6);
            i32x4_t lo = *(const i32x4_t*)(smem + base + ((((h << 1) | 0) ^ s) << 4));
            i32x4_t hi = *(const i32x4_t*)(smem + base + ((((h << 1) | 1) ^ s) << 4));
            bf[nf][0] = lo[0]; bf[nf][1] = lo[1]; bf[nf][2] = lo[2]; bf[nf][3] = lo[3];
            bf[nf][4] = hi[0]; bf[nf][5] = hi[1]; bf[nf][6] = hi[2]; bf[nf][7] = hi[3];
        }
#pragma unroll
        for (int mf = 0; mf < 2; ++mf)
#pragma unroll
            for (int nf = 0; nf < 2; ++nf)
                acc[mf][nf] = __builtin_amdgcn_mfma_scale_f32_32x32x64_f8f6f4(
                    af[mf], bf[nf], acc[mf][nf],
                    0, 0,                       // cbsz=fp8, blgp=fp8
                    0, 0x7F7F7F7F,              // opselA, scaleA = 1.0
                    0, 0x7F7F7F7F);             // opselB, scaleB = 1.0
        __syncthreads();
    }

    // C/D 32x32 layout: col = lane&31, row = (reg&3) + 8*(reg>>2) + 4*(lane>>5)
#pragma unroll
    for (int nf = 0; nf < 2; ++nf) {
        const int col = o0 + wn * 64 + nf * 32 + l31;
        const float bv = bias[col];
#pragma unroll
        for (int mf = 0; mf < 2; ++mf)
#pragma unroll
            for (int rg = 0; rg < 16; ++rg) {
                const int row = n0 + wm * 64 + mf * 32 + (rg & 3) + ((rg >> 2) << 3) + (h << 2);
                C[(size_t)row * ldc + col] = __float2bfloat16(acc[mf][nf][rg] + bv);
            }
    }
}

// ---------------------------------------------------------------------------
// final_v2: G^T [NPIX][1536] n-major, Xb [3][NPIX][512] bf16 (= gamma_i x_i).
// ---------------------------------------------------------------------------
__global__ __launch_bounds__(256)
void final_v2(const __hip_bfloat16* __restrict__ G,
              const __hip_bfloat16* __restrict__ Xb,
              float* __restrict__ out)
{
    __shared__ float tile[64][68];
    const int n0  = blockIdx.x * 64;
    const int b   = n0 >> 10;
    const int hw0 = n0 & (HWSZ - 1);
    const int t   = threadIdx.x;
    const int nl  = t >> 2;
    const int cg  = (t & 3) * 16;
    const int n   = n0 + nl;
    const unsigned short* gr = (const unsigned short*)G + (size_t)n * 1536;
    const unsigned short* xr = (const unsigned short*)Xb + (size_t)n * 512;
    const int seg = t & 3;
    float* outb = out + (size_t)b * (DCH * HWSZ) + hw0;

    for (int c0 = 0; c0 < DCH; c0 += 64) {
        u16x8_t gl[3][2], xl[3][2];
#pragma unroll
        for (int i = 0; i < 3; ++i) {
            gl[i][0] = *(const u16x8_t*)(gr + i * 512 + c0 + cg);
            gl[i][1] = *(const u16x8_t*)(gr + i * 512 + c0 + cg + 8);
            xl[i][0] = *(const u16x8_t*)(xr + (size_t)i * NPIX * 512 + c0 + cg);
            xl[i][1] = *(const u16x8_t*)(xr + (size_t)i * NPIX * 512 + c0 + cg + 8);
        }
#pragma unroll
        for (int e = 0; e < 16; ++e) {
            const int hh = e >> 3, w = e & 7;
            const float s0 = bf2f(gl[0][hh][w]);
            const float s1 = bf2f(gl[1][hh][w]);
            const float s2 = bf2f(gl[2][hh][w]);
            const float g0 = 1.0f / (1.0f + __expf(-s0));
            const float g1 = 1.0f / (1.0f + __expf(-s1));
            const float g2 = 1.0f / (1.0f + __expf(-s2));
            const float e0 = __expf(g0), e1 = __expf(g1), e2 = __expf(g2);
            const float inv = 1.0f / (e0 + e1 + e2);
            tile[cg + e][nl] = inv * (e0 * bf2f(xl[0][hh][w])
                                    + e1 * bf2f(xl[1][hh][w])
                                    + e2 * bf2f(xl[2][hh][w]));
        }
        __syncthreads();
#pragma unroll
        for (int j4 = 0; j4 < 4; ++j4) {
            float4 v = *(const float4*)&tile[nl][seg * 16 + j4 * 4];
            *(float4*)(outb + (size_t)(c0 + nl) * HWSZ + seg * 16 + j4 * 4) = v;
        }
        __syncthreads();
    }
}

// ---------------------------------------------------------------------------
// final (fallback): G channel-major [1536][NPIX], x fp32 natural layout.
// ---------------------------------------------------------------------------
__global__ __launch_bounds__(256)
void final_fuse(const __hip_bfloat16* __restrict__ G,
                const float* __restrict__ x0, const float* __restrict__ x1,
                const float* __restrict__ x2,
                const float* __restrict__ gp0, const float* __restrict__ gp1,
                const float* __restrict__ gp2,
                float* __restrict__ out)
{
    const int n  = blockIdx.x * 256 + threadIdx.x;
    const int b  = n >> 10;
    const int hw = n & (HWSZ - 1);
    const int c0 = blockIdx.y * 64;
    const float ga0 = gp0[0], ga1 = gp1[0], ga2 = gp2[0];
    for (int cc = 0; cc < 64; ++cc) {
        const int c = c0 + cc;
        const float s0 = __bfloat162float(G[(size_t)c * NPIX + n]);
        const float s1 = __bfloat162float(G[(size_t)(c + DCH) * NPIX + n]);
        const float s2 = __bfloat162float(G[(size_t)(c + 2 * DCH) * NPIX + n]);
        const float g0v = 1.0f / (1.0f + __expf(-s0));
        const float g1v = 1.0f / (1.0f + __expf(-s1));
        const float g2v = 1.0f / (1.0f + __expf(-s2));
        const float e0 = __expf(g0v), e1 = __expf(g1v), e2 = __expf(g2v);
        const float inv = 1.0f / (e0 + e1 + e2);
        const size_t xo = (size_t)b * (DCH * HWSZ) + (size_t)c * HWSZ + hw;
        out[xo] = inv * (e0 * ga0 * x0[xo] + e1 * ga1 * x1[xo] + e2 * ga2 * x2[xo]);
    }
}

// ---------------------------------------------------------------------------
extern "C" void kernel_launch(void* const* d_in, const int* in_sizes, int n_in,
                              void* d_out, int out_size, void* d_ws, size_t ws_size,
                              hipStream_t stream)
{
    const float* out0   = (const float*)d_in[0];
    const float* out1   = (const float*)d_in[1];
    const float* out2   = (const float*)d_in[2];
    const float* gamma0 = (const float*)d_in[3];
    const float* gamma1 = (const float*)d_in[4];
    const float* gamma2 = (const float*)d_in[5];
    const float* W_in1  = (const float*)d_in[6];
    const float* W_in2  = (const float*)d_in[8];
    const float* W_in3  = (const float*)d_in[10];
    const float* b_in1  = (const float*)d_in[7];
    const float* b_in2  = (const float*)d_in[9];
    const float* b_in3  = (const float*)d_in[11];
    const float* W_tr   = (const float*)d_in[12];
    const float* b_tr   = (const float*)d_in[13];
    const float* W_o1   = (const float*)d_in[14];
    const float* b_o1   = (const float*)d_in[15];
    const float* W_o2   = (const float*)d_in[16];
    const float* b_o2   = (const float*)d_in[17];
    const float* W_o3   = (const float*)d_in[18];
    const float* b_o3   = (const float*)d_in[19];
    float* outp = (float*)d_out;

    unsigned char* ws = (unsigned char*)d_ws;
    const size_t SZ_ACT   = (size_t)3 * NPIX * DCH * 2;     // 100663296
    const size_t WB_BYTES = (size_t)(6 * WSQ + WTR) * 2;    // 7864320
    const size_t NEED3    = 3 * SZ_ACT + WB_BYTES + 4096 * 4;
    const bool   big      = (ws_size >= NEED3);

    __hip_bfloat16* buf0 = (__hip_bfloat16*)ws;
    __hip_bfloat16* buf1 = (__hip_bfloat16*)(ws + SZ_ACT);
    __hip_bfloat16* buf2 = big ? (__hip_bfloat16*)(ws + 2 * SZ_ACT) : buf0;
    unsigned char*  wtop = ws + (big ? 3 : 2) * SZ_ACT;
    __hip_bfloat16* Wb     = (__hip_bfloat16*)wtop;
    __hip_bfloat16* Wb_tr  = Wb + 3 * WSQ;                  // fp8 region (aliased)
    unsigned char*  Wtr8   = (unsigned char*)Wb_tr;
    __hip_bfloat16* Wb_o   = Wb_tr + WTR;
    float*          biasWS = (float*)(wtop + WB_BYTES);     // [6][512]

    const int CVT_TOTAL = 6 * WSQ + WTR;
    cvt_all<<<CVT_TOTAL / 1024 + 1, 256, 0, stream>>>(
        W_in1, W_in2, W_in3, W_tr, W_o1, W_o2, W_o3, Wb,
        b_in1, b_in2, b_in3, b_o1, b_o2, b_o3, biasWS);

    stage_transpose<<<dim3(16, 8, 96), 256, 0, stream>>>(out0, out1, out2,
                                                         gamma0, gamma1, gamma2, buf0);

    // GEMM-A (batched 3 branches, bf16 in, FP8 OUT): XbT x W_in_i -> Hcat8[n][br*512+o]
    gemm256<<<dim3(768), 512, 0, stream>>>(
        buf0, DCH, Wb, DCH, biasWS,
        buf1, 3 * DCH, 0, DCH, 2, 256, NPIX * DCH, WSQ, DCH, DCH, 0, 1);

    // GEMM-B (MX-fp8): Hcat8 x Wtr8 -> H_traT bf16 (buf2 big / buf0 fallback)
    gemm_f8<<<dim3((NPIX / 128) * 12), 256, 0, stream>>>(
        (const unsigned char*)buf1, 3 * DCH, Wtr8, 3 * DCH, b_tr,
        buf2, 3 * DCH, 3 * DCH, 12);

    if (big) {
        // GEMM-C (batched, bf16): H_traT[:, br*512:] x W_out_i -> G^T[n][br*512+o]
        gemm256<<<dim3(768), 512, 0, stream>>>(
            buf2, 3 * DCH, Wb_o, DCH, biasWS + 3 * DCH,
            buf1, 3 * DCH, 0, DCH, 2, 256, DCH, WSQ, DCH, DCH, 0, 0);
        final_v2<<<dim3(NPIX / 64), 256, 0, stream>>>(buf1, buf0, outp);
    } else {
        gemm256<<<dim3(768), 512, 0, stream>>>(
            buf0, 3 * DCH, Wb_o, DCH, biasWS + 3 * DCH,
            buf1, NPIX, 0, DCH, 2, 256, DCH, WSQ, DCH, DCH, 1, 0);
        final_fuse<<<dim3(NPIX / 256, DCH / 64), 256, 0, stream>>>(
            buf1, out0, out1, out2, gamma0, gamma1, gamma2, outp);
    }
}

// Round 9
// 380.865 us; speedup vs baseline: 1.5951x; 1.1138x over previous
//
#include <hip/hip_runtime.h>
#include <hip/hip_bf16.h>

#define NPIX 32768
#define DCH 512
#define HWSZ 1024
#define WSQ (DCH * DCH)
#define WTR (3 * DCH * 3 * DCH)

typedef __bf16 bf16x8_t __attribute__((ext_vector_type(8)));
typedef float f32x4_t __attribute__((ext_vector_type(4)));
typedef float f32x16_t __attribute__((ext_vector_type(16)));
typedef int i32x4_t __attribute__((ext_vector_type(4)));
typedef int i32x8_t __attribute__((ext_vector_type(8)));
typedef unsigned short u16x8_t __attribute__((ext_vector_type(8)));
typedef unsigned short u16x4_t __attribute__((ext_vector_type(4)));

static __device__ __forceinline__ unsigned short f2bf(float f) {
    return __builtin_bit_cast(unsigned short, __float2bfloat16(f));
}
static __device__ __forceinline__ float bf2f(unsigned short u) {
    unsigned v = (unsigned)u << 16;
    return __builtin_bit_cast(float, v);
}

// ---------------------------------------------------------------------------
// Weights: in1-3 -> bf16, tr -> fp8 e4m3 (HW cvt), o1-3 -> bf16. Last: biases.
// ---------------------------------------------------------------------------
__global__ __launch_bounds__(256)
void cvt_all(const float* __restrict__ w0, const float* __restrict__ w1,
             const float* __restrict__ w2, const float* __restrict__ w3,
             const float* __restrict__ w4, const float* __restrict__ w5,
             const float* __restrict__ w6, __hip_bfloat16* __restrict__ d,
             const float* __restrict__ b0, const float* __restrict__ b1,
             const float* __restrict__ b2, const float* __restrict__ b3,
             const float* __restrict__ b4, const float* __restrict__ b5,
             float* __restrict__ biasd)
{
    if (blockIdx.x == gridDim.x - 1) {
        for (int idx = threadIdx.x; idx < 3072; idx += 256) {
            const int r = idx >> 9, off = idx & 511;
            const float* s = (r == 0) ? b0 : (r == 1) ? b1 : (r == 2) ? b2
                           : (r == 3) ? b3 : (r == 4) ? b4 : b5;
            biasd[idx] = s[off];
        }
        return;
    }
    const int i = (blockIdx.x * 256 + threadIdx.x) * 4;
    if (i < 3 * WSQ) {
        int r = i >> 18;
        const float* src = (r == 0) ? w0 : ((r == 1) ? w1 : w2);
        int off = i - r * WSQ;
        float4 f = *(const float4*)(src + off);
        u16x4_t v;
        v[0] = f2bf(f.x); v[1] = f2bf(f.y); v[2] = f2bf(f.z); v[3] = f2bf(f.w);
        *(u16x4_t*)((unsigned short*)d + i) = v;
    } else if (i < 3 * WSQ + WTR) {
        int off = i - 3 * WSQ;
        float4 f = *(const float4*)(w3 + off);
        int dw = __builtin_amdgcn_cvt_pk_fp8_f32(f.x, f.y, 0, false);
        dw     = __builtin_amdgcn_cvt_pk_fp8_f32(f.z, f.w, dw, true);
        unsigned char* d8 = (unsigned char*)(d + 3 * WSQ);   // Wtr8 region
        *(int*)(d8 + off) = dw;
    } else {
        int j = i - 3 * WSQ - WTR;
        int r = j >> 18;
        const float* src = (r == 0) ? w4 : ((r == 1) ? w5 : w6);
        int off = j - r * WSQ;
        float4 f = *(const float4*)(src + off);
        u16x4_t v;
        v[0] = f2bf(f.x); v[1] = f2bf(f.y); v[2] = f2bf(f.z); v[3] = f2bf(f.w);
        *(u16x4_t*)((unsigned short*)d + i) = v;
    }
}

// ---------------------------------------------------------------------------
// Stage: X[b][c][hw] fp32 -> XbT[branch][n][c] bf16 with gamma scale.
// ---------------------------------------------------------------------------
__global__ __launch_bounds__(256)
void stage_transpose(const float* __restrict__ x0, const float* __restrict__ x1,
                     const float* __restrict__ x2,
                     const float* __restrict__ gp0, const float* __restrict__ gp1,
                     const float* __restrict__ gp2,
                     __hip_bfloat16* __restrict__ XbT)
{
    __shared__ float tile[64][65];
    const int hw0 = blockIdx.x * 64;
    const int c0  = blockIdx.y * 64;
    const int bz  = blockIdx.z;
    const int br  = bz >> 5;
    const int b   = bz & 31;
    const float* x = (br == 0) ? x0 : ((br == 1) ? x1 : x2);
    const float g  = ((br == 0) ? gp0 : ((br == 1) ? gp1 : gp2))[0];
    const int t = threadIdx.x;

    const int hwi = t & 63;
    const int cb  = t >> 6;
    const float* src = x + (size_t)b * (DCH * HWSZ) + (size_t)c0 * HWSZ + hw0;
#pragma unroll
    for (int i = 0; i < 16; ++i) {
        const int ci = cb + i * 4;
        tile[ci][hwi] = g * src[(size_t)ci * HWSZ + hwi];
    }
    __syncthreads();

    const int hwr = t >> 2;
    const int cch = (t & 3) * 16;
    __hip_bfloat16* dst = XbT + (size_t)((size_t)br * NPIX + b * HWSZ + hw0 + hwr) * DCH + c0 + cch;
    u16x8_t v0, v1;
#pragma unroll
    for (int e = 0; e < 8; ++e) v0[e] = f2bf(tile[cch + e][hwr]);
#pragma unroll
    for (int e = 0; e < 8; ++e) v1[e] = f2bf(tile[cch + 8 + e][hwr]);
    *(u16x8_t*)dst = v0;
    *((u16x8_t*)dst + 1) = v1;
}

// ---------------------------------------------------------------------------
// 256x256 pipelined bf16 NT GEMM (R7 K-loop, unchanged) + batched decode.
// cmode=0: bf16 out. cmode=1: fp8 e4m3 out via HW v_cvt_pk_fp8_f32.
// trans_out=1: channel-major bf16 (fallback path).
// ---------------------------------------------------------------------------
__global__ __launch_bounds__(512, 2)
void gemm256(const __hip_bfloat16* __restrict__ A, int lda,
             const __hip_bfloat16* __restrict__ B, int ldb,
             const float* __restrict__ bias,
             __hip_bfloat16* __restrict__ C, int ldc, int coff0,
             int K, int NO, int TPB, int brA, int brB, int bstride,
             int cstride, int trans_out, int cmode)
{
    __shared__ __align__(16) unsigned char smem[131072];
    const int tid  = threadIdx.x;
    const int lane = tid & 63;
    const int wave = tid >> 6;
    const int wm   = wave >> 2;
    const int wn   = wave & 3;
    const int l16  = lane & 15;
    const int l4   = lane >> 4;

    const int per  = gridDim.x >> 3;
    const int flat = (blockIdx.x & 7) * per + (blockIdx.x >> 3);
    const int br   = flat / TPB;
    const int rem  = flat - br * TPB;
    const int nt   = rem / NO;
    const int ot   = rem - nt * NO;
    const int n0 = nt * 256;
    const int o0 = ot * 256;
    const int NT = K >> 6;

    A    += (size_t)br * (size_t)brA;
    B    += (size_t)br * (size_t)brB;
    bias += br * bstride;
    const int coff = coff0 + br * cstride;

    const unsigned xorv = (unsigned)((l16 & 7) << 4);
    unsigned baseA[2], baseB[2];
#pragma unroll
    for (int kk = 0; kk < 2; ++kk) {
        const unsigned ko = ((unsigned)(kk * 64 + l4 * 16)) ^ xorv;
        baseA[kk] = (unsigned)((wm * 128 + l16) * 128) + ko;
        baseB[kk] = 32768u + (unsigned)((wn * 64 + l16) * 128) + ko;
    }

    const int rr  = lane >> 3;
    const int kel = 8 * ((lane & 7) ^ rr);

    auto stageA = [&](int t, int half) {
        const unsigned dst = (unsigned)((t & 1) * 65536 + half * 16384 + wave * 2048);
        const __hip_bfloat16* g = A + (size_t)(n0 + half * 128 + wave * 16 + rr) * lda + t * 64 + kel;
#pragma unroll
        for (int s = 0; s < 2; ++s) {
            __builtin_amdgcn_global_load_lds(
                (const __attribute__((address_space(1))) unsigned int*)(g + (size_t)s * 8 * lda),
                (__attribute__((address_space(3))) unsigned int*)(smem + dst + s * 1024),
                16, 0, 0);
        }
    };
    auto stageB = [&](int t, int half) {
        const unsigned dst = (unsigned)((t & 1) * 65536 + 32768 + half * 16384 + wave * 2048);
        const __hip_bfloat16* g = B + (size_t)(o0 + half * 128 + wave * 16 + rr) * ldb + t * 64 + kel;
#pragma unroll
        for (int s = 0; s < 2; ++s) {
            __builtin_amdgcn_global_load_lds(
                (const __attribute__((address_space(1))) unsigned int*)(g + (size_t)s * 8 * ldb),
                (__attribute__((address_space(3))) unsigned int*)(smem + dst + s * 1024),
                16, 0, 0);
        }
    };

#define DSRO(dst, addr, OFF) \
    asm volatile("ds_read_b128 %0, %1 offset:" #OFF : "=v"(dst) : "v"(addr))
#define BC(x) __builtin_bit_cast(bf16x8_t, x)

    stageA(0, 0); stageA(0, 1); stageB(0, 0); stageB(0, 1);
    stageA(1, 0); stageA(1, 1); stageB(1, 0); stageB(1, 1);
    asm volatile("s_waitcnt vmcnt(8)");
    __builtin_amdgcn_s_barrier();

    f32x4_t aR[4][2], a2[4][2], bA[2][2], bB[2][2];
    f32x4_t acc[8][4];
#pragma unroll
    for (int m = 0; m < 8; ++m)
#pragma unroll
        for (int n = 0; n < 4; ++n) acc[m][n] = (f32x4_t){0.f, 0.f, 0.f, 0.f};

    {
        unsigned a0 = baseA[0], a1 = baseA[1], b0 = baseB[0], b1 = baseB[1];
        DSRO(aR[0][0], a0, 0);    DSRO(aR[1][0], a0, 2048);
        DSRO(aR[2][0], a0, 4096); DSRO(aR[3][0], a0, 6144);
        DSRO(aR[0][1], a1, 0);    DSRO(aR[1][1], a1, 2048);
        DSRO(aR[2][1], a1, 4096); DSRO(aR[3][1], a1, 6144);
        DSRO(bA[0][0], b0, 0);    DSRO(bA[1][0], b0, 2048);
        DSRO(bA[0][1], b1, 0);    DSRO(bA[1][1], b1, 2048);
    }

    unsigned cb = 0;
    for (int t = 0; t < NT; ++t) {
        const unsigned cbn = cb ^ 65536u;
        const unsigned a0 = cb + baseA[0], a1 = cb + baseA[1];
        const unsigned b0 = cb + baseB[0], b1 = cb + baseB[1];

        // ---- P0
        asm volatile("s_waitcnt lgkmcnt(0)");
        __builtin_amdgcn_sched_barrier(0);
        DSRO(bB[0][0], b0, 4096); DSRO(bB[1][0], b0, 6144);
        DSRO(bB[0][1], b1, 4096); DSRO(bB[1][1], b1, 6144);
        __builtin_amdgcn_sched_barrier(0);
        __builtin_amdgcn_s_setprio(1);
#pragma unroll
        for (int m = 0; m < 4; ++m)
#pragma unroll
            for (int n = 0; n < 2; ++n)
#pragma unroll
                for (int kk = 0; kk < 2; ++kk)
                    acc[m][n] = __builtin_amdgcn_mfma_f32_16x16x32_bf16(BC(aR[m][kk]), BC(bA[n][kk]), acc[m][n], 0, 0, 0);
        __builtin_amdgcn_s_setprio(0);
        __builtin_amdgcn_s_barrier();

        // ---- P1
        asm volatile("s_waitcnt lgkmcnt(0)");
        __builtin_amdgcn_sched_barrier(0);
        DSRO(a2[0][0], a0, 8192);  DSRO(a2[1][0], a0, 10240);
        DSRO(a2[2][0], a0, 12288); DSRO(a2[3][0], a0, 14336);
        DSRO(a2[0][1], a1, 8192);  DSRO(a2[1][1], a1, 10240);
        DSRO(a2[2][1], a1, 12288); DSRO(a2[3][1], a1, 14336);
        __builtin_amdgcn_sched_barrier(0);
        __builtin_amdgcn_s_setprio(1);
#pragma unroll
        for (int m = 0; m < 4; ++m)
#pragma unroll
            for (int n = 0; n < 2; ++n)
#pragma unroll
                for (int kk = 0; kk < 2; ++kk)
                    acc[m][n + 2] = __builtin_amdgcn_mfma_f32_16x16x32_bf16(BC(aR[m][kk]), BC(bB[n][kk]), acc[m][n + 2], 0, 0, 0);
        __builtin_amdgcn_s_setprio(0);
        __builtin_amdgcn_s_barrier();

        // ---- P2
        asm volatile("s_waitcnt lgkmcnt(0)");
        __builtin_amdgcn_sched_barrier(0);
        if (t + 2 < NT) { stageB(t + 2, 0); stageB(t + 2, 1); }
        __builtin_amdgcn_sched_barrier(0);
        __builtin_amdgcn_s_setprio(1);
#pragma unroll
        for (int m = 0; m < 4; ++m)
#pragma unroll
            for (int n = 0; n < 2; ++n)
#pragma unroll
                for (int kk = 0; kk < 2; ++kk)
                    acc[m + 4][n] = __builtin_amdgcn_mfma_f32_16x16x32_bf16(BC(a2[m][kk]), BC(bA[n][kk]), acc[m + 4][n], 0, 0, 0);
        __builtin_amdgcn_s_setprio(0);
        if (t + 2 < NT)        { asm volatile("s_waitcnt vmcnt(4)"); }
        else if (t + 2 == NT)  { asm volatile("s_waitcnt vmcnt(0)"); }
        __builtin_amdgcn_s_barrier();

        // ---- P3
        if (t + 1 < NT) {
            const unsigned na0 = cbn + baseA[0], na1 = cbn + baseA[1];
            const unsigned nb0 = cbn + baseB[0], nb1 = cbn + baseB[1];
            DSRO(aR[0][0], na0, 0);    DSRO(aR[1][0], na0, 2048);
            DSRO(aR[2][0], na0, 4096); DSRO(aR[3][0], na0, 6144);
            DSRO(aR[0][1], na1, 0);    DSRO(aR[1][1], na1, 2048);
            DSRO(aR[2][1], na1, 4096); DSRO(aR[3][1], na1, 6144);
            DSRO(bA[0][0], nb0, 0);    DSRO(bA[1][0], nb0, 2048);
            DSRO(bA[0][1], nb1, 0);    DSRO(bA[1][1], nb1, 2048);
        }
        if (t + 2 < NT) { stageA(t + 2, 0); stageA(t + 2, 1); }
        __builtin_amdgcn_sched_barrier(0);
        __builtin_amdgcn_s_setprio(1);
#pragma unroll
        for (int m = 0; m < 4; ++m)
#pragma unroll
            for (int n = 0; n < 2; ++n)
#pragma unroll
                for (int kk = 0; kk < 2; ++kk)
                    acc[m + 4][n + 2] = __builtin_amdgcn_mfma_f32_16x16x32_bf16(BC(a2[m][kk]), BC(bB[n][kk]), acc[m + 4][n + 2], 0, 0, 0);
        __builtin_amdgcn_s_setprio(0);
        cb = cbn;
    }

    if (!trans_out) {
        if (cmode == 1) {
            // HW packed fp8 convert: 2x cvt_pk per (m,n) -> dword = 4 rows x 1 col
            unsigned char* C8 = (unsigned char*)C;
#pragma unroll
            for (int n = 0; n < 4; ++n) {
                const int oc = o0 + wn * 64 + n * 16 + l16;
                const float bv = bias[oc];
#pragma unroll
                for (int m = 0; m < 8; ++m) {
                    int dw = __builtin_amdgcn_cvt_pk_fp8_f32(acc[m][n][0] + bv, acc[m][n][1] + bv, 0, false);
                    dw     = __builtin_amdgcn_cvt_pk_fp8_f32(acc[m][n][2] + bv, acc[m][n][3] + bv, dw, true);
                    const int nr = n0 + wm * 128 + m * 16 + l4 * 4;
                    const size_t base = (size_t)nr * ldc + coff + oc;
                    const unsigned u = (unsigned)dw;
                    C8[base]           = (unsigned char)u;
                    C8[base + ldc]     = (unsigned char)(u >> 8);
                    C8[base + 2 * ldc] = (unsigned char)(u >> 16);
                    C8[base + 3 * ldc] = (unsigned char)(u >> 24);
                }
            }
        } else {
#pragma unroll
            for (int n = 0; n < 4; ++n) {
                const int oc = o0 + wn * 64 + n * 16 + l16;
                const float bv = bias[oc];
#pragma unroll
                for (int m = 0; m < 8; ++m)
#pragma unroll
                    for (int r = 0; r < 4; ++r) {
                        const int nr = n0 + wm * 128 + m * 16 + l4 * 4 + r;
                        C[(size_t)nr * ldc + coff + oc] = __float2bfloat16(acc[m][n][r] + bv);
                    }
            }
        }
    } else {
        __syncthreads();
#pragma unroll
        for (int n = 0; n < 4; ++n) {
            const int ocl = wn * 64 + n * 16 + l16;
            const float bv = bias[o0 + ocl];
#pragma unroll
            for (int m = 0; m < 8; ++m)
#pragma unroll
                for (int r = 0; r < 4; ++r) {
                    const int nrow = wm * 128 + m * 16 + l4 * 4 + r;
                    const unsigned phys = (unsigned)nrow * 512u
                        + (((unsigned)ocl * 2u) ^ (((unsigned)(nrow & 7)) << 4));
                    *(unsigned short*)(smem + phys) = f2bf(acc[m][n][r] + bv);
                }
        }
        __syncthreads();
        const int ol = tid >> 1;
        const int nh = (tid & 1) * 128;
        __hip_bfloat16* dst = C + (size_t)(coff + o0 + ol) * ldc + n0 + nh;
#pragma unroll
        for (int j8 = 0; j8 < 16; ++j8) {
            u16x8_t v;
#pragma unroll
            for (int e = 0; e < 8; ++e) {
                const int n2 = nh + j8 * 8 + e;
                v[e] = *(const unsigned short*)(smem + (unsigned)n2 * 512u
                        + ((((unsigned)ol * 2u) ^ ((unsigned)e << 4))));
            }
            *(u16x8_t*)((unsigned short*)dst + j8 * 8) = v;
        }
    }
#undef DSRO
#undef BC
}

// ---------------------------------------------------------------------------
// gemm_f8: 128x128 tile, 4 waves (2x2), per-wave 64x64, MX-fp8 K=64/instr.
// A [M][lda] e4m3, B [N][ldb] e4m3, C bf16 [M][ldc] = A·B^T + bias.
// Double-buffered 32KB LDS, 3 blocks/CU; scales fixed at 1.0 (0x7F bytes).
// LDS chunk swizzle: cidx ^= (row&3)^((row>>2)&3), applied stage-src + read.
// ---------------------------------------------------------------------------
__global__ __launch_bounds__(256, 3)
void gemm_f8(const unsigned char* __restrict__ A, int lda,
             const unsigned char* __restrict__ B, int ldb,
             const float* __restrict__ bias,
             __hip_bfloat16* __restrict__ C, int ldc,
             int K, int NO)
{
    __shared__ __align__(16) unsigned char smem[32768];
    const int tid  = threadIdx.x;
    const int lane = tid & 63;
    const int wave = tid >> 6;
    const int wm = wave >> 1, wn = wave & 1;
    const int l31 = lane & 31;
    const int h   = lane >> 5;

    const int per  = gridDim.x >> 3;
    const int flat = (blockIdx.x & 7) * per + (blockIdx.x >> 3);
    const int nt = flat / NO, ot = flat % NO;
    const int n0 = nt * 128, o0 = ot * 128;
    const int NT = K >> 6;

    auto stage = [&](int t, unsigned bufb) {
#pragma unroll
        for (int p = 0; p < 2; ++p) {
            const int f   = tid + p * 256;
            const int row = f >> 2, cidx = f & 3;
            const int gch = ((cidx ^ (row & 3) ^ ((row >> 2) & 3)) << 4);
            const unsigned char* ga = A + (size_t)(n0 + row) * lda + t * 64 + gch;
            __builtin_amdgcn_global_load_lds(
                (const __attribute__((address_space(1))) unsigned int*)ga,
                (__attribute__((address_space(3))) unsigned int*)(smem + bufb + f * 16),
                16, 0, 0);
            const unsigned char* gb = B + (size_t)(o0 + row) * ldb + t * 64 + gch;
            __builtin_amdgcn_global_load_lds(
                (const __attribute__((address_space(1))) unsigned int*)gb,
                (__attribute__((address_space(3))) unsigned int*)(smem + bufb + 8192u + f * 16),
                16, 0, 0);
        }
    };

    f32x16_t acc[2][2];
#pragma unroll
    for (int mf = 0; mf < 2; ++mf)
#pragma unroll
        for (int nf = 0; nf < 2; ++nf)
#pragma unroll
            for (int e = 0; e < 16; ++e) acc[mf][nf][e] = 0.f;

    stage(0, 0);
    __syncthreads();

    for (int t = 0; t < NT; ++t) {
        const unsigned bb = (unsigned)((t & 1) << 14);
        if (t + 1 < NT) stage(t + 1, bb ^ 16384u);

        i32x8_t af[2], bf[2];
#pragma unroll
        for (int mf = 0; mf < 2; ++mf) {
            const int r = wm * 64 + mf * 32 + l31;
            const int s = (r & 3) ^ ((r >> 2) & 3);
            const unsigned base = bb + (unsigned)(r << 6);
            i32x4_t lo = *(const i32x4_t*)(smem + base + ((((h << 1) | 0) ^ s) << 4));
            i32x4_t hi = *(const i32x4_t*)(smem + base + ((((h << 1) | 1) ^ s) << 4));
            af[mf][0] = lo[0]; af[mf][1] = lo[1]; af[mf][2] = lo[2]; af[mf][3] = lo[3];
            af[mf][4] = hi[0]; af[mf][5] = hi[1]; af[mf][6] = hi[2]; af[mf][7] = hi[3];
        }
#pragma unroll
        for (int nf = 0; nf < 2; ++nf) {
            const int r = wn * 64 + nf * 32 + l31;
            const int s = (r & 3) ^ ((r >> 2) & 3);
            const unsigned base = bb + 8192u + (unsigned)(r << 6);
            i32x4_t lo = *(const i32x4_t*)(smem + base + ((((h << 1) | 0) ^ s) << 4));
            i32x4_t hi = *(const i32x4_t*)(smem + base + ((((h << 1) | 1) ^ s) << 4));
            bf[nf][0] = lo[0]; bf[nf][1] = lo[1]; bf[nf][2] = lo[2]; bf[nf][3] = lo[3];
            bf[nf][4] = hi[0]; bf[nf][5] = hi[1]; bf[nf][6] = hi[2]; bf[nf][7] = hi[3];
        }
#pragma unroll
        for (int mf = 0; mf < 2; ++mf)
#pragma unroll
            for (int nf = 0; nf < 2; ++nf)
                acc[mf][nf] = __builtin_amdgcn_mfma_scale_f32_32x32x64_f8f6f4(
                    af[mf], bf[nf], acc[mf][nf],
                    0, 0,                       // cbsz=fp8, blgp=fp8
                    0, 0x7F7F7F7F,              // opselA, scaleA = 1.0
                    0, 0x7F7F7F7F);             // opselB, scaleB = 1.0
        __syncthreads();
    }

    // C/D 32x32 layout: col = lane&31, row = (reg&3) + 8*(reg>>2) + 4*(lane>>5)
#pragma unroll
    for (int nf = 0; nf < 2; ++nf) {
        const int col = o0 + wn * 64 + nf * 32 + l31;
        const float bv = bias[col];
#pragma unroll
        for (int mf = 0; mf < 2; ++mf)
#pragma unroll
            for (int rg = 0; rg < 16; ++rg) {
                const int row = n0 + wm * 64 + mf * 32 + (rg & 3) + ((rg >> 2) << 3) + (h << 2);
                C[(size_t)row * ldc + col] = __float2bfloat16(acc[mf][nf][rg] + bv);
            }
    }
}

// ---------------------------------------------------------------------------
// final_v2: G^T [NPIX][1536] n-major, Xb [3][NPIX][512] bf16 (= gamma_i x_i).
// ---------------------------------------------------------------------------
__global__ __launch_bounds__(256)
void final_v2(const __hip_bfloat16* __restrict__ G,
              const __hip_bfloat16* __restrict__ Xb,
              float* __restrict__ out)
{
    __shared__ float tile[64][68];
    const int n0  = blockIdx.x * 64;
    const int b   = n0 >> 10;
    const int hw0 = n0 & (HWSZ - 1);
    const int t   = threadIdx.x;
    const int nl  = t >> 2;
    const int cg  = (t & 3) * 16;
    const int n   = n0 + nl;
    const unsigned short* gr = (const unsigned short*)G + (size_t)n * 1536;
    const unsigned short* xr = (const unsigned short*)Xb + (size_t)n * 512;
    const int seg = t & 3;
    float* outb = out + (size_t)b * (DCH * HWSZ) + hw0;

    for (int c0 = 0; c0 < DCH; c0 += 64) {
        u16x8_t gl[3][2], xl[3][2];
#pragma unroll
        for (int i = 0; i < 3; ++i) {
            gl[i][0] = *(const u16x8_t*)(gr + i * 512 + c0 + cg);
            gl[i][1] = *(const u16x8_t*)(gr + i * 512 + c0 + cg + 8);
            xl[i][0] = *(const u16x8_t*)(xr + (size_t)i * NPIX * 512 + c0 + cg);
            xl[i][1] = *(const u16x8_t*)(xr + (size_t)i * NPIX * 512 + c0 + cg + 8);
        }
#pragma unroll
        for (int e = 0; e < 16; ++e) {
            const int hh = e >> 3, w = e & 7;
            const float s0 = bf2f(gl[0][hh][w]);
            const float s1 = bf2f(gl[1][hh][w]);
            const float s2 = bf2f(gl[2][hh][w]);
            const float g0 = 1.0f / (1.0f + __expf(-s0));
            const float g1 = 1.0f / (1.0f + __expf(-s1));
            const float g2 = 1.0f / (1.0f + __expf(-s2));
            const float e0 = __expf(g0), e1 = __expf(g1), e2 = __expf(g2);
            const float inv = 1.0f / (e0 + e1 + e2);
            tile[cg + e][nl] = inv * (e0 * bf2f(xl[0][hh][w])
                                    + e1 * bf2f(xl[1][hh][w])
                                    + e2 * bf2f(xl[2][hh][w]));
        }
        __syncthreads();
#pragma unroll
        for (int j4 = 0; j4 < 4; ++j4) {
            float4 v = *(const float4*)&tile[nl][seg * 16 + j4 * 4];
            *(float4*)(outb + (size_t)(c0 + nl) * HWSZ + seg * 16 + j4 * 4) = v;
        }
        __syncthreads();
    }
}

// ---------------------------------------------------------------------------
// final (fallback): G channel-major [1536][NPIX], x fp32 natural layout.
// ---------------------------------------------------------------------------
__global__ __launch_bounds__(256)
void final_fuse(const __hip_bfloat16* __restrict__ G,
                const float* __restrict__ x0, const float* __restrict__ x1,
                const float* __restrict__ x2,
                const float* __restrict__ gp0, const float* __restrict__ gp1,
                const float* __restrict__ gp2,
                float* __restrict__ out)
{
    const int n  = blockIdx.x * 256 + threadIdx.x;
    const int b  = n >> 10;
    const int hw = n & (HWSZ - 1);
    const int c0 = blockIdx.y * 64;
    const float ga0 = gp0[0], ga1 = gp1[0], ga2 = gp2[0];
    for (int cc = 0; cc < 64; ++cc) {
        const int c = c0 + cc;
        const float s0 = __bfloat162float(G[(size_t)c * NPIX + n]);
        const float s1 = __bfloat162float(G[(size_t)(c + DCH) * NPIX + n]);
        const float s2 = __bfloat162float(G[(size_t)(c + 2 * DCH) * NPIX + n]);
        const float g0v = 1.0f / (1.0f + __expf(-s0));
        const float g1v = 1.0f / (1.0f + __expf(-s1));
        const float g2v = 1.0f / (1.0f + __expf(-s2));
        const float e0 = __expf(g0v), e1 = __expf(g1v), e2 = __expf(g2v);
        const float inv = 1.0f / (e0 + e1 + e2);
        const size_t xo = (size_t)b * (DCH * HWSZ) + (size_t)c * HWSZ + hw;
        out[xo] = inv * (e0 * ga0 * x0[xo] + e1 * ga1 * x1[xo] + e2 * ga2 * x2[xo]);
    }
}

// ---------------------------------------------------------------------------
extern "C" void kernel_launch(void* const* d_in, const int* in_sizes, int n_in,
                              void* d_out, int out_size, void* d_ws, size_t ws_size,
                              hipStream_t stream)
{
    const float* out0   = (const float*)d_in[0];
    const float* out1   = (const float*)d_in[1];
    const float* out2   = (const float*)d_in[2];
    const float* gamma0 = (const float*)d_in[3];
    const float* gamma1 = (const float*)d_in[4];
    const float* gamma2 = (const float*)d_in[5];
    const float* W_in1  = (const float*)d_in[6];
    const float* W_in2  = (const float*)d_in[8];
    const float* W_in3  = (const float*)d_in[10];
    const float* b_in1  = (const float*)d_in[7];
    const float* b_in2  = (const float*)d_in[9];
    const float* b_in3  = (const float*)d_in[11];
    const float* W_tr   = (const float*)d_in[12];
    const float* b_tr   = (const float*)d_in[13];
    const float* W_o1   = (const float*)d_in[14];
    const float* b_o1   = (const float*)d_in[15];
    const float* W_o2   = (const float*)d_in[16];
    const float* b_o2   = (const float*)d_in[17];
    const float* W_o3   = (const float*)d_in[18];
    const float* b_o3   = (const float*)d_in[19];
    float* outp = (float*)d_out;

    unsigned char* ws = (unsigned char*)d_ws;
    const size_t SZ_ACT   = (size_t)3 * NPIX * DCH * 2;     // 100663296
    const size_t WB_BYTES = (size_t)(6 * WSQ + WTR) * 2;    // 7864320
    const size_t NEED3    = 3 * SZ_ACT + WB_BYTES + 4096 * 4;
    const bool   big      = (ws_size >= NEED3);

    __hip_bfloat16* buf0 = (__hip_bfloat16*)ws;
    __hip_bfloat16* buf1 = (__hip_bfloat16*)(ws + SZ_ACT);
    __hip_bfloat16* buf2 = big ? (__hip_bfloat16*)(ws + 2 * SZ_ACT) : buf0;
    unsigned char*  wtop = ws + (big ? 3 : 2) * SZ_ACT;
    __hip_bfloat16* Wb     = (__hip_bfloat16*)wtop;
    __hip_bfloat16* Wb_tr  = Wb + 3 * WSQ;                  // fp8 region (aliased)
    unsigned char*  Wtr8   = (unsigned char*)Wb_tr;
    __hip_bfloat16* Wb_o   = Wb_tr + WTR;
    float*          biasWS = (float*)(wtop + WB_BYTES);     // [6][512]

    const int CVT_TOTAL = 6 * WSQ + WTR;
    cvt_all<<<CVT_TOTAL / 1024 + 1, 256, 0, stream>>>(
        W_in1, W_in2, W_in3, W_tr, W_o1, W_o2, W_o3, Wb,
        b_in1, b_in2, b_in3, b_o1, b_o2, b_o3, biasWS);

    stage_transpose<<<dim3(16, 8, 96), 256, 0, stream>>>(out0, out1, out2,
                                                         gamma0, gamma1, gamma2, buf0);

    // GEMM-A (batched 3 branches, bf16 in, FP8 OUT): XbT x W_in_i -> Hcat8[n][br*512+o]
    gemm256<<<dim3(768), 512, 0, stream>>>(
        buf0, DCH, Wb, DCH, biasWS,
        buf1, 3 * DCH, 0, DCH, 2, 256, NPIX * DCH, WSQ, DCH, DCH, 0, 1);

    // GEMM-B (MX-fp8): Hcat8 x Wtr8 -> H_traT bf16 (buf2 big / buf0 fallback)
    gemm_f8<<<dim3((NPIX / 128) * 12), 256, 0, stream>>>(
        (const unsigned char*)buf1, 3 * DCH, Wtr8, 3 * DCH, b_tr,
        buf2, 3 * DCH, 3 * DCH, 12);

    if (big) {
        // GEMM-C (batched, bf16): H_traT[:, br*512:] x W_out_i -> G^T[n][br*512+o]
        gemm256<<<dim3(768), 512, 0, stream>>>(
            buf2, 3 * DCH, Wb_o, DCH, biasWS + 3 * DCH,
            buf1, 3 * DCH, 0, DCH, 2, 256, DCH, WSQ, DCH, DCH, 0, 0);
        final_v2<<<dim3(NPIX / 64), 256, 0, stream>>>(buf1, buf0, outp);
    } else {
        gemm256<<<dim3(768), 512, 0, stream>>>(
            buf0, 3 * DCH, Wb_o, DCH, biasWS + 3 * DCH,
            buf1, NPIX, 0, DCH, 2, 256, DCH, WSQ, DCH, DCH, 1, 0);
        final_fuse<<<dim3(NPIX / 256, DCH / 64), 256, 0, stream>>>(
            buf1, out0, out1, out2, gamma0, gamma1, gamma2, outp);
    }
}

// Round 10
// 325.086 us; speedup vs baseline: 1.8687x; 1.1716x over previous
//
#include <hip/hip_runtime.h>
#include <hip/hip_bf16.h>

#define NPIX 32768
#define DCH 512
#define HWSZ 1024
#define WSQ (DCH * DCH)
#define WTR (3 * DCH * 3 * DCH)

typedef __bf16 bf16x8_t __attribute__((ext_vector_type(8)));
typedef float f32x4_t __attribute__((ext_vector_type(4)));
typedef float f32x16_t __attribute__((ext_vector_type(16)));
typedef int i32x4_t __attribute__((ext_vector_type(4)));
typedef int i32x8_t __attribute__((ext_vector_type(8)));
typedef unsigned short u16x8_t __attribute__((ext_vector_type(8)));
typedef unsigned short u16x4_t __attribute__((ext_vector_type(4)));

static __device__ __forceinline__ unsigned short f2bf(float f) {
    return __builtin_bit_cast(unsigned short, __float2bfloat16(f));
}
static __device__ __forceinline__ float bf2f(unsigned short u) {
    unsigned v = (unsigned)u << 16;
    return __builtin_bit_cast(float, v);
}

// ---------------------------------------------------------------------------
// Weights fp32 -> bf16 (blocks [0,NB)) AND fp8 e4m3 (blocks [NB,2NB)),
// last block copies biases. Order: in1,in2,in3, tr, o1,o2,o3.
// ---------------------------------------------------------------------------
__global__ __launch_bounds__(256)
void cvt_all(const float* __restrict__ w0, const float* __restrict__ w1,
             const float* __restrict__ w2, const float* __restrict__ w3,
             const float* __restrict__ w4, const float* __restrict__ w5,
             const float* __restrict__ w6,
             __hip_bfloat16* __restrict__ d, unsigned char* __restrict__ d8,
             const float* __restrict__ b0, const float* __restrict__ b1,
             const float* __restrict__ b2, const float* __restrict__ b3,
             const float* __restrict__ b4, const float* __restrict__ b5,
             float* __restrict__ biasd)
{
    const int NB = (6 * WSQ + WTR) >> 10;
    const int bid = blockIdx.x;
    if (bid == 2 * NB) {
        for (int idx = threadIdx.x; idx < 3072; idx += 256) {
            const int r = idx >> 9, off = idx & 511;
            const float* s = (r == 0) ? b0 : (r == 1) ? b1 : (r == 2) ? b2
                           : (r == 3) ? b3 : (r == 4) ? b4 : b5;
            biasd[idx] = s[off];
        }
        return;
    }
    const bool do8 = (bid >= NB);
    const int i = ((do8 ? bid - NB : bid) * 256 + threadIdx.x) * 4;
    const float* src;
    int off;
    if (i < 3 * WSQ) {
        int r = i >> 18;
        src = (r == 0) ? w0 : ((r == 1) ? w1 : w2);
        off = i - r * WSQ;
    } else if (i < 3 * WSQ + WTR) {
        src = w3; off = i - 3 * WSQ;
    } else {
        int j = i - 3 * WSQ - WTR;
        int r = j >> 18;
        src = (r == 0) ? w4 : ((r == 1) ? w5 : w6);
        off = j - r * WSQ;
    }
    float4 f = *(const float4*)(src + off);
    if (do8) {
        int dw = __builtin_amdgcn_cvt_pk_fp8_f32(f.x, f.y, 0, false);
        dw     = __builtin_amdgcn_cvt_pk_fp8_f32(f.z, f.w, dw, true);
        *(int*)(d8 + i) = dw;
    } else {
        u16x4_t v;
        v[0] = f2bf(f.x); v[1] = f2bf(f.y); v[2] = f2bf(f.z); v[3] = f2bf(f.w);
        *(u16x4_t*)((unsigned short*)d + i) = v;
    }
}

// ---------------------------------------------------------------------------
// Stage: X[b][c][hw] fp32 -> XbT bf16 [br][n][c] (+ optional fp8 copy).
// ---------------------------------------------------------------------------
__global__ __launch_bounds__(256)
void stage_transpose(const float* __restrict__ x0, const float* __restrict__ x1,
                     const float* __restrict__ x2,
                     const float* __restrict__ gp0, const float* __restrict__ gp1,
                     const float* __restrict__ gp2,
                     __hip_bfloat16* __restrict__ XbT,
                     unsigned char* __restrict__ Xb8, int emit8)
{
    __shared__ float tile[64][65];
    const int hw0 = blockIdx.x * 64;
    const int c0  = blockIdx.y * 64;
    const int bz  = blockIdx.z;
    const int br  = bz >> 5;
    const int b   = bz & 31;
    const float* x = (br == 0) ? x0 : ((br == 1) ? x1 : x2);
    const float g  = ((br == 0) ? gp0 : ((br == 1) ? gp1 : gp2))[0];
    const int t = threadIdx.x;

    const int hwi = t & 63;
    const int cb  = t >> 6;
    const float* src = x + (size_t)b * (DCH * HWSZ) + (size_t)c0 * HWSZ + hw0;
#pragma unroll
    for (int i = 0; i < 16; ++i) {
        const int ci = cb + i * 4;
        tile[ci][hwi] = g * src[(size_t)ci * HWSZ + hwi];
    }
    __syncthreads();

    const int hwr = t >> 2;
    const int cch = (t & 3) * 16;
    const size_t nrow = (size_t)br * NPIX + b * HWSZ + hw0 + hwr;
    __hip_bfloat16* dst = XbT + nrow * DCH + c0 + cch;
    u16x8_t v0, v1;
#pragma unroll
    for (int e = 0; e < 8; ++e) v0[e] = f2bf(tile[cch + e][hwr]);
#pragma unroll
    for (int e = 0; e < 8; ++e) v1[e] = f2bf(tile[cch + 8 + e][hwr]);
    *(u16x8_t*)dst = v0;
    *((u16x8_t*)dst + 1) = v1;

    if (emit8) {
        i32x4_t w;
#pragma unroll
        for (int q = 0; q < 4; ++q) {
            int dw = __builtin_amdgcn_cvt_pk_fp8_f32(tile[cch + 4 * q][hwr],
                                                     tile[cch + 4 * q + 1][hwr], 0, false);
            dw     = __builtin_amdgcn_cvt_pk_fp8_f32(tile[cch + 4 * q + 2][hwr],
                                                     tile[cch + 4 * q + 3][hwr], dw, true);
            w[q] = dw;
        }
        *(i32x4_t*)(Xb8 + nrow * DCH + c0 + cch) = w;
    }
}

// ---------------------------------------------------------------------------
// gemm_f8: 128x128 tile, 4 waves (2x2), per-wave 64x64, MX-fp8 K=64/instr.
// 3-deep LDS pipeline (48KB, 3 blocks/CU): stage t+2 while computing t,
// counted vmcnt(4) per tile (never 0 mid-loop), raw s_barrier, asm ds_read.
// Batched-branch decode (TPB/brA/brB/bstride/cstride). cmode: 0=bf16, 1=fp8.
// ---------------------------------------------------------------------------
__global__ __launch_bounds__(256, 3)
void gemm_f8(const unsigned char* __restrict__ A, int lda,
             const unsigned char* __restrict__ B, int ldb,
             const float* __restrict__ bias,
             void* __restrict__ Cv, int ldc, int coff0,
             int K, int NO, int TPB, int brA, int brB,
             int bstride, int cstride, int cmode)
{
    __shared__ __align__(16) unsigned char smem[49152];
    const int tid  = threadIdx.x;
    const int lane = tid & 63;
    const int wave = tid >> 6;
    const int wm = wave >> 1, wn = wave & 1;
    const int l31 = lane & 31;
    const int h   = lane >> 5;

    const int per  = gridDim.x >> 3;
    const int flat = (blockIdx.x & 7) * per + (blockIdx.x >> 3);
    const int br   = flat / TPB;
    const int rem  = flat - br * TPB;
    const int nt = rem / NO, ot = rem % NO;
    const int n0 = nt * 128, o0 = ot * 128;
    const int NT = K >> 6;

    A    += (size_t)br * (size_t)brA;
    B    += (size_t)br * (size_t)brB;
    bias += br * bstride;
    const int coff = coff0 + br * cstride;

    auto stage = [&](int t, unsigned bufb) {
#pragma unroll
        for (int p = 0; p < 2; ++p) {
            const int f   = tid + p * 256;
            const int row = f >> 2, cidx = f & 3;
            const int gch = ((cidx ^ (row & 3) ^ ((row >> 2) & 3)) << 4);
            const unsigned char* ga = A + (size_t)(n0 + row) * lda + t * 64 + gch;
            __builtin_amdgcn_global_load_lds(
                (const __attribute__((address_space(1))) unsigned int*)ga,
                (__attribute__((address_space(3))) unsigned int*)(smem + bufb + f * 16),
                16, 0, 0);
            const unsigned char* gb = B + (size_t)(o0 + row) * ldb + t * 64 + gch;
            __builtin_amdgcn_global_load_lds(
                (const __attribute__((address_space(1))) unsigned int*)gb,
                (__attribute__((address_space(3))) unsigned int*)(smem + bufb + 8192u + f * 16),
                16, 0, 0);
        }
    };

#define DSR(dst, a) asm volatile("ds_read_b128 %0, %1" : "=v"(dst) : "v"(a))

    f32x16_t acc[2][2];
#pragma unroll
    for (int mf = 0; mf < 2; ++mf)
#pragma unroll
        for (int nf = 0; nf < 2; ++nf)
#pragma unroll
            for (int e = 0; e < 16; ++e) acc[mf][nf][e] = 0.f;

    // prologue: tiles 0,1 in flight; wait tile 0 (8 outstanding -> 4)
    stage(0, 0u); stage(1, 16384u);
    asm volatile("s_waitcnt vmcnt(4)");
    __builtin_amdgcn_s_barrier();

    unsigned cur = 0u, nxt = 16384u, thr = 32768u;
    // precomputed per-lane read geometry
    int sA[2], sB[2];
    unsigned baseA[2], baseB[2];
#pragma unroll
    for (int mf = 0; mf < 2; ++mf) {
        const int r = wm * 64 + mf * 32 + l31;
        sA[mf] = (r & 3) ^ ((r >> 2) & 3);
        baseA[mf] = (unsigned)(r << 6);
        const int rb = wn * 64 + mf * 32 + l31;
        sB[mf] = (rb & 3) ^ ((rb >> 2) & 3);
        baseB[mf] = 8192u + (unsigned)(rb << 6);
    }

    for (int t = 0; t < NT; ++t) {
        if (t + 2 < NT) stage(t + 2, thr);

        i32x4_t alo[2], ahi[2], blo[2], bhi[2];
#pragma unroll
        for (int mf = 0; mf < 2; ++mf) {
            DSR(alo[mf], cur + baseA[mf] + ((((h << 1) | 0) ^ sA[mf]) << 4));
            DSR(ahi[mf], cur + baseA[mf] + ((((h << 1) | 1) ^ sA[mf]) << 4));
            DSR(blo[mf], cur + baseB[mf] + ((((h << 1) | 0) ^ sB[mf]) << 4));
            DSR(bhi[mf], cur + baseB[mf] + ((((h << 1) | 1) ^ sB[mf]) << 4));
        }
        asm volatile("s_waitcnt lgkmcnt(0)");
        __builtin_amdgcn_sched_barrier(0);

        i32x8_t af[2], bf[2];
#pragma unroll
        for (int mf = 0; mf < 2; ++mf) {
#pragma unroll
            for (int e = 0; e < 4; ++e) {
                af[mf][e] = alo[mf][e]; af[mf][e + 4] = ahi[mf][e];
                bf[mf][e] = blo[mf][e]; bf[mf][e + 4] = bhi[mf][e];
            }
        }
        __builtin_amdgcn_s_setprio(1);
#pragma unroll
        for (int mf = 0; mf < 2; ++mf)
#pragma unroll
            for (int nf = 0; nf < 2; ++nf)
                acc[mf][nf] = __builtin_amdgcn_mfma_scale_f32_32x32x64_f8f6f4(
                    af[mf], bf[nf], acc[mf][nf],
                    0, 0, 0, 0x7F7F7F7F, 0, 0x7F7F7F7F);
        __builtin_amdgcn_s_setprio(0);

        if (t + 2 < NT)      { asm volatile("s_waitcnt vmcnt(4)"); }
        else if (t + 1 < NT) { asm volatile("s_waitcnt vmcnt(0)"); }
        __builtin_amdgcn_s_barrier();
        const unsigned tmp = cur; cur = nxt; nxt = thr; thr = tmp;
    }
#undef DSR

    // C/D 32x32 layout: col = lane&31, row = (rg&3) + 8*(rg>>2) + 4*(lane>>5)
    if (cmode == 0) {
        __hip_bfloat16* C = (__hip_bfloat16*)Cv;
#pragma unroll
        for (int nf = 0; nf < 2; ++nf) {
            const int col = o0 + wn * 64 + nf * 32 + l31;
            const float bv = bias[col];
#pragma unroll
            for (int mf = 0; mf < 2; ++mf)
#pragma unroll
                for (int rg = 0; rg < 16; ++rg) {
                    const int row = n0 + wm * 64 + mf * 32 + (rg & 3) + ((rg >> 2) << 3) + (h << 2);
                    C[(size_t)row * ldc + coff + col] = __float2bfloat16(acc[mf][nf][rg] + bv);
                }
        }
    } else {
        unsigned char* C8 = (unsigned char*)Cv;
#pragma unroll
        for (int nf = 0; nf < 2; ++nf) {
            const int col = o0 + wn * 64 + nf * 32 + l31;
            const float bv = bias[col];
#pragma unroll
            for (int mf = 0; mf < 2; ++mf)
#pragma unroll
                for (int q = 0; q < 4; ++q) {
                    int dw = __builtin_amdgcn_cvt_pk_fp8_f32(acc[mf][nf][4 * q] + bv,
                                                             acc[mf][nf][4 * q + 1] + bv, 0, false);
                    dw     = __builtin_amdgcn_cvt_pk_fp8_f32(acc[mf][nf][4 * q + 2] + bv,
                                                             acc[mf][nf][4 * q + 3] + bv, dw, true);
                    const int row = n0 + wm * 64 + mf * 32 + 8 * q + (h << 2);
                    const size_t base = (size_t)row * ldc + coff + col;
                    const unsigned u = (unsigned)dw;
                    C8[base]           = (unsigned char)u;
                    C8[base + ldc]     = (unsigned char)(u >> 8);
                    C8[base + 2 * ldc] = (unsigned char)(u >> 16);
                    C8[base + 3 * ldc] = (unsigned char)(u >> 24);
                }
        }
    }
}

// ---------------------------------------------------------------------------
// 256x256 bf16 NT GEMM (fallback path only; R7 structure).
// ---------------------------------------------------------------------------
__global__ __launch_bounds__(512, 2)
void gemm256(const __hip_bfloat16* __restrict__ A, int lda,
             const __hip_bfloat16* __restrict__ B, int ldb,
             const float* __restrict__ bias,
             __hip_bfloat16* __restrict__ C, int ldc, int coff0,
             int K, int NO, int TPB, int brA, int brB, int bstride,
             int cstride, int trans_out)
{
    __shared__ __align__(16) unsigned char smem[131072];
    const int tid  = threadIdx.x;
    const int lane = tid & 63;
    const int wave = tid >> 6;
    const int wm   = wave >> 2;
    const int wn   = wave & 3;
    const int l16  = lane & 15;
    const int l4   = lane >> 4;

    const int per  = gridDim.x >> 3;
    const int flat = (blockIdx.x & 7) * per + (blockIdx.x >> 3);
    const int br   = flat / TPB;
    const int rem  = flat - br * TPB;
    const int nt   = rem / NO;
    const int ot   = rem - nt * NO;
    const int n0 = nt * 256;
    const int o0 = ot * 256;
    const int NT = K >> 6;

    A    += (size_t)br * (size_t)brA;
    B    += (size_t)br * (size_t)brB;
    bias += br * bstride;
    const int coff = coff0 + br * cstride;

    const unsigned xorv = (unsigned)((l16 & 7) << 4);
    unsigned baseA[2], baseB[2];
#pragma unroll
    for (int kk = 0; kk < 2; ++kk) {
        const unsigned ko = ((unsigned)(kk * 64 + l4 * 16)) ^ xorv;
        baseA[kk] = (unsigned)((wm * 128 + l16) * 128) + ko;
        baseB[kk] = 32768u + (unsigned)((wn * 64 + l16) * 128) + ko;
    }

    const int rr  = lane >> 3;
    const int kel = 8 * ((lane & 7) ^ rr);

    auto stageA = [&](int t, int half) {
        const unsigned dst = (unsigned)((t & 1) * 65536 + half * 16384 + wave * 2048);
        const __hip_bfloat16* g = A + (size_t)(n0 + half * 128 + wave * 16 + rr) * lda + t * 64 + kel;
#pragma unroll
        for (int s = 0; s < 2; ++s) {
            __builtin_amdgcn_global_load_lds(
                (const __attribute__((address_space(1))) unsigned int*)(g + (size_t)s * 8 * lda),
                (__attribute__((address_space(3))) unsigned int*)(smem + dst + s * 1024),
                16, 0, 0);
        }
    };
    auto stageB = [&](int t, int half) {
        const unsigned dst = (unsigned)((t & 1) * 65536 + 32768 + half * 16384 + wave * 2048);
        const __hip_bfloat16* g = B + (size_t)(o0 + half * 128 + wave * 16 + rr) * ldb + t * 64 + kel;
#pragma unroll
        for (int s = 0; s < 2; ++s) {
            __builtin_amdgcn_global_load_lds(
                (const __attribute__((address_space(1))) unsigned int*)(g + (size_t)s * 8 * ldb),
                (__attribute__((address_space(3))) unsigned int*)(smem + dst + s * 1024),
                16, 0, 0);
        }
    };

#define DSRO(dst, addr, OFF) \
    asm volatile("ds_read_b128 %0, %1 offset:" #OFF : "=v"(dst) : "v"(addr))
#define BC(x) __builtin_bit_cast(bf16x8_t, x)

    stageA(0, 0); stageA(0, 1); stageB(0, 0); stageB(0, 1);
    stageA(1, 0); stageA(1, 1); stageB(1, 0); stageB(1, 1);
    asm volatile("s_waitcnt vmcnt(8)");
    __builtin_amdgcn_s_barrier();

    f32x4_t aR[4][2], a2[4][2], bA[2][2], bB[2][2];
    f32x4_t acc[8][4];
#pragma unroll
    for (int m = 0; m < 8; ++m)
#pragma unroll
        for (int n = 0; n < 4; ++n) acc[m][n] = (f32x4_t){0.f, 0.f, 0.f, 0.f};

    {
        unsigned a0 = baseA[0], a1 = baseA[1], b0 = baseB[0], b1 = baseB[1];
        DSRO(aR[0][0], a0, 0);    DSRO(aR[1][0], a0, 2048);
        DSRO(aR[2][0], a0, 4096); DSRO(aR[3][0], a0, 6144);
        DSRO(aR[0][1], a1, 0);    DSRO(aR[1][1], a1, 2048);
        DSRO(aR[2][1], a1, 4096); DSRO(aR[3][1], a1, 6144);
        DSRO(bA[0][0], b0, 0);    DSRO(bA[1][0], b0, 2048);
        DSRO(bA[0][1], b1, 0);    DSRO(bA[1][1], b1, 2048);
    }

    unsigned cb = 0;
    for (int t = 0; t < NT; ++t) {
        const unsigned cbn = cb ^ 65536u;
        const unsigned a0 = cb + baseA[0], a1 = cb + baseA[1];
        const unsigned b0 = cb + baseB[0], b1 = cb + baseB[1];

        asm volatile("s_waitcnt lgkmcnt(0)");
        __builtin_amdgcn_sched_barrier(0);
        DSRO(bB[0][0], b0, 4096); DSRO(bB[1][0], b0, 6144);
        DSRO(bB[0][1], b1, 4096); DSRO(bB[1][1], b1, 6144);
        __builtin_amdgcn_sched_barrier(0);
        __builtin_amdgcn_s_setprio(1);
#pragma unroll
        for (int m = 0; m < 4; ++m)
#pragma unroll
            for (int n = 0; n < 2; ++n)
#pragma unroll
                for (int kk = 0; kk < 2; ++kk)
                    acc[m][n] = __builtin_amdgcn_mfma_f32_16x16x32_bf16(BC(aR[m][kk]), BC(bA[n][kk]), acc[m][n], 0, 0, 0);
        __builtin_amdgcn_s_setprio(0);
        __builtin_amdgcn_s_barrier();

        asm volatile("s_waitcnt lgkmcnt(0)");
        __builtin_amdgcn_sched_barrier(0);
        DSRO(a2[0][0], a0, 8192);  DSRO(a2[1][0], a0, 10240);
        DSRO(a2[2][0], a0, 12288); DSRO(a2[3][0], a0, 14336);
        DSRO(a2[0][1], a1, 8192);  DSRO(a2[1][1], a1, 10240);
        DSRO(a2[2][1], a1, 12288); DSRO(a2[3][1], a1, 14336);
        __builtin_amdgcn_sched_barrier(0);
        __builtin_amdgcn_s_setprio(1);
#pragma unroll
        for (int m = 0; m < 4; ++m)
#pragma unroll
            for (int n = 0; n < 2; ++n)
#pragma unroll
                for (int kk = 0; kk < 2; ++kk)
                    acc[m][n + 2] = __builtin_amdgcn_mfma_f32_16x16x32_bf16(BC(aR[m][kk]), BC(bB[n][kk]), acc[m][n + 2], 0, 0, 0);
        __builtin_amdgcn_s_setprio(0);
        __builtin_amdgcn_s_barrier();

        asm volatile("s_waitcnt lgkmcnt(0)");
        __builtin_amdgcn_sched_barrier(0);
        if (t + 2 < NT) { stageB(t + 2, 0); stageB(t + 2, 1); }
        __builtin_amdgcn_sched_barrier(0);
        __builtin_amdgcn_s_setprio(1);
#pragma unroll
        for (int m = 0; m < 4; ++m)
#pragma unroll
            for (int n = 0; n < 2; ++n)
#pragma unroll
                for (int kk = 0; kk < 2; ++kk)
                    acc[m + 4][n] = __builtin_amdgcn_mfma_f32_16x16x32_bf16(BC(a2[m][kk]), BC(bA[n][kk]), acc[m + 4][n], 0, 0, 0);
        __builtin_amdgcn_s_setprio(0);
        if (t + 2 < NT)        { asm volatile("s_waitcnt vmcnt(4)"); }
        else if (t + 2 == NT)  { asm volatile("s_waitcnt vmcnt(0)"); }
        __builtin_amdgcn_s_barrier();

        if (t + 1 < NT) {
            const unsigned na0 = cbn + baseA[0], na1 = cbn + baseA[1];
            const unsigned nb0 = cbn + baseB[0], nb1 = cbn + baseB[1];
            DSRO(aR[0][0], na0, 0);    DSRO(aR[1][0], na0, 2048);
            DSRO(aR[2][0], na0, 4096); DSRO(aR[3][0], na0, 6144);
            DSRO(aR[0][1], na1, 0);    DSRO(aR[1][1], na1, 2048);
            DSRO(aR[2][1], na1, 4096); DSRO(aR[3][1], na1, 6144);
            DSRO(bA[0][0], nb0, 0);    DSRO(bA[1][0], nb0, 2048);
            DSRO(bA[0][1], nb1, 0);    DSRO(bA[1][1], nb1, 2048);
        }
        if (t + 2 < NT) { stageA(t + 2, 0); stageA(t + 2, 1); }
        __builtin_amdgcn_sched_barrier(0);
        __builtin_amdgcn_s_setprio(1);
#pragma unroll
        for (int m = 0; m < 4; ++m)
#pragma unroll
            for (int n = 0; n < 2; ++n)
#pragma unroll
                for (int kk = 0; kk < 2; ++kk)
                    acc[m + 4][n + 2] = __builtin_amdgcn_mfma_f32_16x16x32_bf16(BC(a2[m][kk]), BC(bB[n][kk]), acc[m + 4][n + 2], 0, 0, 0);
        __builtin_amdgcn_s_setprio(0);
        cb = cbn;
    }

    if (!trans_out) {
#pragma unroll
        for (int n = 0; n < 4; ++n) {
            const int oc = o0 + wn * 64 + n * 16 + l16;
            const float bv = bias[oc];
#pragma unroll
            for (int m = 0; m < 8; ++m)
#pragma unroll
                for (int r = 0; r < 4; ++r) {
                    const int nr = n0 + wm * 128 + m * 16 + l4 * 4 + r;
                    C[(size_t)nr * ldc + coff + oc] = __float2bfloat16(acc[m][n][r] + bv);
                }
        }
    } else {
        __syncthreads();
#pragma unroll
        for (int n = 0; n < 4; ++n) {
            const int ocl = wn * 64 + n * 16 + l16;
            const float bv = bias[o0 + ocl];
#pragma unroll
            for (int m = 0; m < 8; ++m)
#pragma unroll
                for (int r = 0; r < 4; ++r) {
                    const int nrow = wm * 128 + m * 16 + l4 * 4 + r;
                    const unsigned phys = (unsigned)nrow * 512u
                        + (((unsigned)ocl * 2u) ^ (((unsigned)(nrow & 7)) << 4));
                    *(unsigned short*)(smem + phys) = f2bf(acc[m][n][r] + bv);
                }
        }
        __syncthreads();
        const int ol = tid >> 1;
        const int nh = (tid & 1) * 128;
        __hip_bfloat16* dst = C + (size_t)(coff + o0 + ol) * ldc + n0 + nh;
#pragma unroll
        for (int j8 = 0; j8 < 16; ++j8) {
            u16x8_t v;
#pragma unroll
            for (int e = 0; e < 8; ++e) {
                const int n2 = nh + j8 * 8 + e;
                v[e] = *(const unsigned short*)(smem + (unsigned)n2 * 512u
                        + ((((unsigned)ol * 2u) ^ ((unsigned)e << 4))));
            }
            *(u16x8_t*)((unsigned short*)dst + j8 * 8) = v;
        }
    }
#undef DSRO
#undef BC
}

// ---------------------------------------------------------------------------
// final_v2: G^T [NPIX][1536] n-major, Xb [3][NPIX][512] bf16 (= gamma_i x_i).
// ---------------------------------------------------------------------------
__global__ __launch_bounds__(256)
void final_v2(const __hip_bfloat16* __restrict__ G,
              const __hip_bfloat16* __restrict__ Xb,
              float* __restrict__ out)
{
    __shared__ float tile[64][68];
    const int n0  = blockIdx.x * 64;
    const int b   = n0 >> 10;
    const int hw0 = n0 & (HWSZ - 1);
    const int t   = threadIdx.x;
    const int nl  = t >> 2;
    const int cg  = (t & 3) * 16;
    const int n   = n0 + nl;
    const unsigned short* gr = (const unsigned short*)G + (size_t)n * 1536;
    const unsigned short* xr = (const unsigned short*)Xb + (size_t)n * 512;
    const int seg = t & 3;
    float* outb = out + (size_t)b * (DCH * HWSZ) + hw0;

    for (int c0 = 0; c0 < DCH; c0 += 64) {
        u16x8_t gl[3][2], xl[3][2];
#pragma unroll
        for (int i = 0; i < 3; ++i) {
            gl[i][0] = *(const u16x8_t*)(gr + i * 512 + c0 + cg);
            gl[i][1] = *(const u16x8_t*)(gr + i * 512 + c0 + cg + 8);
            xl[i][0] = *(const u16x8_t*)(xr + (size_t)i * NPIX * 512 + c0 + cg);
            xl[i][1] = *(const u16x8_t*)(xr + (size_t)i * NPIX * 512 + c0 + cg + 8);
        }
#pragma unroll
        for (int e = 0; e < 16; ++e) {
            const int hh = e >> 3, w = e & 7;
            const float s0 = bf2f(gl[0][hh][w]);
            const float s1 = bf2f(gl[1][hh][w]);
            const float s2 = bf2f(gl[2][hh][w]);
            const float g0 = 1.0f / (1.0f + __expf(-s0));
            const float g1 = 1.0f / (1.0f + __expf(-s1));
            const float g2 = 1.0f / (1.0f + __expf(-s2));
            const float e0 = __expf(g0), e1 = __expf(g1), e2 = __expf(g2);
            const float inv = 1.0f / (e0 + e1 + e2);
            tile[cg + e][nl] = inv * (e0 * bf2f(xl[0][hh][w])
                                    + e1 * bf2f(xl[1][hh][w])
                                    + e2 * bf2f(xl[2][hh][w]));
        }
        __syncthreads();
#pragma unroll
        for (int j4 = 0; j4 < 4; ++j4) {
            float4 v = *(const float4*)&tile[nl][seg * 16 + j4 * 4];
            *(float4*)(outb + (size_t)(c0 + nl) * HWSZ + seg * 16 + j4 * 4) = v;
        }
        __syncthreads();
    }
}

// ---------------------------------------------------------------------------
// final (fallback): G channel-major [1536][NPIX], x fp32 natural layout.
// ---------------------------------------------------------------------------
__global__ __launch_bounds__(256)
void final_fuse(const __hip_bfloat16* __restrict__ G,
                const float* __restrict__ x0, const float* __restrict__ x1,
                const float* __restrict__ x2,
                const float* __restrict__ gp0, const float* __restrict__ gp1,
                const float* __restrict__ gp2,
                float* __restrict__ out)
{
    const int n  = blockIdx.x * 256 + threadIdx.x;
    const int b  = n >> 10;
    const int hw = n & (HWSZ - 1);
    const int c0 = blockIdx.y * 64;
    const float ga0 = gp0[0], ga1 = gp1[0], ga2 = gp2[0];
    for (int cc = 0; cc < 64; ++cc) {
        const int c = c0 + cc;
        const float s0 = __bfloat162float(G[(size_t)c * NPIX + n]);
        const float s1 = __bfloat162float(G[(size_t)(c + DCH) * NPIX + n]);
        const float s2 = __bfloat162float(G[(size_t)(c + 2 * DCH) * NPIX + n]);
        const float g0v = 1.0f / (1.0f + __expf(-s0));
        const float g1v = 1.0f / (1.0f + __expf(-s1));
        const float g2v = 1.0f / (1.0f + __expf(-s2));
        const float e0 = __expf(g0v), e1 = __expf(g1v), e2 = __expf(g2v);
        const float inv = 1.0f / (e0 + e1 + e2);
        const size_t xo = (size_t)b * (DCH * HWSZ) + (size_t)c * HWSZ + hw;
        out[xo] = inv * (e0 * ga0 * x0[xo] + e1 * ga1 * x1[xo] + e2 * ga2 * x2[xo]);
    }
}

// ---------------------------------------------------------------------------
extern "C" void kernel_launch(void* const* d_in, const int* in_sizes, int n_in,
                              void* d_out, int out_size, void* d_ws, size_t ws_size,
                              hipStream_t stream)
{
    const float* out0   = (const float*)d_in[0];
    const float* out1   = (const float*)d_in[1];
    const float* out2   = (const float*)d_in[2];
    const float* gamma0 = (const float*)d_in[3];
    const float* gamma1 = (const float*)d_in[4];
    const float* gamma2 = (const float*)d_in[5];
    const float* W_in1  = (const float*)d_in[6];
    const float* W_in2  = (const float*)d_in[8];
    const float* W_in3  = (const float*)d_in[10];
    const float* b_in1  = (const float*)d_in[7];
    const float* b_in2  = (const float*)d_in[9];
    const float* b_in3  = (const float*)d_in[11];
    const float* W_tr   = (const float*)d_in[12];
    const float* b_tr   = (const float*)d_in[13];
    const float* W_o1   = (const float*)d_in[14];
    const float* b_o1   = (const float*)d_in[15];
    const float* W_o2   = (const float*)d_in[16];
    const float* b_o2   = (const float*)d_in[17];
    const float* W_o3   = (const float*)d_in[18];
    const float* b_o3   = (const float*)d_in[19];
    float* outp = (float*)d_out;

    unsigned char* ws = (unsigned char*)d_ws;
    const size_t SZ_ACT  = (size_t)3 * NPIX * DCH * 2;   // 96 MB bf16 acts
    const size_t SZ_ACT8 = (size_t)3 * NPIX * DCH;       // 48 MB fp8 acts
    const size_t WB_BF16 = (size_t)(6 * WSQ + WTR) * 2;  // 7864320
    const size_t WB_FP8  = (size_t)(6 * WSQ + WTR);      // 3932160
    const size_t NEED    = 2 * SZ_ACT + SZ_ACT8 + WB_BF16 + WB_FP8 + 16384;
    const bool   big     = (ws_size >= NEED);

    // big layout: buf0 (96M bf16 XbT) | P8 (48M: XbT8 then Htra8) |
    //             Q (96M: Hcat8 first 48M, then G bf16) | weights | bias
    __hip_bfloat16* buf0 = (__hip_bfloat16*)ws;
    unsigned char*  P8   = ws + SZ_ACT;
    unsigned char*  Q    = ws + SZ_ACT + SZ_ACT8;
    unsigned char*  wtop = big ? (ws + 2 * SZ_ACT + SZ_ACT8) : (ws + 2 * SZ_ACT);
    __hip_bfloat16* Wb     = (__hip_bfloat16*)wtop;
    __hip_bfloat16* Wb_tr  = Wb + 3 * WSQ;
    __hip_bfloat16* Wb_o   = Wb_tr + WTR;
    unsigned char*  Wf8    = wtop + WB_BF16;
    unsigned char*  Win8   = Wf8;
    unsigned char*  Wtr8   = Wf8 + 3 * WSQ;
    unsigned char*  Wo8    = Wf8 + 3 * WSQ + WTR;
    float*          biasWS = (float*)(wtop + WB_BF16 + WB_FP8);

    const int NB = (6 * WSQ + WTR) >> 10;   // 3840
    cvt_all<<<2 * NB + 1, 256, 0, stream>>>(
        W_in1, W_in2, W_in3, W_tr, W_o1, W_o2, W_o3, Wb, Wf8,
        b_in1, b_in2, b_in3, b_o1, b_o2, b_o3, biasWS);

    stage_transpose<<<dim3(16, 8, 96), 256, 0, stream>>>(
        out0, out1, out2, gamma0, gamma1, gamma2, buf0, P8, big ? 1 : 0);

    if (big) {
        // GEMM-A (fp8 batched): XbT8 x W_in_i -> Hcat8[n][br*512+o]
        gemm_f8<<<dim3(3072), 256, 0, stream>>>(
            P8, DCH, Win8, DCH, biasWS, Q, 3 * DCH, 0,
            DCH, 4, 1024, NPIX * DCH, WSQ, DCH, DCH, 1);
        // GEMM-B (fp8): Hcat8 x Wtr8 -> Htra8 (P8; XbT8 dead)
        gemm_f8<<<dim3(3072), 256, 0, stream>>>(
            Q, 3 * DCH, Wtr8, 3 * DCH, b_tr, P8, 3 * DCH, 0,
            3 * DCH, 12, 3072, 0, 0, 0, 0, 1);
        // GEMM-C (fp8 batched): Htra8[:, br*512:] x W_out_i -> G bf16 (Q; Hcat8 dead)
        gemm_f8<<<dim3(3072), 256, 0, stream>>>(
            P8, 3 * DCH, Wo8, DCH, biasWS + 3 * DCH, Q, 3 * DCH, 0,
            DCH, 4, 1024, DCH, WSQ, DCH, DCH, 0);
        final_v2<<<dim3(NPIX / 64), 256, 0, stream>>>((const __hip_bfloat16*)Q, buf0, outp);
    } else {
        // fallback: all-bf16 two-buffer flow (R7)
        __hip_bfloat16* buf1 = (__hip_bfloat16*)(ws + SZ_ACT);
        gemm256<<<dim3(768), 512, 0, stream>>>(
            buf0, DCH, Wb, DCH, biasWS,
            buf1, 3 * DCH, 0, DCH, 2, 256, NPIX * DCH, WSQ, DCH, DCH, 0);
        gemm256<<<dim3(768), 512, 0, stream>>>(
            buf1, 3 * DCH, Wb_tr, 3 * DCH, b_tr,
            buf0, 3 * DCH, 0, 3 * DCH, 6, 768, 0, 0, 0, 0, 0);
        gemm256<<<dim3(768), 512, 0, stream>>>(
            buf0, 3 * DCH, Wb_o, DCH, biasWS + 3 * DCH,
            buf1, NPIX, 0, DCH, 2, 256, DCH, WSQ, DCH, DCH, 1);
        final_fuse<<<dim3(NPIX / 256, DCH / 64), 256, 0, stream>>>(
            buf1, out0, out1, out2, gamma0, gamma1, gamma2, outp);
    }
}

// Round 11
// 318.956 us; speedup vs baseline: 1.9047x; 1.0192x over previous
//
#include <hip/hip_runtime.h>
#include <hip/hip_bf16.h>

#define NPIX 32768
#define DCH 512
#define HWSZ 1024
#define WSQ (DCH * DCH)
#define WTR (3 * DCH * 3 * DCH)

typedef __bf16 bf16x8_t __attribute__((ext_vector_type(8)));
typedef float f32x4_t __attribute__((ext_vector_type(4)));
typedef float f32x16_t __attribute__((ext_vector_type(16)));
typedef int i32x4_t __attribute__((ext_vector_type(4)));
typedef int i32x8_t __attribute__((ext_vector_type(8)));
typedef unsigned short u16x8_t __attribute__((ext_vector_type(8)));
typedef unsigned short u16x4_t __attribute__((ext_vector_type(4)));

static __device__ __forceinline__ unsigned short f2bf(float f) {
    return __builtin_bit_cast(unsigned short, __float2bfloat16(f));
}
static __device__ __forceinline__ float bf2f(unsigned short u) {
    unsigned v = (unsigned)u << 16;
    return __builtin_bit_cast(float, v);
}

// ---------------------------------------------------------------------------
// Weights fp32 -> bf16 (blocks [0,NB)) AND fp8 e4m3 (blocks [NB,2NB)),
// last block copies biases. Order: in1,in2,in3, tr, o1,o2,o3.
// ---------------------------------------------------------------------------
__global__ __launch_bounds__(256)
void cvt_all(const float* __restrict__ w0, const float* __restrict__ w1,
             const float* __restrict__ w2, const float* __restrict__ w3,
             const float* __restrict__ w4, const float* __restrict__ w5,
             const float* __restrict__ w6,
             __hip_bfloat16* __restrict__ d, unsigned char* __restrict__ d8,
             const float* __restrict__ b0, const float* __restrict__ b1,
             const float* __restrict__ b2, const float* __restrict__ b3,
             const float* __restrict__ b4, const float* __restrict__ b5,
             float* __restrict__ biasd)
{
    const int NB = (6 * WSQ + WTR) >> 10;
    const int bid = blockIdx.x;
    if (bid == 2 * NB) {
        for (int idx = threadIdx.x; idx < 3072; idx += 256) {
            const int r = idx >> 9, off = idx & 511;
            const float* s = (r == 0) ? b0 : (r == 1) ? b1 : (r == 2) ? b2
                           : (r == 3) ? b3 : (r == 4) ? b4 : b5;
            biasd[idx] = s[off];
        }
        return;
    }
    const bool do8 = (bid >= NB);
    const int i = ((do8 ? bid - NB : bid) * 256 + threadIdx.x) * 4;
    const float* src;
    int off;
    if (i < 3 * WSQ) {
        int r = i >> 18;
        src = (r == 0) ? w0 : ((r == 1) ? w1 : w2);
        off = i - r * WSQ;
    } else if (i < 3 * WSQ + WTR) {
        src = w3; off = i - 3 * WSQ;
    } else {
        int j = i - 3 * WSQ - WTR;
        int r = j >> 18;
        src = (r == 0) ? w4 : ((r == 1) ? w5 : w6);
        off = j - r * WSQ;
    }
    float4 f = *(const float4*)(src + off);
    if (do8) {
        int dw = __builtin_amdgcn_cvt_pk_fp8_f32(f.x, f.y, 0, false);
        dw     = __builtin_amdgcn_cvt_pk_fp8_f32(f.z, f.w, dw, true);
        *(int*)(d8 + i) = dw;
    } else {
        u16x4_t v;
        v[0] = f2bf(f.x); v[1] = f2bf(f.y); v[2] = f2bf(f.z); v[3] = f2bf(f.w);
        *(u16x4_t*)((unsigned short*)d + i) = v;
    }
}

// ---------------------------------------------------------------------------
// Stage: X[b][c][hw] fp32 -> XbT bf16 [br][n][c] (+ optional fp8 copy).
// ---------------------------------------------------------------------------
__global__ __launch_bounds__(256)
void stage_transpose(const float* __restrict__ x0, const float* __restrict__ x1,
                     const float* __restrict__ x2,
                     const float* __restrict__ gp0, const float* __restrict__ gp1,
                     const float* __restrict__ gp2,
                     __hip_bfloat16* __restrict__ XbT,
                     unsigned char* __restrict__ Xb8, int emit8)
{
    __shared__ float tile[64][65];
    const int hw0 = blockIdx.x * 64;
    const int c0  = blockIdx.y * 64;
    const int bz  = blockIdx.z;
    const int br  = bz >> 5;
    const int b   = bz & 31;
    const float* x = (br == 0) ? x0 : ((br == 1) ? x1 : x2);
    const float g  = ((br == 0) ? gp0 : ((br == 1) ? gp1 : gp2))[0];
    const int t = threadIdx.x;

    const int hwi = t & 63;
    const int cb  = t >> 6;
    const float* src = x + (size_t)b * (DCH * HWSZ) + (size_t)c0 * HWSZ + hw0;
#pragma unroll
    for (int i = 0; i < 16; ++i) {
        const int ci = cb + i * 4;
        tile[ci][hwi] = g * src[(size_t)ci * HWSZ + hwi];
    }
    __syncthreads();

    const int hwr = t >> 2;
    const int cch = (t & 3) * 16;
    const size_t nrow = (size_t)br * NPIX + b * HWSZ + hw0 + hwr;
    __hip_bfloat16* dst = XbT + nrow * DCH + c0 + cch;
    u16x8_t v0, v1;
#pragma unroll
    for (int e = 0; e < 8; ++e) v0[e] = f2bf(tile[cch + e][hwr]);
#pragma unroll
    for (int e = 0; e < 8; ++e) v1[e] = f2bf(tile[cch + 8 + e][hwr]);
    *(u16x8_t*)dst = v0;
    *((u16x8_t*)dst + 1) = v1;

    if (emit8) {
        i32x4_t w;
#pragma unroll
        for (int q = 0; q < 4; ++q) {
            int dw = __builtin_amdgcn_cvt_pk_fp8_f32(tile[cch + 4 * q][hwr],
                                                     tile[cch + 4 * q + 1][hwr], 0, false);
            dw     = __builtin_amdgcn_cvt_pk_fp8_f32(tile[cch + 4 * q + 2][hwr],
                                                     tile[cch + 4 * q + 3][hwr], dw, true);
            w[q] = dw;
        }
        *(i32x4_t*)(Xb8 + nrow * DCH + c0 + cch) = w;
    }
}

// ---------------------------------------------------------------------------
// gemm_f8: 256x128 tile, 4 waves (2x2), per-wave 128x64 (8 MFMA/K-tile),
// MX-fp8 32x32x64. 3-deep LDS pipeline (72KB, 2 blocks/CU), counted vmcnt(6),
// raw s_barrier, asm ds_read. Chunk swizzle cidx ^= (row&3)^((row>>2)&3).
// Batched-branch decode. cmode: 0=bf16 out, 1=fp8 out.
// ---------------------------------------------------------------------------
__global__ __launch_bounds__(256, 2)
void gemm_f8(const unsigned char* __restrict__ A, int lda,
             const unsigned char* __restrict__ B, int ldb,
             const float* __restrict__ bias,
             void* __restrict__ Cv, int ldc, int coff0,
             int K, int NO, int TPB, int brA, int brB,
             int bstride, int cstride, int cmode)
{
    __shared__ __align__(16) unsigned char smem[73728];   // 3 x (16K A + 8K B)
    const int tid  = threadIdx.x;
    const int lane = tid & 63;
    const int wave = tid >> 6;
    const int wm = wave >> 1, wn = wave & 1;
    const int l31 = lane & 31;
    const int h   = lane >> 5;

    const int per  = gridDim.x >> 3;
    const int flat = (blockIdx.x & 7) * per + (blockIdx.x >> 3);
    const int br   = flat / TPB;
    const int rem  = flat - br * TPB;
    const int nt = rem / NO, ot = rem % NO;
    const int n0 = nt * 256, o0 = ot * 128;
    const int NT = K >> 6;

    A    += (size_t)br * (size_t)brA;
    B    += (size_t)br * (size_t)brB;
    bias += br * bstride;
    const int coff = coff0 + br * cstride;

    // stage one K-tile: A 256x64 (chunks 0..1023) + B 128x64 (chunks 0..511)
    auto stage = [&](int t, unsigned bufb) {
#pragma unroll
        for (int p = 0; p < 6; ++p) {
            const int f = tid + p * 256;
            if (p < 4) {
                const int row = f >> 2, cidx = f & 3;
                const int gch = ((cidx ^ (row & 3) ^ ((row >> 2) & 3)) << 4);
                const unsigned char* ga = A + (size_t)(n0 + row) * lda + t * 64 + gch;
                __builtin_amdgcn_global_load_lds(
                    (const __attribute__((address_space(1))) unsigned int*)ga,
                    (__attribute__((address_space(3))) unsigned int*)(smem + bufb + f * 16),
                    16, 0, 0);
            } else {
                const int fb = f - 1024;
                const int row = fb >> 2, cidx = fb & 3;
                const int gch = ((cidx ^ (row & 3) ^ ((row >> 2) & 3)) << 4);
                const unsigned char* gb = B + (size_t)(o0 + row) * ldb + t * 64 + gch;
                __builtin_amdgcn_global_load_lds(
                    (const __attribute__((address_space(1))) unsigned int*)gb,
                    (__attribute__((address_space(3))) unsigned int*)(smem + bufb + 16384u + fb * 16),
                    16, 0, 0);
            }
        }
    };

#define DSR(dst, a) asm volatile("ds_read_b128 %0, %1" : "=v"(dst) : "v"(a))

    f32x16_t acc[4][2];
#pragma unroll
    for (int mf = 0; mf < 4; ++mf)
#pragma unroll
        for (int nf = 0; nf < 2; ++nf)
#pragma unroll
            for (int e = 0; e < 16; ++e) acc[mf][nf][e] = 0.f;

    // per-lane read geometry
    int sA[4], sB[2];
    unsigned baseA[4], baseB[2];
#pragma unroll
    for (int mf = 0; mf < 4; ++mf) {
        const int r = wm * 128 + mf * 32 + l31;
        sA[mf] = (r & 3) ^ ((r >> 2) & 3);
        baseA[mf] = (unsigned)(r << 6);
    }
#pragma unroll
    for (int nf = 0; nf < 2; ++nf) {
        const int rb = wn * 64 + nf * 32 + l31;
        sB[nf] = (rb & 3) ^ ((rb >> 2) & 3);
        baseB[nf] = 16384u + (unsigned)(rb << 6);
    }

    // prologue: tiles 0,1 in flight (12 loads); wait tile 0 (6 remain)
    stage(0, 0u); stage(1, 24576u);
    asm volatile("s_waitcnt vmcnt(6)");
    __builtin_amdgcn_s_barrier();

    unsigned cur = 0u, nxt = 24576u, thr = 49152u;
    for (int t = 0; t < NT; ++t) {
        if (t + 2 < NT) stage(t + 2, thr);

        i32x8_t af[4], bf[2];
#pragma unroll
        for (int mf = 0; mf < 4; ++mf) {
            i32x4_t lo, hi;
            DSR(lo, cur + baseA[mf] + ((((h << 1) | 0) ^ sA[mf]) << 4));
            DSR(hi, cur + baseA[mf] + ((((h << 1) | 1) ^ sA[mf]) << 4));
#pragma unroll
            for (int e = 0; e < 4; ++e) { af[mf][e] = lo[e]; af[mf][e + 4] = hi[e]; }
        }
#pragma unroll
        for (int nf = 0; nf < 2; ++nf) {
            i32x4_t lo, hi;
            DSR(lo, cur + baseB[nf] + ((((h << 1) | 0) ^ sB[nf]) << 4));
            DSR(hi, cur + baseB[nf] + ((((h << 1) | 1) ^ sB[nf]) << 4));
#pragma unroll
            for (int e = 0; e < 4; ++e) { bf[nf][e] = lo[e]; bf[nf][e + 4] = hi[e]; }
        }
        asm volatile("s_waitcnt lgkmcnt(0)");
        __builtin_amdgcn_sched_barrier(0);

        __builtin_amdgcn_s_setprio(1);
#pragma unroll
        for (int mf = 0; mf < 4; ++mf)
#pragma unroll
            for (int nf = 0; nf < 2; ++nf)
                acc[mf][nf] = __builtin_amdgcn_mfma_scale_f32_32x32x64_f8f6f4(
                    af[mf], bf[nf], acc[mf][nf],
                    0, 0, 0, 0x7F7F7F7F, 0, 0x7F7F7F7F);
        __builtin_amdgcn_s_setprio(0);

        if (t + 2 < NT)      { asm volatile("s_waitcnt vmcnt(6)"); }
        else if (t + 1 < NT) { asm volatile("s_waitcnt vmcnt(0)"); }
        __builtin_amdgcn_s_barrier();
        const unsigned tmp = cur; cur = nxt; nxt = thr; thr = tmp;
    }
#undef DSR

    // C/D 32x32 layout: col = lane&31, row = (rg&3) + 8*(rg>>2) + 4*(lane>>5)
    if (cmode == 0) {
        __hip_bfloat16* C = (__hip_bfloat16*)Cv;
#pragma unroll
        for (int nf = 0; nf < 2; ++nf) {
            const int col = o0 + wn * 64 + nf * 32 + l31;
            const float bv = bias[col];
#pragma unroll
            for (int mf = 0; mf < 4; ++mf)
#pragma unroll
                for (int rg = 0; rg < 16; ++rg) {
                    const int row = n0 + wm * 128 + mf * 32 + (rg & 3) + ((rg >> 2) << 3) + (h << 2);
                    C[(size_t)row * ldc + coff + col] = __float2bfloat16(acc[mf][nf][rg] + bv);
                }
        }
    } else {
        unsigned char* C8 = (unsigned char*)Cv;
#pragma unroll
        for (int nf = 0; nf < 2; ++nf) {
            const int col = o0 + wn * 64 + nf * 32 + l31;
            const float bv = bias[col];
#pragma unroll
            for (int mf = 0; mf < 4; ++mf)
#pragma unroll
                for (int q = 0; q < 4; ++q) {
                    int dw = __builtin_amdgcn_cvt_pk_fp8_f32(acc[mf][nf][4 * q] + bv,
                                                             acc[mf][nf][4 * q + 1] + bv, 0, false);
                    dw     = __builtin_amdgcn_cvt_pk_fp8_f32(acc[mf][nf][4 * q + 2] + bv,
                                                             acc[mf][nf][4 * q + 3] + bv, dw, true);
                    const int row = n0 + wm * 128 + mf * 32 + 8 * q + (h << 2);
                    const size_t base = (size_t)row * ldc + coff + col;
                    const unsigned u = (unsigned)dw;
                    C8[base]           = (unsigned char)u;
                    C8[base + ldc]     = (unsigned char)(u >> 8);
                    C8[base + 2 * ldc] = (unsigned char)(u >> 16);
                    C8[base + 3 * ldc] = (unsigned char)(u >> 24);
                }
        }
    }
}

// ---------------------------------------------------------------------------
// 256x256 bf16 NT GEMM (fallback path only; R7 structure).
// ---------------------------------------------------------------------------
__global__ __launch_bounds__(512, 2)
void gemm256(const __hip_bfloat16* __restrict__ A, int lda,
             const __hip_bfloat16* __restrict__ B, int ldb,
             const float* __restrict__ bias,
             __hip_bfloat16* __restrict__ C, int ldc, int coff0,
             int K, int NO, int TPB, int brA, int brB, int bstride,
             int cstride, int trans_out)
{
    __shared__ __align__(16) unsigned char smem[131072];
    const int tid  = threadIdx.x;
    const int lane = tid & 63;
    const int wave = tid >> 6;
    const int wm   = wave >> 2;
    const int wn   = wave & 3;
    const int l16  = lane & 15;
    const int l4   = lane >> 4;

    const int per  = gridDim.x >> 3;
    const int flat = (blockIdx.x & 7) * per + (blockIdx.x >> 3);
    const int br   = flat / TPB;
    const int rem  = flat - br * TPB;
    const int nt   = rem / NO;
    const int ot   = rem - nt * NO;
    const int n0 = nt * 256;
    const int o0 = ot * 256;
    const int NT = K >> 6;

    A    += (size_t)br * (size_t)brA;
    B    += (size_t)br * (size_t)brB;
    bias += br * bstride;
    const int coff = coff0 + br * cstride;

    const unsigned xorv = (unsigned)((l16 & 7) << 4);
    unsigned baseA[2], baseB[2];
#pragma unroll
    for (int kk = 0; kk < 2; ++kk) {
        const unsigned ko = ((unsigned)(kk * 64 + l4 * 16)) ^ xorv;
        baseA[kk] = (unsigned)((wm * 128 + l16) * 128) + ko;
        baseB[kk] = 32768u + (unsigned)((wn * 64 + l16) * 128) + ko;
    }

    const int rr  = lane >> 3;
    const int kel = 8 * ((lane & 7) ^ rr);

    auto stageA = [&](int t, int half) {
        const unsigned dst = (unsigned)((t & 1) * 65536 + half * 16384 + wave * 2048);
        const __hip_bfloat16* g = A + (size_t)(n0 + half * 128 + wave * 16 + rr) * lda + t * 64 + kel;
#pragma unroll
        for (int s = 0; s < 2; ++s) {
            __builtin_amdgcn_global_load_lds(
                (const __attribute__((address_space(1))) unsigned int*)(g + (size_t)s * 8 * lda),
                (__attribute__((address_space(3))) unsigned int*)(smem + dst + s * 1024),
                16, 0, 0);
        }
    };
    auto stageB = [&](int t, int half) {
        const unsigned dst = (unsigned)((t & 1) * 65536 + 32768 + half * 16384 + wave * 2048);
        const __hip_bfloat16* g = B + (size_t)(o0 + half * 128 + wave * 16 + rr) * ldb + t * 64 + kel;
#pragma unroll
        for (int s = 0; s < 2; ++s) {
            __builtin_amdgcn_global_load_lds(
                (const __attribute__((address_space(1))) unsigned int*)(g + (size_t)s * 8 * ldb),
                (__attribute__((address_space(3))) unsigned int*)(smem + dst + s * 1024),
                16, 0, 0);
        }
    };

#define DSRO(dst, addr, OFF) \
    asm volatile("ds_read_b128 %0, %1 offset:" #OFF : "=v"(dst) : "v"(addr))
#define BC(x) __builtin_bit_cast(bf16x8_t, x)

    stageA(0, 0); stageA(0, 1); stageB(0, 0); stageB(0, 1);
    stageA(1, 0); stageA(1, 1); stageB(1, 0); stageB(1, 1);
    asm volatile("s_waitcnt vmcnt(8)");
    __builtin_amdgcn_s_barrier();

    f32x4_t aR[4][2], a2[4][2], bA[2][2], bB[2][2];
    f32x4_t acc[8][4];
#pragma unroll
    for (int m = 0; m < 8; ++m)
#pragma unroll
        for (int n = 0; n < 4; ++n) acc[m][n] = (f32x4_t){0.f, 0.f, 0.f, 0.f};

    {
        unsigned a0 = baseA[0], a1 = baseA[1], b0 = baseB[0], b1 = baseB[1];
        DSRO(aR[0][0], a0, 0);    DSRO(aR[1][0], a0, 2048);
        DSRO(aR[2][0], a0, 4096); DSRO(aR[3][0], a0, 6144);
        DSRO(aR[0][1], a1, 0);    DSRO(aR[1][1], a1, 2048);
        DSRO(aR[2][1], a1, 4096); DSRO(aR[3][1], a1, 6144);
        DSRO(bA[0][0], b0, 0);    DSRO(bA[1][0], b0, 2048);
        DSRO(bA[0][1], b1, 0);    DSRO(bA[1][1], b1, 2048);
    }

    unsigned cb = 0;
    for (int t = 0; t < NT; ++t) {
        const unsigned cbn = cb ^ 65536u;
        const unsigned a0 = cb + baseA[0], a1 = cb + baseA[1];
        const unsigned b0 = cb + baseB[0], b1 = cb + baseB[1];

        asm volatile("s_waitcnt lgkmcnt(0)");
        __builtin_amdgcn_sched_barrier(0);
        DSRO(bB[0][0], b0, 4096); DSRO(bB[1][0], b0, 6144);
        DSRO(bB[0][1], b1, 4096); DSRO(bB[1][1], b1, 6144);
        __builtin_amdgcn_sched_barrier(0);
        __builtin_amdgcn_s_setprio(1);
#pragma unroll
        for (int m = 0; m < 4; ++m)
#pragma unroll
            for (int n = 0; n < 2; ++n)
#pragma unroll
                for (int kk = 0; kk < 2; ++kk)
                    acc[m][n] = __builtin_amdgcn_mfma_f32_16x16x32_bf16(BC(aR[m][kk]), BC(bA[n][kk]), acc[m][n], 0, 0, 0);
        __builtin_amdgcn_s_setprio(0);
        __builtin_amdgcn_s_barrier();

        asm volatile("s_waitcnt lgkmcnt(0)");
        __builtin_amdgcn_sched_barrier(0);
        DSRO(a2[0][0], a0, 8192);  DSRO(a2[1][0], a0, 10240);
        DSRO(a2[2][0], a0, 12288); DSRO(a2[3][0], a0, 14336);
        DSRO(a2[0][1], a1, 8192);  DSRO(a2[1][1], a1, 10240);
        DSRO(a2[2][1], a1, 12288); DSRO(a2[3][1], a1, 14336);
        __builtin_amdgcn_sched_barrier(0);
        __builtin_amdgcn_s_setprio(1);
#pragma unroll
        for (int m = 0; m < 4; ++m)
#pragma unroll
            for (int n = 0; n < 2; ++n)
#pragma unroll
                for (int kk = 0; kk < 2; ++kk)
                    acc[m][n + 2] = __builtin_amdgcn_mfma_f32_16x16x32_bf16(BC(aR[m][kk]), BC(bB[n][kk]), acc[m][n + 2], 0, 0, 0);
        __builtin_amdgcn_s_setprio(0);
        __builtin_amdgcn_s_barrier();

        asm volatile("s_waitcnt lgkmcnt(0)");
        __builtin_amdgcn_sched_barrier(0);
        if (t + 2 < NT) { stageB(t + 2, 0); stageB(t + 2, 1); }
        __builtin_amdgcn_sched_barrier(0);
        __builtin_amdgcn_s_setprio(1);
#pragma unroll
        for (int m = 0; m < 4; ++m)
#pragma unroll
            for (int n = 0; n < 2; ++n)
#pragma unroll
                for (int kk = 0; kk < 2; ++kk)
                    acc[m + 4][n] = __builtin_amdgcn_mfma_f32_16x16x32_bf16(BC(a2[m][kk]), BC(bA[n][kk]), acc[m + 4][n], 0, 0, 0);
        __builtin_amdgcn_s_setprio(0);
        if (t + 2 < NT)        { asm volatile("s_waitcnt vmcnt(4)"); }
        else if (t + 2 == NT)  { asm volatile("s_waitcnt vmcnt(0)"); }
        __builtin_amdgcn_s_barrier();

        if (t + 1 < NT) {
            const unsigned na0 = cbn + baseA[0], na1 = cbn + baseA[1];
            const unsigned nb0 = cbn + baseB[0], nb1 = cbn + baseB[1];
            DSRO(aR[0][0], na0, 0);    DSRO(aR[1][0], na0, 2048);
            DSRO(aR[2][0], na0, 4096); DSRO(aR[3][0], na0, 6144);
            DSRO(aR[0][1], na1, 0);    DSRO(aR[1][1], na1, 2048);
            DSRO(aR[2][1], na1, 4096); DSRO(aR[3][1], na1, 6144);
            DSRO(bA[0][0], nb0, 0);    DSRO(bA[1][0], nb0, 2048);
            DSRO(bA[0][1], nb1, 0);    DSRO(bA[1][1], nb1, 2048);
        }
        if (t + 2 < NT) { stageA(t + 2, 0); stageA(t + 2, 1); }
        __builtin_amdgcn_sched_barrier(0);
        __builtin_amdgcn_s_setprio(1);
#pragma unroll
        for (int m = 0; m < 4; ++m)
#pragma unroll
            for (int n = 0; n < 2; ++n)
#pragma unroll
                for (int kk = 0; kk < 2; ++kk)
                    acc[m + 4][n + 2] = __builtin_amdgcn_mfma_f32_16x16x32_bf16(BC(a2[m][kk]), BC(bB[n][kk]), acc[m + 4][n + 2], 0, 0, 0);
        __builtin_amdgcn_s_setprio(0);
        cb = cbn;
    }

    if (!trans_out) {
#pragma unroll
        for (int n = 0; n < 4; ++n) {
            const int oc = o0 + wn * 64 + n * 16 + l16;
            const float bv = bias[oc];
#pragma unroll
            for (int m = 0; m < 8; ++m)
#pragma unroll
                for (int r = 0; r < 4; ++r) {
                    const int nr = n0 + wm * 128 + m * 16 + l4 * 4 + r;
                    C[(size_t)nr * ldc + coff + oc] = __float2bfloat16(acc[m][n][r] + bv);
                }
        }
    } else {
        __syncthreads();
#pragma unroll
        for (int n = 0; n < 4; ++n) {
            const int ocl = wn * 64 + n * 16 + l16;
            const float bv = bias[o0 + ocl];
#pragma unroll
            for (int m = 0; m < 8; ++m)
#pragma unroll
                for (int r = 0; r < 4; ++r) {
                    const int nrow = wm * 128 + m * 16 + l4 * 4 + r;
                    const unsigned phys = (unsigned)nrow * 512u
                        + (((unsigned)ocl * 2u) ^ (((unsigned)(nrow & 7)) << 4));
                    *(unsigned short*)(smem + phys) = f2bf(acc[m][n][r] + bv);
                }
        }
        __syncthreads();
        const int ol = tid >> 1;
        const int nh = (tid & 1) * 128;
        __hip_bfloat16* dst = C + (size_t)(coff + o0 + ol) * ldc + n0 + nh;
#pragma unroll
        for (int j8 = 0; j8 < 16; ++j8) {
            u16x8_t v;
#pragma unroll
            for (int e = 0; e < 8; ++e) {
                const int n2 = nh + j8 * 8 + e;
                v[e] = *(const unsigned short*)(smem + (unsigned)n2 * 512u
                        + ((((unsigned)ol * 2u) ^ ((unsigned)e << 4))));
            }
            *(u16x8_t*)((unsigned short*)dst + j8 * 8) = v;
        }
    }
#undef DSRO
#undef BC
}

// ---------------------------------------------------------------------------
// final_v2: G^T [NPIX][1536] n-major, Xb [3][NPIX][512] bf16 (= gamma_i x_i).
// ---------------------------------------------------------------------------
__global__ __launch_bounds__(256)
void final_v2(const __hip_bfloat16* __restrict__ G,
              const __hip_bfloat16* __restrict__ Xb,
              float* __restrict__ out)
{
    __shared__ float tile[64][68];
    const int n0  = blockIdx.x * 64;
    const int b   = n0 >> 10;
    const int hw0 = n0 & (HWSZ - 1);
    const int t   = threadIdx.x;
    const int nl  = t >> 2;
    const int cg  = (t & 3) * 16;
    const int n   = n0 + nl;
    const unsigned short* gr = (const unsigned short*)G + (size_t)n * 1536;
    const unsigned short* xr = (const unsigned short*)Xb + (size_t)n * 512;
    const int seg = t & 3;
    float* outb = out + (size_t)b * (DCH * HWSZ) + hw0;

    for (int c0 = 0; c0 < DCH; c0 += 64) {
        u16x8_t gl[3][2], xl[3][2];
#pragma unroll
        for (int i = 0; i < 3; ++i) {
            gl[i][0] = *(const u16x8_t*)(gr + i * 512 + c0 + cg);
            gl[i][1] = *(const u16x8_t*)(gr + i * 512 + c0 + cg + 8);
            xl[i][0] = *(const u16x8_t*)(xr + (size_t)i * NPIX * 512 + c0 + cg);
            xl[i][1] = *(const u16x8_t*)(xr + (size_t)i * NPIX * 512 + c0 + cg + 8);
        }
#pragma unroll
        for (int e = 0; e < 16; ++e) {
            const int hh = e >> 3, w = e & 7;
            const float s0 = bf2f(gl[0][hh][w]);
            const float s1 = bf2f(gl[1][hh][w]);
            const float s2 = bf2f(gl[2][hh][w]);
            const float g0 = 1.0f / (1.0f + __expf(-s0));
            const float g1 = 1.0f / (1.0f + __expf(-s1));
            const float g2 = 1.0f / (1.0f + __expf(-s2));
            const float e0 = __expf(g0), e1 = __expf(g1), e2 = __expf(g2);
            const float inv = 1.0f / (e0 + e1 + e2);
            tile[cg + e][nl] = inv * (e0 * bf2f(xl[0][hh][w])
                                    + e1 * bf2f(xl[1][hh][w])
                                    + e2 * bf2f(xl[2][hh][w]));
        }
        __syncthreads();
#pragma unroll
        for (int j4 = 0; j4 < 4; ++j4) {
            float4 v = *(const float4*)&tile[nl][seg * 16 + j4 * 4];
            *(float4*)(outb + (size_t)(c0 + nl) * HWSZ + seg * 16 + j4 * 4) = v;
        }
        __syncthreads();
    }
}

// ---------------------------------------------------------------------------
// final (fallback): G channel-major [1536][NPIX], x fp32 natural layout.
// ---------------------------------------------------------------------------
__global__ __launch_bounds__(256)
void final_fuse(const __hip_bfloat16* __restrict__ G,
                const float* __restrict__ x0, const float* __restrict__ x1,
                const float* __restrict__ x2,
                const float* __restrict__ gp0, const float* __restrict__ gp1,
                const float* __restrict__ gp2,
                float* __restrict__ out)
{
    const int n  = blockIdx.x * 256 + threadIdx.x;
    const int b  = n >> 10;
    const int hw = n & (HWSZ - 1);
    const int c0 = blockIdx.y * 64;
    const float ga0 = gp0[0], ga1 = gp1[0], ga2 = gp2[0];
    for (int cc = 0; cc < 64; ++cc) {
        const int c = c0 + cc;
        const float s0 = __bfloat162float(G[(size_t)c * NPIX + n]);
        const float s1 = __bfloat162float(G[(size_t)(c + DCH) * NPIX + n]);
        const float s2 = __bfloat162float(G[(size_t)(c + 2 * DCH) * NPIX + n]);
        const float g0v = 1.0f / (1.0f + __expf(-s0));
        const float g1v = 1.0f / (1.0f + __expf(-s1));
        const float g2v = 1.0f / (1.0f + __expf(-s2));
        const float e0 = __expf(g0v), e1 = __expf(g1v), e2 = __expf(g2v);
        const float inv = 1.0f / (e0 + e1 + e2);
        const size_t xo = (size_t)b * (DCH * HWSZ) + (size_t)c * HWSZ + hw;
        out[xo] = inv * (e0 * ga0 * x0[xo] + e1 * ga1 * x1[xo] + e2 * ga2 * x2[xo]);
    }
}

// ---------------------------------------------------------------------------
extern "C" void kernel_launch(void* const* d_in, const int* in_sizes, int n_in,
                              void* d_out, int out_size, void* d_ws, size_t ws_size,
                              hipStream_t stream)
{
    const float* out0   = (const float*)d_in[0];
    const float* out1   = (const float*)d_in[1];
    const float* out2   = (const float*)d_in[2];
    const float* gamma0 = (const float*)d_in[3];
    const float* gamma1 = (const float*)d_in[4];
    const float* gamma2 = (const float*)d_in[5];
    const float* W_in1  = (const float*)d_in[6];
    const float* W_in2  = (const float*)d_in[8];
    const float* W_in3  = (const float*)d_in[10];
    const float* b_in1  = (const float*)d_in[7];
    const float* b_in2  = (const float*)d_in[9];
    const float* b_in3  = (const float*)d_in[11];
    const float* W_tr   = (const float*)d_in[12];
    const float* b_tr   = (const float*)d_in[13];
    const float* W_o1   = (const float*)d_in[14];
    const float* b_o1   = (const float*)d_in[15];
    const float* W_o2   = (const float*)d_in[16];
    const float* b_o2   = (const float*)d_in[17];
    const float* W_o3   = (const float*)d_in[18];
    const float* b_o3   = (const float*)d_in[19];
    float* outp = (float*)d_out;

    unsigned char* ws = (unsigned char*)d_ws;
    const size_t SZ_ACT  = (size_t)3 * NPIX * DCH * 2;   // 96 MB bf16 acts
    const size_t SZ_ACT8 = (size_t)3 * NPIX * DCH;       // 48 MB fp8 acts
    const size_t WB_BF16 = (size_t)(6 * WSQ + WTR) * 2;  // 7864320
    const size_t WB_FP8  = (size_t)(6 * WSQ + WTR);      // 3932160
    const size_t NEED    = 2 * SZ_ACT + SZ_ACT8 + WB_BF16 + WB_FP8 + 16384;
    const bool   big     = (ws_size >= NEED);

    // big layout: buf0 (96M bf16 XbT) | P8 (48M: XbT8 then Htra8) |
    //             Q (96M: Hcat8 first 48M, then G bf16) | weights | bias
    __hip_bfloat16* buf0 = (__hip_bfloat16*)ws;
    unsigned char*  P8   = ws + SZ_ACT;
    unsigned char*  Q    = ws + SZ_ACT + SZ_ACT8;
    unsigned char*  wtop = big ? (ws + 2 * SZ_ACT + SZ_ACT8) : (ws + 2 * SZ_ACT);
    __hip_bfloat16* Wb     = (__hip_bfloat16*)wtop;
    __hip_bfloat16* Wb_tr  = Wb + 3 * WSQ;
    __hip_bfloat16* Wb_o   = Wb_tr + WTR;
    unsigned char*  Wf8    = wtop + WB_BF16;
    unsigned char*  Win8   = Wf8;
    unsigned char*  Wtr8   = Wf8 + 3 * WSQ;
    unsigned char*  Wo8    = Wf8 + 3 * WSQ + WTR;
    float*          biasWS = (float*)(wtop + WB_BF16 + WB_FP8);

    const int NB = (6 * WSQ + WTR) >> 10;   // 3840
    cvt_all<<<2 * NB + 1, 256, 0, stream>>>(
        W_in1, W_in2, W_in3, W_tr, W_o1, W_o2, W_o3, Wb, Wf8,
        b_in1, b_in2, b_in3, b_o1, b_o2, b_o3, biasWS);

    stage_transpose<<<dim3(16, 8, 96), 256, 0, stream>>>(
        out0, out1, out2, gamma0, gamma1, gamma2, buf0, P8, big ? 1 : 0);

    if (big) {
        // GEMM-A (fp8 batched): XbT8 x W_in_i -> Hcat8[n][br*512+o]
        gemm_f8<<<dim3(1536), 256, 0, stream>>>(
            P8, DCH, Win8, DCH, biasWS, Q, 3 * DCH, 0,
            DCH, 4, 512, NPIX * DCH, WSQ, DCH, DCH, 1);
        // GEMM-B (fp8): Hcat8 x Wtr8 -> Htra8 (P8; XbT8 dead)
        gemm_f8<<<dim3(1536), 256, 0, stream>>>(
            Q, 3 * DCH, Wtr8, 3 * DCH, b_tr, P8, 3 * DCH, 0,
            3 * DCH, 12, 1536, 0, 0, 0, 0, 1);
        // GEMM-C (fp8 batched): Htra8[:, br*512:] x W_out_i -> G bf16 (Q; Hcat8 dead)
        gemm_f8<<<dim3(1536), 256, 0, stream>>>(
            P8, 3 * DCH, Wo8, DCH, biasWS + 3 * DCH, Q, 3 * DCH, 0,
            DCH, 4, 512, DCH, WSQ, DCH, DCH, 0);
        final_v2<<<dim3(NPIX / 64), 256, 0, stream>>>((const __hip_bfloat16*)Q, buf0, outp);
    } else {
        // fallback: all-bf16 two-buffer flow (R7)
        __hip_bfloat16* buf1 = (__hip_bfloat16*)(ws + SZ_ACT);
        gemm256<<<dim3(768), 512, 0, stream>>>(
            buf0, DCH, Wb, DCH, biasWS,
            buf1, 3 * DCH, 0, DCH, 2, 256, NPIX * DCH, WSQ, DCH, DCH, 0);
        gemm256<<<dim3(768), 512, 0, stream>>>(
            buf1, 3 * DCH, Wb_tr, 3 * DCH, b_tr,
            buf0, 3 * DCH, 0, 3 * DCH, 6, 768, 0, 0, 0, 0, 0);
        gemm256<<<dim3(768), 512, 0, stream>>>(
            buf0, 3 * DCH, Wb_o, DCH, biasWS + 3 * DCH,
            buf1, NPIX, 0, DCH, 2, 256, DCH, WSQ, DCH, DCH, 1);
        final_fuse<<<dim3(NPIX / 256, DCH / 64), 256, 0, stream>>>(
            buf1, out0, out1, out2, gamma0, gamma1, gamma2, outp);
    }
}

// Round 12
// 317.759 us; speedup vs baseline: 1.9118x; 1.0038x over previous
//
#include <hip/hip_runtime.h>
#include <hip/hip_bf16.h>

#define NPIX 32768
#define DCH 512
#define HWSZ 1024
#define WSQ (DCH * DCH)
#define WTR (3 * DCH * 3 * DCH)

typedef __bf16 bf16x8_t __attribute__((ext_vector_type(8)));
typedef float f32x4_t __attribute__((ext_vector_type(4)));
typedef float f32x16_t __attribute__((ext_vector_type(16)));
typedef int i32x4_t __attribute__((ext_vector_type(4)));
typedef int i32x8_t __attribute__((ext_vector_type(8)));
typedef unsigned short u16x8_t __attribute__((ext_vector_type(8)));
typedef unsigned short u16x4_t __attribute__((ext_vector_type(4)));

static __device__ __forceinline__ unsigned short f2bf(float f) {
    return __builtin_bit_cast(unsigned short, __float2bfloat16(f));
}
static __device__ __forceinline__ float bf2f(unsigned short u) {
    unsigned v = (unsigned)u << 16;
    return __builtin_bit_cast(float, v);
}

// ---------------------------------------------------------------------------
// Weights fp32 -> bf16 (blocks [0,NB)) AND fp8 e4m3 (blocks [NB,2NB)),
// last block copies biases. Order: in1,in2,in3, tr, o1,o2,o3.
// ---------------------------------------------------------------------------
__global__ __launch_bounds__(256)
void cvt_all(const float* __restrict__ w0, const float* __restrict__ w1,
             const float* __restrict__ w2, const float* __restrict__ w3,
             const float* __restrict__ w4, const float* __restrict__ w5,
             const float* __restrict__ w6,
             __hip_bfloat16* __restrict__ d, unsigned char* __restrict__ d8,
             const float* __restrict__ b0, const float* __restrict__ b1,
             const float* __restrict__ b2, const float* __restrict__ b3,
             const float* __restrict__ b4, const float* __restrict__ b5,
             float* __restrict__ biasd)
{
    const int NB = (6 * WSQ + WTR) >> 10;
    const int bid = blockIdx.x;
    if (bid == 2 * NB) {
        for (int idx = threadIdx.x; idx < 3072; idx += 256) {
            const int r = idx >> 9, off = idx & 511;
            const float* s = (r == 0) ? b0 : (r == 1) ? b1 : (r == 2) ? b2
                           : (r == 3) ? b3 : (r == 4) ? b4 : b5;
            biasd[idx] = s[off];
        }
        return;
    }
    const bool do8 = (bid >= NB);
    const int i = ((do8 ? bid - NB : bid) * 256 + threadIdx.x) * 4;
    const float* src;
    int off;
    if (i < 3 * WSQ) {
        int r = i >> 18;
        src = (r == 0) ? w0 : ((r == 1) ? w1 : w2);
        off = i - r * WSQ;
    } else if (i < 3 * WSQ + WTR) {
        src = w3; off = i - 3 * WSQ;
    } else {
        int j = i - 3 * WSQ - WTR;
        int r = j >> 18;
        src = (r == 0) ? w4 : ((r == 1) ? w5 : w6);
        off = j - r * WSQ;
    }
    float4 f = *(const float4*)(src + off);
    if (do8) {
        int dw = __builtin_amdgcn_cvt_pk_fp8_f32(f.x, f.y, 0, false);
        dw     = __builtin_amdgcn_cvt_pk_fp8_f32(f.z, f.w, dw, true);
        *(int*)(d8 + i) = dw;
    } else {
        u16x4_t v;
        v[0] = f2bf(f.x); v[1] = f2bf(f.y); v[2] = f2bf(f.z); v[3] = f2bf(f.w);
        *(u16x4_t*)((unsigned short*)d + i) = v;
    }
}

// ---------------------------------------------------------------------------
// Stage: X[b][c][hw] fp32 -> XbT bf16 [br][n][c] (+ optional fp8 copy).
// float4 global reads (4/thread); single LDS-read pass emits bf16 AND fp8.
// ---------------------------------------------------------------------------
__global__ __launch_bounds__(256)
void stage_transpose(const float* __restrict__ x0, const float* __restrict__ x1,
                     const float* __restrict__ x2,
                     const float* __restrict__ gp0, const float* __restrict__ gp1,
                     const float* __restrict__ gp2,
                     __hip_bfloat16* __restrict__ XbT,
                     unsigned char* __restrict__ Xb8, int emit8)
{
    __shared__ float tile[64][65];
    const int hw0 = blockIdx.x * 64;
    const int c0  = blockIdx.y * 64;
    const int bz  = blockIdx.z;
    const int br  = bz >> 5;
    const int b   = bz & 31;
    const float* x = (br == 0) ? x0 : ((br == 1) ? x1 : x2);
    const float g  = ((br == 0) ? gp0 : ((br == 1) ? gp1 : gp2))[0];
    const int t = threadIdx.x;

    // read phase: float4 along hw (64 lanes x 16B, coalesced)
    const int qh = (t & 15) * 4;
    const int rb = t >> 4;
    const float* src = x + (size_t)b * (DCH * HWSZ) + (size_t)c0 * HWSZ + hw0;
#pragma unroll
    for (int i = 0; i < 4; ++i) {
        const int ci = rb + i * 16;
        float4 v = *(const float4*)(src + (size_t)ci * HWSZ + qh);
        v.x *= g; v.y *= g; v.z *= g; v.w *= g;
        *(float4*)&tile[ci][qh] = v;
    }
    __syncthreads();

    // write phase: one tile-read pass -> bf16 (and fp8 if emit8)
    const int hwr = t >> 2;
    const int cch = (t & 3) * 16;
    const size_t nrow = (size_t)br * NPIX + b * HWSZ + hw0 + hwr;
    float vals[16];
#pragma unroll
    for (int e = 0; e < 16; ++e) vals[e] = tile[cch + e][hwr];

    __hip_bfloat16* dst = XbT + nrow * DCH + c0 + cch;
    u16x8_t v0, v1;
#pragma unroll
    for (int e = 0; e < 8; ++e) v0[e] = f2bf(vals[e]);
#pragma unroll
    for (int e = 0; e < 8; ++e) v1[e] = f2bf(vals[8 + e]);
    *(u16x8_t*)dst = v0;
    *((u16x8_t*)dst + 1) = v1;

    if (emit8) {
        i32x4_t w;
#pragma unroll
        for (int q = 0; q < 4; ++q) {
            int dw = __builtin_amdgcn_cvt_pk_fp8_f32(vals[4 * q], vals[4 * q + 1], 0, false);
            dw     = __builtin_amdgcn_cvt_pk_fp8_f32(vals[4 * q + 2], vals[4 * q + 3], dw, true);
            w[q] = dw;
        }
        *(i32x4_t*)(Xb8 + nrow * DCH + c0 + cch) = w;
    }
}

// ---------------------------------------------------------------------------
// gemm_f8: 256x128 tile, 4 waves (2x2), per-wave 128x64 (8 MFMA/K-tile),
// MX-fp8 32x32x64. 3-deep LDS pipeline (72KB, 2 blocks/CU), counted vmcnt(6),
// raw s_barrier, asm ds_read straight into {lo,hi} pairs (bit_cast to i32x8).
// Chunk swizzle cidx ^= (row&3)^((row>>2)&3); hi-addr = lo-addr ^ 16.
// Batched-branch decode. cmode: 0=bf16 out, 1=fp8 out.
// ---------------------------------------------------------------------------
struct pair4 { i32x4_t lo, hi; };

__global__ __launch_bounds__(256, 2)
void gemm_f8(const unsigned char* __restrict__ A, int lda,
             const unsigned char* __restrict__ B, int ldb,
             const float* __restrict__ bias,
             void* __restrict__ Cv, int ldc, int coff0,
             int K, int NO, int TPB, int brA, int brB,
             int bstride, int cstride, int cmode)
{
    __shared__ __align__(16) unsigned char smem[73728];   // 3 x (16K A + 8K B)
    const int tid  = threadIdx.x;
    const int lane = tid & 63;
    const int wave = tid >> 6;
    const int wm = wave >> 1, wn = wave & 1;
    const int l31 = lane & 31;
    const int h   = lane >> 5;

    const int per  = gridDim.x >> 3;
    const int flat = (blockIdx.x & 7) * per + (blockIdx.x >> 3);
    const int br   = flat / TPB;
    const int rem  = flat - br * TPB;
    const int nt = rem / NO, ot = rem % NO;
    const int n0 = nt * 256, o0 = ot * 128;
    const int NT = K >> 6;

    A    += (size_t)br * (size_t)brA;
    B    += (size_t)br * (size_t)brB;
    bias += br * bstride;
    const int coff = coff0 + br * cstride;

    // stage one K-tile: A 256x64 (chunks 0..1023) + B 128x64 (chunks 0..511)
    auto stage = [&](int t, unsigned bufb) {
#pragma unroll
        for (int p = 0; p < 6; ++p) {
            const int f = tid + p * 256;
            if (p < 4) {
                const int row = f >> 2, cidx = f & 3;
                const int gch = ((cidx ^ (row & 3) ^ ((row >> 2) & 3)) << 4);
                const unsigned char* ga = A + (size_t)(n0 + row) * lda + t * 64 + gch;
                __builtin_amdgcn_global_load_lds(
                    (const __attribute__((address_space(1))) unsigned int*)ga,
                    (__attribute__((address_space(3))) unsigned int*)(smem + bufb + f * 16),
                    16, 0, 0);
            } else {
                const int fb = f - 1024;
                const int row = fb >> 2, cidx = fb & 3;
                const int gch = ((cidx ^ (row & 3) ^ ((row >> 2) & 3)) << 4);
                const unsigned char* gb = B + (size_t)(o0 + row) * ldb + t * 64 + gch;
                __builtin_amdgcn_global_load_lds(
                    (const __attribute__((address_space(1))) unsigned int*)gb,
                    (__attribute__((address_space(3))) unsigned int*)(smem + bufb + 16384u + fb * 16),
                    16, 0, 0);
            }
        }
    };

#define DSR(dst, a) asm volatile("ds_read_b128 %0, %1" : "=v"(dst) : "v"(a))

    f32x16_t acc[4][2];
#pragma unroll
    for (int mf = 0; mf < 4; ++mf)
#pragma unroll
        for (int nf = 0; nf < 2; ++nf)
#pragma unroll
            for (int e = 0; e < 16; ++e) acc[mf][nf][e] = 0.f;

    // per-lane read geometry: lo-chunk addresses; hi = lo ^ 16
    unsigned addrA[4], addrB[2];
#pragma unroll
    for (int mf = 0; mf < 4; ++mf) {
        const int r = wm * 128 + mf * 32 + l31;
        const int s = (r & 3) ^ ((r >> 2) & 3);
        addrA[mf] = (unsigned)(r << 6) + (unsigned)((((h << 1)) ^ s) << 4);
    }
#pragma unroll
    for (int nf = 0; nf < 2; ++nf) {
        const int rb = wn * 64 + nf * 32 + l31;
        const int s = (rb & 3) ^ ((rb >> 2) & 3);
        addrB[nf] = 16384u + (unsigned)(rb << 6) + (unsigned)((((h << 1)) ^ s) << 4);
    }

    // prologue: tiles 0,1 in flight (12 loads); wait tile 0 (6 remain)
    stage(0, 0u); stage(1, 24576u);
    asm volatile("s_waitcnt vmcnt(6)");
    __builtin_amdgcn_s_barrier();

    unsigned cur = 0u, nxt = 24576u, thr = 49152u;
    for (int t = 0; t < NT; ++t) {
        if (t + 2 < NT) stage(t + 2, thr);

        pair4 a_[4], b_[2];
#pragma unroll
        for (int mf = 0; mf < 4; ++mf) {
            DSR(a_[mf].lo, cur + addrA[mf]);
            DSR(a_[mf].hi, (cur + addrA[mf]) ^ 16u);
        }
#pragma unroll
        for (int nf = 0; nf < 2; ++nf) {
            DSR(b_[nf].lo, cur + addrB[nf]);
            DSR(b_[nf].hi, (cur + addrB[nf]) ^ 16u);
        }
        asm volatile("s_waitcnt lgkmcnt(0)");
        __builtin_amdgcn_sched_barrier(0);

        __builtin_amdgcn_s_setprio(1);
#pragma unroll
        for (int mf = 0; mf < 4; ++mf)
#pragma unroll
            for (int nf = 0; nf < 2; ++nf)
                acc[mf][nf] = __builtin_amdgcn_mfma_scale_f32_32x32x64_f8f6f4(
                    __builtin_bit_cast(i32x8_t, a_[mf]),
                    __builtin_bit_cast(i32x8_t, b_[nf]), acc[mf][nf],
                    0, 0, 0, 0x7F7F7F7F, 0, 0x7F7F7F7F);
        __builtin_amdgcn_s_setprio(0);

        if (t + 2 < NT)      { asm volatile("s_waitcnt vmcnt(6)"); }
        else if (t + 1 < NT) { asm volatile("s_waitcnt vmcnt(0)"); }
        __builtin_amdgcn_s_barrier();
        const unsigned tmp = cur; cur = nxt; nxt = thr; thr = tmp;
    }
#undef DSR

    // C/D 32x32 layout: col = lane&31, row = (rg&3) + 8*(rg>>2) + 4*(lane>>5)
    if (cmode == 0) {
        __hip_bfloat16* C = (__hip_bfloat16*)Cv;
#pragma unroll
        for (int nf = 0; nf < 2; ++nf) {
            const int col = o0 + wn * 64 + nf * 32 + l31;
            const float bv = bias[col];
#pragma unroll
            for (int mf = 0; mf < 4; ++mf)
#pragma unroll
                for (int rg = 0; rg < 16; ++rg) {
                    const int row = n0 + wm * 128 + mf * 32 + (rg & 3) + ((rg >> 2) << 3) + (h << 2);
                    C[(size_t)row * ldc + coff + col] = __float2bfloat16(acc[mf][nf][rg] + bv);
                }
        }
    } else {
        unsigned char* C8 = (unsigned char*)Cv;
#pragma unroll
        for (int nf = 0; nf < 2; ++nf) {
            const int col = o0 + wn * 64 + nf * 32 + l31;
            const float bv = bias[col];
#pragma unroll
            for (int mf = 0; mf < 4; ++mf)
#pragma unroll
                for (int q = 0; q < 4; ++q) {
                    int dw = __builtin_amdgcn_cvt_pk_fp8_f32(acc[mf][nf][4 * q] + bv,
                                                             acc[mf][nf][4 * q + 1] + bv, 0, false);
                    dw     = __builtin_amdgcn_cvt_pk_fp8_f32(acc[mf][nf][4 * q + 2] + bv,
                                                             acc[mf][nf][4 * q + 3] + bv, dw, true);
                    const int row = n0 + wm * 128 + mf * 32 + 8 * q + (h << 2);
                    const size_t base = (size_t)row * ldc + coff + col;
                    const unsigned u = (unsigned)dw;
                    C8[base]           = (unsigned char)u;
                    C8[base + ldc]     = (unsigned char)(u >> 8);
                    C8[base + 2 * ldc] = (unsigned char)(u >> 16);
                    C8[base + 3 * ldc] = (unsigned char)(u >> 24);
                }
        }
    }
}

// ---------------------------------------------------------------------------
// 256x256 bf16 NT GEMM (fallback path only; R7 structure).
// ---------------------------------------------------------------------------
__global__ __launch_bounds__(512, 2)
void gemm256(const __hip_bfloat16* __restrict__ A, int lda,
             const __hip_bfloat16* __restrict__ B, int ldb,
             const float* __restrict__ bias,
             __hip_bfloat16* __restrict__ C, int ldc, int coff0,
             int K, int NO, int TPB, int brA, int brB, int bstride,
             int cstride, int trans_out)
{
    __shared__ __align__(16) unsigned char smem[131072];
    const int tid  = threadIdx.x;
    const int lane = tid & 63;
    const int wave = tid >> 6;
    const int wm   = wave >> 2;
    const int wn   = wave & 3;
    const int l16  = lane & 15;
    const int l4   = lane >> 4;

    const int per  = gridDim.x >> 3;
    const int flat = (blockIdx.x & 7) * per + (blockIdx.x >> 3);
    const int br   = flat / TPB;
    const int rem  = flat - br * TPB;
    const int nt   = rem / NO;
    const int ot   = rem - nt * NO;
    const int n0 = nt * 256;
    const int o0 = ot * 256;
    const int NT = K >> 6;

    A    += (size_t)br * (size_t)brA;
    B    += (size_t)br * (size_t)brB;
    bias += br * bstride;
    const int coff = coff0 + br * cstride;

    const unsigned xorv = (unsigned)((l16 & 7) << 4);
    unsigned baseA[2], baseB[2];
#pragma unroll
    for (int kk = 0; kk < 2; ++kk) {
        const unsigned ko = ((unsigned)(kk * 64 + l4 * 16)) ^ xorv;
        baseA[kk] = (unsigned)((wm * 128 + l16) * 128) + ko;
        baseB[kk] = 32768u + (unsigned)((wn * 64 + l16) * 128) + ko;
    }

    const int rr  = lane >> 3;
    const int kel = 8 * ((lane & 7) ^ rr);

    auto stageA = [&](int t, int half) {
        const unsigned dst = (unsigned)((t & 1) * 65536 + half * 16384 + wave * 2048);
        const __hip_bfloat16* g = A + (size_t)(n0 + half * 128 + wave * 16 + rr) * lda + t * 64 + kel;
#pragma unroll
        for (int s = 0; s < 2; ++s) {
            __builtin_amdgcn_global_load_lds(
                (const __attribute__((address_space(1))) unsigned int*)(g + (size_t)s * 8 * lda),
                (__attribute__((address_space(3))) unsigned int*)(smem + dst + s * 1024),
                16, 0, 0);
        }
    };
    auto stageB = [&](int t, int half) {
        const unsigned dst = (unsigned)((t & 1) * 65536 + 32768 + half * 16384 + wave * 2048);
        const __hip_bfloat16* g = B + (size_t)(o0 + half * 128 + wave * 16 + rr) * ldb + t * 64 + kel;
#pragma unroll
        for (int s = 0; s < 2; ++s) {
            __builtin_amdgcn_global_load_lds(
                (const __attribute__((address_space(1))) unsigned int*)(g + (size_t)s * 8 * ldb),
                (__attribute__((address_space(3))) unsigned int*)(smem + dst + s * 1024),
                16, 0, 0);
        }
    };

#define DSRO(dst, addr, OFF) \
    asm volatile("ds_read_b128 %0, %1 offset:" #OFF : "=v"(dst) : "v"(addr))
#define BC(x) __builtin_bit_cast(bf16x8_t, x)

    stageA(0, 0); stageA(0, 1); stageB(0, 0); stageB(0, 1);
    stageA(1, 0); stageA(1, 1); stageB(1, 0); stageB(1, 1);
    asm volatile("s_waitcnt vmcnt(8)");
    __builtin_amdgcn_s_barrier();

    f32x4_t aR[4][2], a2[4][2], bA[2][2], bB[2][2];
    f32x4_t acc[8][4];
#pragma unroll
    for (int m = 0; m < 8; ++m)
#pragma unroll
        for (int n = 0; n < 4; ++n) acc[m][n] = (f32x4_t){0.f, 0.f, 0.f, 0.f};

    {
        unsigned a0 = baseA[0], a1 = baseA[1], b0 = baseB[0], b1 = baseB[1];
        DSRO(aR[0][0], a0, 0);    DSRO(aR[1][0], a0, 2048);
        DSRO(aR[2][0], a0, 4096); DSRO(aR[3][0], a0, 6144);
        DSRO(aR[0][1], a1, 0);    DSRO(aR[1][1], a1, 2048);
        DSRO(aR[2][1], a1, 4096); DSRO(aR[3][1], a1, 6144);
        DSRO(bA[0][0], b0, 0);    DSRO(bA[1][0], b0, 2048);
        DSRO(bA[0][1], b1, 0);    DSRO(bA[1][1], b1, 2048);
    }

    unsigned cb = 0;
    for (int t = 0; t < NT; ++t) {
        const unsigned cbn = cb ^ 65536u;
        const unsigned a0 = cb + baseA[0], a1 = cb + baseA[1];
        const unsigned b0 = cb + baseB[0], b1 = cb + baseB[1];

        asm volatile("s_waitcnt lgkmcnt(0)");
        __builtin_amdgcn_sched_barrier(0);
        DSRO(bB[0][0], b0, 4096); DSRO(bB[1][0], b0, 6144);
        DSRO(bB[0][1], b1, 4096); DSRO(bB[1][1], b1, 6144);
        __builtin_amdgcn_sched_barrier(0);
        __builtin_amdgcn_s_setprio(1);
#pragma unroll
        for (int m = 0; m < 4; ++m)
#pragma unroll
            for (int n = 0; n < 2; ++n)
#pragma unroll
                for (int kk = 0; kk < 2; ++kk)
                    acc[m][n] = __builtin_amdgcn_mfma_f32_16x16x32_bf16(BC(aR[m][kk]), BC(bA[n][kk]), acc[m][n], 0, 0, 0);
        __builtin_amdgcn_s_setprio(0);
        __builtin_amdgcn_s_barrier();

        asm volatile("s_waitcnt lgkmcnt(0)");
        __builtin_amdgcn_sched_barrier(0);
        DSRO(a2[0][0], a0, 8192);  DSRO(a2[1][0], a0, 10240);
        DSRO(a2[2][0], a0, 12288); DSRO(a2[3][0], a0, 14336);
        DSRO(a2[0][1], a1, 8192);  DSRO(a2[1][1], a1, 10240);
        DSRO(a2[2][1], a1, 12288); DSRO(a2[3][1], a1, 14336);
        __builtin_amdgcn_sched_barrier(0);
        __builtin_amdgcn_s_setprio(1);
#pragma unroll
        for (int m = 0; m < 4; ++m)
#pragma unroll
            for (int n = 0; n < 2; ++n)
#pragma unroll
                for (int kk = 0; kk < 2; ++kk)
                    acc[m][n + 2] = __builtin_amdgcn_mfma_f32_16x16x32_bf16(BC(aR[m][kk]), BC(bB[n][kk]), acc[m][n + 2], 0, 0, 0);
        __builtin_amdgcn_s_setprio(0);
        __builtin_amdgcn_s_barrier();

        asm volatile("s_waitcnt lgkmcnt(0)");
        __builtin_amdgcn_sched_barrier(0);
        if (t + 2 < NT) { stageB(t + 2, 0); stageB(t + 2, 1); }
        __builtin_amdgcn_sched_barrier(0);
        __builtin_amdgcn_s_setprio(1);
#pragma unroll
        for (int m = 0; m < 4; ++m)
#pragma unroll
            for (int n = 0; n < 2; ++n)
#pragma unroll
                for (int kk = 0; kk < 2; ++kk)
                    acc[m + 4][n] = __builtin_amdgcn_mfma_f32_16x16x32_bf16(BC(a2[m][kk]), BC(bA[n][kk]), acc[m + 4][n], 0, 0, 0);
        __builtin_amdgcn_s_setprio(0);
        if (t + 2 < NT)        { asm volatile("s_waitcnt vmcnt(4)"); }
        else if (t + 2 == NT)  { asm volatile("s_waitcnt vmcnt(0)"); }
        __builtin_amdgcn_s_barrier();

        if (t + 1 < NT) {
            const unsigned na0 = cbn + baseA[0], na1 = cbn + baseA[1];
            const unsigned nb0 = cbn + baseB[0], nb1 = cbn + baseB[1];
            DSRO(aR[0][0], na0, 0);    DSRO(aR[1][0], na0, 2048);
            DSRO(aR[2][0], na0, 4096); DSRO(aR[3][0], na0, 6144);
            DSRO(aR[0][1], na1, 0);    DSRO(aR[1][1], na1, 2048);
            DSRO(aR[2][1], na1, 4096); DSRO(aR[3][1], na1, 6144);
            DSRO(bA[0][0], nb0, 0);    DSRO(bA[1][0], nb0, 2048);
            DSRO(bA[0][1], nb1, 0);    DSRO(bA[1][1], nb1, 2048);
        }
        if (t + 2 < NT) { stageA(t + 2, 0); stageA(t + 2, 1); }
        __builtin_amdgcn_sched_barrier(0);
        __builtin_amdgcn_s_setprio(1);
#pragma unroll
        for (int m = 0; m < 4; ++m)
#pragma unroll
            for (int n = 0; n < 2; ++n)
#pragma unroll
                for (int kk = 0; kk < 2; ++kk)
                    acc[m + 4][n + 2] = __builtin_amdgcn_mfma_f32_16x16x32_bf16(BC(a2[m][kk]), BC(bB[n][kk]), acc[m + 4][n + 2], 0, 0, 0);
        __builtin_amdgcn_s_setprio(0);
        cb = cbn;
    }

    if (!trans_out) {
#pragma unroll
        for (int n = 0; n < 4; ++n) {
            const int oc = o0 + wn * 64 + n * 16 + l16;
            const float bv = bias[oc];
#pragma unroll
            for (int m = 0; m < 8; ++m)
#pragma unroll
                for (int r = 0; r < 4; ++r) {
                    const int nr = n0 + wm * 128 + m * 16 + l4 * 4 + r;
                    C[(size_t)nr * ldc + coff + oc] = __float2bfloat16(acc[m][n][r] + bv);
                }
        }
    } else {
        __syncthreads();
#pragma unroll
        for (int n = 0; n < 4; ++n) {
            const int ocl = wn * 64 + n * 16 + l16;
            const float bv = bias[o0 + ocl];
#pragma unroll
            for (int m = 0; m < 8; ++m)
#pragma unroll
                for (int r = 0; r < 4; ++r) {
                    const int nrow = wm * 128 + m * 16 + l4 * 4 + r;
                    const unsigned phys = (unsigned)nrow * 512u
                        + (((unsigned)ocl * 2u) ^ (((unsigned)(nrow & 7)) << 4));
                    *(unsigned short*)(smem + phys) = f2bf(acc[m][n][r] + bv);
                }
        }
        __syncthreads();
        const int ol = tid >> 1;
        const int nh = (tid & 1) * 128;
        __hip_bfloat16* dst = C + (size_t)(coff + o0 + ol) * ldc + n0 + nh;
#pragma unroll
        for (int j8 = 0; j8 < 16; ++j8) {
            u16x8_t v;
#pragma unroll
            for (int e = 0; e < 8; ++e) {
                const int n2 = nh + j8 * 8 + e;
                v[e] = *(const unsigned short*)(smem + (unsigned)n2 * 512u
                        + ((((unsigned)ol * 2u) ^ ((unsigned)e << 4))));
            }
            *(u16x8_t*)((unsigned short*)dst + j8 * 8) = v;
        }
    }
#undef DSRO
#undef BC
}

// ---------------------------------------------------------------------------
// final_v2: G^T [NPIX][1536] n-major, Xb [3][NPIX][512] bf16 (= gamma_i x_i).
// ---------------------------------------------------------------------------
__global__ __launch_bounds__(256)
void final_v2(const __hip_bfloat16* __restrict__ G,
              const __hip_bfloat16* __restrict__ Xb,
              float* __restrict__ out)
{
    __shared__ float tile[64][68];
    const int n0  = blockIdx.x * 64;
    const int b   = n0 >> 10;
    const int hw0 = n0 & (HWSZ - 1);
    const int t   = threadIdx.x;
    const int nl  = t >> 2;
    const int cg  = (t & 3) * 16;
    const int n   = n0 + nl;
    const unsigned short* gr = (const unsigned short*)G + (size_t)n * 1536;
    const unsigned short* xr = (const unsigned short*)Xb + (size_t)n * 512;
    const int seg = t & 3;
    float* outb = out + (size_t)b * (DCH * HWSZ) + hw0;

    for (int c0 = 0; c0 < DCH; c0 += 64) {
        u16x8_t gl[3][2], xl[3][2];
#pragma unroll
        for (int i = 0; i < 3; ++i) {
            gl[i][0] = *(const u16x8_t*)(gr + i * 512 + c0 + cg);
            gl[i][1] = *(const u16x8_t*)(gr + i * 512 + c0 + cg + 8);
            xl[i][0] = *(const u16x8_t*)(xr + (size_t)i * NPIX * 512 + c0 + cg);
            xl[i][1] = *(const u16x8_t*)(xr + (size_t)i * NPIX * 512 + c0 + cg + 8);
        }
#pragma unroll
        for (int e = 0; e < 16; ++e) {
            const int hh = e >> 3, w = e & 7;
            const float s0 = bf2f(gl[0][hh][w]);
            const float s1 = bf2f(gl[1][hh][w]);
            const float s2 = bf2f(gl[2][hh][w]);
            const float g0 = 1.0f / (1.0f + __expf(-s0));
            const float g1 = 1.0f / (1.0f + __expf(-s1));
            const float g2 = 1.0f / (1.0f + __expf(-s2));
            const float e0 = __expf(g0), e1 = __expf(g1), e2 = __expf(g2);
            const float inv = 1.0f / (e0 + e1 + e2);
            tile[cg + e][nl] = inv * (e0 * bf2f(xl[0][hh][w])
                                    + e1 * bf2f(xl[1][hh][w])
                                    + e2 * bf2f(xl[2][hh][w]));
        }
        __syncthreads();
#pragma unroll
        for (int j4 = 0; j4 < 4; ++j4) {
            float4 v = *(const float4*)&tile[nl][seg * 16 + j4 * 4];
            *(float4*)(outb + (size_t)(c0 + nl) * HWSZ + seg * 16 + j4 * 4) = v;
        }
        __syncthreads();
    }
}

// ---------------------------------------------------------------------------
// final (fallback): G channel-major [1536][NPIX], x fp32 natural layout.
// ---------------------------------------------------------------------------
__global__ __launch_bounds__(256)
void final_fuse(const __hip_bfloat16* __restrict__ G,
                const float* __restrict__ x0, const float* __restrict__ x1,
                const float* __restrict__ x2,
                const float* __restrict__ gp0, const float* __restrict__ gp1,
                const float* __restrict__ gp2,
                float* __restrict__ out)
{
    const int n  = blockIdx.x * 256 + threadIdx.x;
    const int b  = n >> 10;
    const int hw = n & (HWSZ - 1);
    const int c0 = blockIdx.y * 64;
    const float ga0 = gp0[0], ga1 = gp1[0], ga2 = gp2[0];
    for (int cc = 0; cc < 64; ++cc) {
        const int c = c0 + cc;
        const float s0 = __bfloat162float(G[(size_t)c * NPIX + n]);
        const float s1 = __bfloat162float(G[(size_t)(c + DCH) * NPIX + n]);
        const float s2 = __bfloat162float(G[(size_t)(c + 2 * DCH) * NPIX + n]);
        const float g0v = 1.0f / (1.0f + __expf(-s0));
        const float g1v = 1.0f / (1.0f + __expf(-s1));
        const float g2v = 1.0f / (1.0f + __expf(-s2));
        const float e0 = __expf(g0v), e1 = __expf(g1v), e2 = __expf(g2v);
        const float inv = 1.0f / (e0 + e1 + e2);
        const size_t xo = (size_t)b * (DCH * HWSZ) + (size_t)c * HWSZ + hw;
        out[xo] = inv * (e0 * ga0 * x0[xo] + e1 * ga1 * x1[xo] + e2 * ga2 * x2[xo]);
    }
}

// ---------------------------------------------------------------------------
extern "C" void kernel_launch(void* const* d_in, const int* in_sizes, int n_in,
                              void* d_out, int out_size, void* d_ws, size_t ws_size,
                              hipStream_t stream)
{
    const float* out0   = (const float*)d_in[0];
    const float* out1   = (const float*)d_in[1];
    const float* out2   = (const float*)d_in[2];
    const float* gamma0 = (const float*)d_in[3];
    const float* gamma1 = (const float*)d_in[4];
    const float* gamma2 = (const float*)d_in[5];
    const float* W_in1  = (const float*)d_in[6];
    const float* W_in2  = (const float*)d_in[8];
    const float* W_in3  = (const float*)d_in[10];
    const float* b_in1  = (const float*)d_in[7];
    const float* b_in2  = (const float*)d_in[9];
    const float* b_in3  = (const float*)d_in[11];
    const float* W_tr   = (const float*)d_in[12];
    const float* b_tr   = (const float*)d_in[13];
    const float* W_o1   = (const float*)d_in[14];
    const float* b_o1   = (const float*)d_in[15];
    const float* W_o2   = (const float*)d_in[16];
    const float* b_o2   = (const float*)d_in[17];
    const float* W_o3   = (const float*)d_in[18];
    const float* b_o3   = (const float*)d_in[19];
    float* outp = (float*)d_out;

    unsigned char* ws = (unsigned char*)d_ws;
    const size_t SZ_ACT  = (size_t)3 * NPIX * DCH * 2;   // 96 MB bf16 acts
    const size_t SZ_ACT8 = (size_t)3 * NPIX * DCH;       // 48 MB fp8 acts
    const size_t WB_BF16 = (size_t)(6 * WSQ + WTR) * 2;  // 7864320
    const size_t WB_FP8  = (size_t)(6 * WSQ + WTR);      // 3932160
    const size_t NEED    = 2 * SZ_ACT + SZ_ACT8 + WB_BF16 + WB_FP8 + 16384;
    const bool   big     = (ws_size >= NEED);

    // big layout: buf0 (96M bf16 XbT) | P8 (48M: XbT8 then Htra8) |
    //             Q (96M: Hcat8 first 48M, then G bf16) | weights | bias
    __hip_bfloat16* buf0 = (__hip_bfloat16*)ws;
    unsigned char*  P8   = ws + SZ_ACT;
    unsigned char*  Q    = ws + SZ_ACT + SZ_ACT8;
    unsigned char*  wtop = big ? (ws + 2 * SZ_ACT + SZ_ACT8) : (ws + 2 * SZ_ACT);
    __hip_bfloat16* Wb     = (__hip_bfloat16*)wtop;
    __hip_bfloat16* Wb_tr  = Wb + 3 * WSQ;
    __hip_bfloat16* Wb_o   = Wb_tr + WTR;
    unsigned char*  Wf8    = wtop + WB_BF16;
    unsigned char*  Win8   = Wf8;
    unsigned char*  Wtr8   = Wf8 + 3 * WSQ;
    unsigned char*  Wo8    = Wf8 + 3 * WSQ + WTR;
    float*          biasWS = (float*)(wtop + WB_BF16 + WB_FP8);

    const int NB = (6 * WSQ + WTR) >> 10;   // 3840
    cvt_all<<<2 * NB + 1, 256, 0, stream>>>(
        W_in1, W_in2, W_in3, W_tr, W_o1, W_o2, W_o3, Wb, Wf8,
        b_in1, b_in2, b_in3, b_o1, b_o2, b_o3, biasWS);

    stage_transpose<<<dim3(16, 8, 96), 256, 0, stream>>>(
        out0, out1, out2, gamma0, gamma1, gamma2, buf0, P8, big ? 1 : 0);

    if (big) {
        // GEMM-A (fp8 batched): XbT8 x W_in_i -> Hcat8[n][br*512+o]
        gemm_f8<<<dim3(1536), 256, 0, stream>>>(
            P8, DCH, Win8, DCH, biasWS, Q, 3 * DCH, 0,
            DCH, 4, 512, NPIX * DCH, WSQ, DCH, DCH, 1);
        // GEMM-B (fp8): Hcat8 x Wtr8 -> Htra8 (P8; XbT8 dead)
        gemm_f8<<<dim3(1536), 256, 0, stream>>>(
            Q, 3 * DCH, Wtr8, 3 * DCH, b_tr, P8, 3 * DCH, 0,
            3 * DCH, 12, 1536, 0, 0, 0, 0, 1);
        // GEMM-C (fp8 batched): Htra8[:, br*512:] x W_out_i -> G bf16 (Q; Hcat8 dead)
        gemm_f8<<<dim3(1536), 256, 0, stream>>>(
            P8, 3 * DCH, Wo8, DCH, biasWS + 3 * DCH, Q, 3 * DCH, 0,
            DCH, 4, 512, DCH, WSQ, DCH, DCH, 0);
        final_v2<<<dim3(NPIX / 64), 256, 0, stream>>>((const __hip_bfloat16*)Q, buf0, outp);
    } else {
        // fallback: all-bf16 two-buffer flow (R7)
        __hip_bfloat16* buf1 = (__hip_bfloat16*)(ws + SZ_ACT);
        gemm256<<<dim3(768), 512, 0, stream>>>(
            buf0, DCH, Wb, DCH, biasWS,
            buf1, 3 * DCH, 0, DCH, 2, 256, NPIX * DCH, WSQ, DCH, DCH, 0);
        gemm256<<<dim3(768), 512, 0, stream>>>(
            buf1, 3 * DCH, Wb_tr, 3 * DCH, b_tr,
            buf0, 3 * DCH, 0, 3 * DCH, 6, 768, 0, 0, 0, 0, 0);
        gemm256<<<dim3(768), 512, 0, stream>>>(
            buf0, 3 * DCH, Wb_o, DCH, biasWS + 3 * DCH,
            buf1, NPIX, 0, DCH, 2, 256, DCH, WSQ, DCH, DCH, 1);
        final_fuse<<<dim3(NPIX / 256, DCH / 64), 256, 0, stream>>>(
            buf1, out0, out1, out2, gamma0, gamma1, gamma2, outp);
    }
}